// Round 6
// baseline (1149.483 us; speedup 1.0000x reference)
//
#include <hip/hip_runtime.h>

// PVDST semseg, MI355X/gfx950. FP32 I/O. Round-5: KNN insert codegen fix.
//   - R4 post-mortem: knn_scan issue-bound at ~350 VALU/candidate (4x ideal):
//     bool c[16] all-live predicates forced VGPR materialization + re-cmp.
//   - Now: packed u64 keys (monotone(d)<<32 | idx) -> unique keys, no tie
//     logic, one array; per-j compute-and-consume predicates (<=2 live).
//   - merge on u64 keys, 256x64 grid; pool split into 512-block partial +
//     reduce. Rest unchanged (passed, absmax 2.9e-3).

#define NB 4
#define NP 4096
#define NT 16384   // NB*NP tokens

#define SCRATCH_BYTES (132u*1024u*1024u)
__device__ __align__(256) unsigned char g_scratch[SCRATCH_BYTES];

typedef __attribute__((ext_vector_type(8))) short short8;   // 8 x bf16 MFMA frag
typedef __attribute__((ext_vector_type(4))) float f32x4;    // MFMA acc
typedef __attribute__((ext_vector_type(4))) unsigned short ushort4v;
typedef unsigned long long u64;

__device__ __forceinline__ float bf2f(unsigned short u){
  unsigned int v = ((unsigned int)u) << 16;
  return __builtin_bit_cast(float, v);
}
__device__ __forceinline__ unsigned short f2bf(float f){
  unsigned int x = __builtin_bit_cast(unsigned int, f);
  x += 0x7fffu + ((x >> 16) & 1u);     // RNE
  return (unsigned short)(x >> 16);
}
// numpy-matched: ((x*x)+(y*y))+(z*z), each op rounded (no fma contraction)
__device__ __forceinline__ float sq3(float x, float y, float z){
  return __fadd_rn(__fadd_rn(__fmul_rn(x,x), __fmul_rn(y,y)), __fmul_rn(z,z));
}
// monotone float->u32 (total order; d is never NaN/-0 here)
__device__ __forceinline__ unsigned fmono(float f){
  unsigned bits = __builtin_bit_cast(unsigned, f);
  unsigned mask = (unsigned)(((int)bits) >> 31) | 0x80000000u;
  return bits ^ mask;
}

// Branchless sorted-ascending insert of k into key[0..15] (unique keys).
// Each j reads old key[j],key[j-1] -> iterations independent, <=2 live preds.
__device__ __forceinline__ void key_insert16(u64 (&key)[16], u64 k){
  #pragma unroll
  for (int j=15;j>=1;--j){
    u64 mn = (k < key[j]) ? k : key[j];
    key[j] = (k < key[j-1]) ? key[j-1] : mn;
  }
  key[0] = (k < key[0]) ? k : key[0];
}

// ---------------- weight fp32 -> bf16 conversion prepass ----------------
__global__ __launch_bounds__(256) void cvt_flat(const float* __restrict__ src,
                                                unsigned dstOff, int n)
{
  unsigned short* dst = (unsigned short*)(g_scratch + dstOff);
  for (int i = blockIdx.x*256 + threadIdx.x; i < n; i += gridDim.x*256)
    dst[i] = f2bf(src[i]);
}
// cls_w1 x-half: rows x 1024 cols out of pitch-3072 rows
__global__ __launch_bounds__(256) void cvt_pitch1024(const float* __restrict__ src,
                                                     unsigned dstOff, int n /*rows<<10*/)
{
  unsigned short* dst = (unsigned short*)(g_scratch + dstOff);
  for (int i = blockIdx.x*256 + threadIdx.x; i < n; i += gridDim.x*256){
    int r = i >> 10, c = i & 1023;
    dst[i] = f2bf(src[(size_t)r*3072 + c]);
  }
}

// ---------------- KNN (exact fp32, packed u64 keys) ----------------
// grid (16 qchunks, 16 cchunks, B), block 256. One thread = one query vs 256
// candidates staged in LDS as float4(x,y,z,sq). 1024 blocks -> 4/CU.
__global__ __launch_bounds__(256) void knn_scan(const float* __restrict__ in,
                                                unsigned pkOff)
{
  u64* pkeys = (u64*)(g_scratch + pkOff);
  __shared__ float4 sp[256];
  int b = blockIdx.z, qc = blockIdx.x, cc = blockIdx.y;
  const float* xb = in + (size_t)b*9*NP;
  int base = cc*256;
  {
    int i = threadIdx.x;
    float x = xb[base+i], y = xb[NP+base+i], z = xb[2*NP+base+i];
    sp[i] = make_float4(x,y,z,sq3(x,y,z));
  }
  __syncthreads();
  int n = qc*256 + threadIdx.x;
  float xn=xb[n], yn=xb[NP+n], zn=xb[2*NP+n];
  float sqn = sq3(xn,yn,zn);
  u64 key[16];
  #pragma unroll
  for (int j=0;j<16;j++) key[j] = ~0ull;
  for (int mm=0; mm<256; ++mm){
    float4 p = sp[mm];
    float dot = __fadd_rn(__fadd_rn(__fmul_rn(xn,p.x), __fmul_rn(yn,p.y)), __fmul_rn(zn,p.z));
    float d = __fsub_rn(__fadd_rn(sqn, p.w), __fmul_rn(2.0f, dot));
    u64 k = ((u64)fmono(d) << 32) | (unsigned)(base + mm);
    key_insert16(key, k);
  }
  size_t o = ((size_t)((b*16 + cc)*NP + n))*16;
  #pragma unroll
  for (int j=0;j<16;j++) pkeys[o+j] = key[j];
}

// grid 256 x 64: merge 16 sorted key lists per query. Early-break: sorted
// list whose next key >= current 16th cannot contribute.
__global__ __launch_bounds__(64) void knn_merge(unsigned pkOff, unsigned idxOff)
{
  const u64* pkeys = (const u64*)(g_scratch + pkOff);
  int*       idxOut= (int*)(g_scratch + idxOff);
  int t = blockIdx.x*64 + threadIdx.x;
  int b = t >> 12, n = t & 4095;
  u64 key[16];
  #pragma unroll
  for (int j=0;j<16;j++) key[j] = ~0ull;
  for (int cc=0; cc<16; ++cc){
    size_t o = ((size_t)((b*16 + cc)*NP + n))*16;
    for (int j=0;j<16;j++){
      u64 k = pkeys[o+j];
      if (k >= key[15]) break;
      key_insert16(key, k);
    }
  }
  #pragma unroll
  for (int j=0;j<16;j++) idxOut[t*16+j] = (int)(key[j] & 0xffffffffu);
}

// ---------------- embedding conv1 (Cin=9), fp32 in -> bf16 out ----------------
__global__ __launch_bounds__(256) void emb1_kernel(const float* __restrict__ in,
                                                   const float* __restrict__ w1,
                                                   const float* __restrict__ s1,
                                                   const float* __restrict__ b1,
                                                   unsigned x1Off)
{
  unsigned short* x1 = (unsigned short*)(g_scratch + x1Off);
  __shared__ float wf[128*9], sf[128], bf_[128];
  for (int i=threadIdx.x;i<128*9;i+=256) wf[i]=w1[i];
  if (threadIdx.x < 128){ sf[threadIdx.x]=s1[threadIdx.x]; bf_[threadIdx.x]=b1[threadIdx.x]; }
  __syncthreads();
  int t = blockIdx.x*256 + threadIdx.x;
  int b = t >> 12, n = t & 4095;
  float v[9];
  #pragma unroll
  for (int c=0;c<9;c++) v[c] = in[((size_t)b*9 + c)*NP + n];
  for (int o=0;o<128;o+=2){
    float a0=0.f, a1=0.f;
    #pragma unroll
    for (int c=0;c<9;c++){ a0 += wf[o*9+c]*v[c]; a1 += wf[(o+1)*9+c]*v[c]; }
    a0 = fmaxf(sf[o]*a0 + bf_[o], 0.f);
    a1 = fmaxf(sf[o+1]*a1 + bf_[o+1], 0.f);
    unsigned pk = (unsigned)f2bf(a0) | ((unsigned)f2bf(a1) << 16);
    *(unsigned*)(x1 + (size_t)t*128 + o) = pk;
  }
}

// ---------------- generic token-major MFMA GEMM (bf16 in/out) ----------------
enum { EPI_PLAIN=0, EPI_RELU_SB=1, EPI_RES=2, EPI_LEAKY=3, EPI_CLS=4 };

template<int EPI, bool EXB>
__global__ __launch_bounds__(256) void gemm_tok(
    unsigned W0off, unsigned W1off, unsigned W2off,
    unsigned O0off, unsigned O1off, unsigned O2off,
    unsigned XoffB, int Xstride, int Xoff,
    int outStride, int outOff,
    const float* sPtr, const float* bPtr,
    const float* extraIn, unsigned extraOffB, int extraStride,
    unsigned resOffB, int resStride, int resOff,
    int K, int Astride)
{
  const unsigned short* X = (const unsigned short*)(g_scratch + XoffB);
  unsigned wOffB   = (blockIdx.z==0) ? W0off : ((blockIdx.z==1) ? W1off : W2off);
  unsigned outOffB = (blockIdx.z==0) ? O0off : ((blockIdx.z==1) ? O1off : O2off);
  const unsigned short* W = (const unsigned short*)(g_scratch + wOffB);
  unsigned short* out = (unsigned short*)(g_scratch + outOffB);
  int lane = threadIdx.x & 63, wave = threadIdx.x >> 6;
  int r = lane & 15, q = lane >> 4;
  int M0 = blockIdx.x*128 + (wave>>1)*64;
  int T0 = blockIdx.y*128 + (wave&1)*64;

  f32x4 acc[4][4];
  #pragma unroll
  for (int i=0;i<4;i++)
    #pragma unroll
    for (int j=0;j<4;j++)
      #pragma unroll
      for (int u=0;u<4;u++) acc[i][j][u] = 0.f;

  const unsigned short* Arow[4]; const unsigned short* Brow[4];
  #pragma unroll
  for (int i=0;i<4;i++) Arow[i] = W + (size_t)(M0 + i*16 + r)*Astride + q*8;
  #pragma unroll
  for (int j=0;j<4;j++) Brow[j] = X + (size_t)(T0 + j*16 + r)*Xstride + Xoff + q*8;

  for (int k0=0; k0<K; k0+=32){
    short8 a[4], bfr[4];
    #pragma unroll
    for (int i=0;i<4;i++) a[i]   = *(const short8*)(Arow[i] + k0);
    #pragma unroll
    for (int j=0;j<4;j++) bfr[j] = *(const short8*)(Brow[j] + k0);
    #pragma unroll
    for (int i=0;i<4;i++)
      #pragma unroll
      for (int j=0;j<4;j++)
        acc[i][j] = __builtin_amdgcn_mfma_f32_16x16x32_bf16(a[i], bfr[j], acc[i][j], 0, 0, 0);
  }

  // epilogue: D layout col=lane&15 (token), row=q*4+reg (channel)
  #pragma unroll
  for (int i=0;i<4;i++){
    int m = M0 + i*16 + q*4;
    float sv[4], bv[4];
    if constexpr (EPI != EPI_PLAIN){
      #pragma unroll
      for (int u=0;u<4;u++){ sv[u]=sPtr[m+u]; bv[u]=bPtr[m+u]; }
    }
    #pragma unroll
    for (int j=0;j<4;j++){
      int token = T0 + j*16 + r;
      float ex[4];
      if constexpr (EPI == EPI_CLS){
        int bb = token >> 12;
        #pragma unroll
        for (int u=0;u<4;u++)
          ex[u] = EXB ? extraIn[bb*extraStride + m + u]
                      : ((const float*)(g_scratch + extraOffB))[bb*extraStride + m + u];
      }
      float resv[4];
      if constexpr (EPI == EPI_RES){
        const unsigned short* resPtr = (const unsigned short*)(g_scratch + resOffB);
        ushort4v rv = *(const ushort4v*)(resPtr + (size_t)token*resStride + resOff + m);
        #pragma unroll
        for (int u=0;u<4;u++) resv[u]=bf2f(rv[u]);
      }
      ushort4v ov;
      #pragma unroll
      for (int u=0;u<4;u++){
        float a = acc[i][j][u];
        float vo;
        if constexpr (EPI == EPI_PLAIN)        vo = a;
        else if constexpr (EPI == EPI_RELU_SB) vo = fmaxf(sv[u]*a + bv[u], 0.f);
        else if constexpr (EPI == EPI_RES)     vo = resv[u] + fmaxf(sv[u]*a + bv[u], 0.f);
        else if constexpr (EPI == EPI_LEAKY){  float tt = sv[u]*a + bv[u]; vo = tt>0.f ? tt : 0.2f*tt; }
        else { /*EPI_CLS: relu(s*(acc+extra)+sh), bPtr=sh*/ vo = fmaxf(sv[u]*(a + ex[u]) + bv[u], 0.f); }
        ov[u] = f2bf(vo);
      }
      *(ushort4v*)(out + (size_t)token*outStride + outOff + m) = ov;
    }
  }
}

// ---------------- attention (one wave per query, 2 channels/lane) ----------------
__global__ __launch_bounds__(256) void attn_kernel(
  unsigned qOff, unsigned kOff, unsigned vOff, unsigned idxOff,
  const float* __restrict__ in, const float* __restrict__ wpos,
  unsigned aggOff)
{
  const unsigned short* Q  = (const unsigned short*)(g_scratch + qOff);
  const unsigned short* Kf = (const unsigned short*)(g_scratch + kOff);
  const unsigned short* V  = (const unsigned short*)(g_scratch + vOff);
  const int* idx           = (const int*)(g_scratch + idxOff);
  unsigned short* agg      = (unsigned short*)(g_scratch + aggOff);

  int lane = threadIdx.x & 63, wv = threadIdx.x >> 6;
  int t = blockIdx.x*4 + wv;
  int b = t >> 12, n = t & 4095;
  const float* xb = in + (size_t)b*9*NP;
  int c0 = lane*2;

  unsigned qv = *(const unsigned*)(Q + (size_t)t*128 + c0);
  float q0 = bf2f((unsigned short)(qv & 0xffff)), q1 = bf2f((unsigned short)(qv >> 16));
  float xn = xb[n], yn = xb[NP+n], zn = xb[2*NP+n];
  float wp00=wpos[c0*3+0],     wp01=wpos[c0*3+1],     wp02=wpos[c0*3+2];
  float wp10=wpos[(c0+1)*3+0], wp11=wpos[(c0+1)*3+1], wp12=wpos[(c0+1)*3+2];

  int mi[16]; float s[16];
  #pragma unroll
  for (int j=0;j<16;j++) mi[j] = idx[(size_t)t*16 + j] & 4095;  // mask: never OOB
  #pragma unroll
  for (int j=0;j<16;j++){
    unsigned kv = *(const unsigned*)(Kf + ((size_t)(b<<12) + mi[j])*128 + c0);
    float p = q0*bf2f((unsigned short)(kv & 0xffff)) + q1*bf2f((unsigned short)(kv >> 16));
    #pragma unroll
    for (int o=32;o>=1;o>>=1) p += __shfl_xor(p, o, 64);
    s[j] = p;
  }
  const float scale = 0.08838834764831845f; // 1/sqrt(128)
  float mx = s[0];
  #pragma unroll
  for (int j=1;j<16;j++) mx = fmaxf(mx, s[j]);
  float e[16], sum = 0.f;
  #pragma unroll
  for (int j=0;j<16;j++){ e[j] = __expf((s[j]-mx)*scale); sum += e[j]; }
  float inv = 1.f / sum;

  float a0=0.f, a1=0.f;
  #pragma unroll
  for (int j=0;j<16;j++){
    int m = mi[j];
    float w = e[j]*inv;
    unsigned vv = *(const unsigned*)(V + ((size_t)(b<<12) + m)*128 + c0);
    float rx = xn - xb[m];
    float ry = yn - xb[NP+m];
    float rz = zn - xb[2*NP+m];
    float p0 = wp00*rx + wp01*ry + wp02*rz;
    float p1 = wp10*rx + wp11*ry + wp12*rz;
    a0 += w*(bf2f((unsigned short)(vv & 0xffff)) + p0);
    a1 += w*(bf2f((unsigned short)(vv >> 16)) + p1);
  }
  unsigned pk = (unsigned)f2bf(a0) | ((unsigned)f2bf(a1) << 16);
  *(unsigned*)(agg + (size_t)t*128 + c0) = pk;
}

// ---------------- max/mean pool over tokens (two-stage) ----------------
// stage1 grid 512 (b*128 + cblk*8 + tseg), block 256 = 64 ch x 4 tg
__global__ __launch_bounds__(256) void pool_part(unsigned xfOff, unsigned gpOff)
{
  const unsigned short* xf = (const unsigned short*)(g_scratch + xfOff);
  float* gp = (float*)(g_scratch + gpOff);   // [b][seg][2][1024]
  int b = blockIdx.x >> 7, cblk = (blockIdx.x >> 3) & 15, seg = blockIdx.x & 7;
  int cl = threadIdx.x & 63, tg = threadIdx.x >> 6;
  int c = cblk*64 + cl;
  float mx = -3.0e38f, sm = 0.f;
  for (int n = seg*512 + tg; n < (seg+1)*512; n += 4){
    float v = bf2f(xf[((size_t)(b<<12) + n)*1024 + c]);
    mx = fmaxf(mx, v); sm += v;
  }
  __shared__ float smx[4][64], ssm[4][64];
  smx[tg][cl]=mx; ssm[tg][cl]=sm;
  __syncthreads();
  if (tg==0){
    #pragma unroll
    for (int k=1;k<4;k++){ mx = fmaxf(mx, smx[k][cl]); sm += ssm[k][cl]; }
    gp[((b*8 + seg)*2 + 0)*1024 + c] = mx;
    gp[((b*8 + seg)*2 + 1)*1024 + c] = sm;
  }
}
// stage2 grid 4 (b), block 256: each thread 4 channels
__global__ __launch_bounds__(256) void pool_final(unsigned gpOff, unsigned gOff)
{
  const float* gp = (const float*)(g_scratch + gpOff);
  float* g = (float*)(g_scratch + gOff);
  int b = blockIdx.x;
  for (int c = threadIdx.x; c < 1024; c += 256){
    float mx = -3.0e38f, sm = 0.f;
    #pragma unroll
    for (int seg=0; seg<8; ++seg){
      mx = fmaxf(mx, gp[((b*8 + seg)*2 + 0)*1024 + c]);
      sm += gp[((b*8 + seg)*2 + 1)*1024 + c];
    }
    g[b*2048 + c] = mx;
    g[b*2048 + 1024 + c] = sm * (1.f/4096.f);
  }
}

// gb[b][o] = cls_bias1[o] + sum_c W1[o][1024+c]*g[b][c]  (fp32; grid 8 x 256)
__global__ __launch_bounds__(256) void gterm_kernel(const float* __restrict__ w1,
                                                    const float* __restrict__ bias1,
                                                    unsigned gOff, unsigned gbOff)
{
  const float* g = (const float*)(g_scratch + gOff);
  float* gb = (float*)(g_scratch + gbOff);
  int b = blockIdx.x >> 1;
  int o = (blockIdx.x & 1)*256 + threadIdx.x;
  const float* wrow = w1 + (size_t)o*3072 + 1024;
  const float* gp = g + b*2048;
  float acc = 0.f;
  for (int c=0;c<2048;c+=4){
    float4 wv4 = *(const float4*)(wrow + c);
    acc += wv4.x*gp[c] + wv4.y*gp[c+1] + wv4.z*gp[c+2] + wv4.w*gp[c+3];
  }
  gb[b*512 + o] = acc + bias1[o];
}

// ---------------- classifier head (O=13), fp32 out ----------------
__global__ __launch_bounds__(256) void cls3_kernel(unsigned c2Off,
                                                   const float* __restrict__ w3,
                                                   const float* __restrict__ bias3,
                                                   float* __restrict__ outp)
{
  const unsigned short* c2 = (const unsigned short*)(g_scratch + c2Off);
  __shared__ float wf[13*256];
  __shared__ float bf3[13];
  for (int i=threadIdx.x;i<13*256;i+=256) wf[i]=w3[i];
  if (threadIdx.x < 13) bf3[threadIdx.x]=bias3[threadIdx.x];
  __syncthreads();
  int lane = threadIdx.x & 63, wv = threadIdx.x >> 6;
  int tl = lane >> 2, cq = lane & 3;
  int t = blockIdx.x*64 + wv*16 + tl;
  const unsigned short* xrow = c2 + (size_t)t*256 + cq*64;
  float acc[13];
  #pragma unroll
  for (int o=0;o<13;o++) acc[o]=0.f;
  for (int c=0;c<64;c+=8){
    short8 xv = *(const short8*)(xrow + c);
    float xs[8];
    #pragma unroll
    for (int u=0;u<8;u++) xs[u]=bf2f((unsigned short)xv[u]);
    #pragma unroll
    for (int o=0;o<13;o++){
      const float* wr = wf + o*256 + cq*64 + c;
      #pragma unroll
      for (int u=0;u<8;u++) acc[o] += wr[u]*xs[u];
    }
  }
  #pragma unroll
  for (int o=0;o<13;o++){
    acc[o] += __shfl_xor(acc[o], 1, 64);
    acc[o] += __shfl_xor(acc[o], 2, 64);
  }
  if (cq==0){
    int b = t >> 12, n = t & 4095;
    #pragma unroll
    for (int o=0;o<13;o++)
      outp[((size_t)b*13 + o)*NP + n] = acc[o] + bf3[o];
  }
}

// ---------------- launch ----------------
extern "C" void kernel_launch(void* const* d_in, const int* in_sizes, int n_in,
                              void* d_out, int out_size, void* d_ws, size_t ws_size,
                              hipStream_t stream) {
  (void)in_sizes; (void)n_in; (void)out_size; (void)d_ws; (void)ws_size;
  const float* in      = (const float*)d_in[0];
  const float* emb_w1  = (const float*)d_in[1];
  const float* emb_s1  = (const float*)d_in[2];
  const float* emb_b1  = (const float*)d_in[3];
  const float* emb_w2  = (const float*)d_in[4];
  const float* emb_s2  = (const float*)d_in[5];
  const float* emb_b2  = (const float*)d_in[6];
  const float* blk_wq  = (const float*)d_in[7];
  const float* blk_wk  = (const float*)d_in[8];
  const float* blk_wv  = (const float*)d_in[9];
  const float* blk_wpos= (const float*)d_in[10];
  const float* blk_wo  = (const float*)d_in[11];
  const float* blk_s   = (const float*)d_in[12];
  const float* blk_b   = (const float*)d_in[13];
  const float* fuse_w  = (const float*)d_in[14];
  const float* fuse_s  = (const float*)d_in[15];
  const float* fuse_b  = (const float*)d_in[16];
  const float* cls_w1  = (const float*)d_in[17];
  const float* cls_b1  = (const float*)d_in[18];
  const float* cls_s1  = (const float*)d_in[19];
  const float* cls_sh1 = (const float*)d_in[20];
  const float* cls_w2  = (const float*)d_in[21];
  const float* cls_b2  = (const float*)d_in[22];
  const float* cls_s2  = (const float*)d_in[23];
  const float* cls_sh2 = (const float*)d_in[24];
  const float* cls_w3  = (const float*)d_in[25];
  const float* cls_b3  = (const float*)d_in[26];

  // byte offsets into g_scratch (non-aliased)
  const unsigned MB = 1u<<20, KB = 1024u;
  const unsigned OFF_IDX   = 0;                 // 1 MB   int idx[T][16]
  const unsigned OFF_WQ    = 1*MB;              // 96 KB  bf16 (3,128,128)
  const unsigned OFF_WK    = 1*MB + 128*KB;     // 96 KB
  const unsigned OFF_WV    = 1*MB + 256*KB;     // 96 KB
  const unsigned OFF_WO    = 1*MB + 384*KB;     // 96 KB
  const unsigned OFF_WEMB2 = 1*MB + 512*KB;     // 32 KB  bf16 (128,128)
  const unsigned OFF_WFUSE = 1*MB + 576*KB;     // 768 KB bf16 (1024,384)
  const unsigned OFF_WW1   = 3*MB;              // 1 MB   bf16 (512,1024) x-half
  const unsigned OFF_WW2   = 4*MB;              // 256 KB bf16 (256,512)
  const unsigned OFF_X1    = 5*MB;              // 4 MB   bf16 (T,128)
  const unsigned OFF_X0    = 9*MB;              // 4 MB   bf16 (T,128)
  const unsigned OFF_XCAT  = 13*MB;             // 12 MB  bf16 (T,384)
  const unsigned OFF_QB    = 25*MB;             // 4 MB
  const unsigned OFF_KB    = 29*MB;             // 4 MB
  const unsigned OFF_VB    = 33*MB;             // 4 MB
  const unsigned OFF_AGG   = 37*MB;             // 4 MB
  const unsigned OFF_XF    = 41*MB;             // 32 MB  bf16 (T,1024)
  const unsigned OFF_C1    = 73*MB;             // 16 MB  bf16 (T,512)
  const unsigned OFF_C2    = 89*MB;             // 8 MB   bf16 (T,256)
  const unsigned OFF_G     = 97*MB;             // 32 KB  f32 (B,2048)
  const unsigned OFF_GB    = 97*MB + 64*KB;     // 8 KB   f32 (B,512)
  const unsigned OFF_GP    = 97*MB + 128*KB;    // 256 KB f32 pool partials
  const unsigned OFF_PK    = 98*MB;             // 32 MB  u64 knn keys (B,16,NP,16)
  float* outp = (float*)d_out;                  // (B,13,N) f32

  // 0: weight conversion prepass (fp32 -> bf16 into scratch)
  cvt_flat<<<dim3(64), 256, 0, stream>>>(emb_w2, OFF_WEMB2, 128*128);
  cvt_flat<<<dim3(192), 256, 0, stream>>>(blk_wq, OFF_WQ, 3*128*128);
  cvt_flat<<<dim3(192), 256, 0, stream>>>(blk_wk, OFF_WK, 3*128*128);
  cvt_flat<<<dim3(192), 256, 0, stream>>>(blk_wv, OFF_WV, 3*128*128);
  cvt_flat<<<dim3(192), 256, 0, stream>>>(blk_wo, OFF_WO, 3*128*128);
  cvt_flat<<<dim3(256), 256, 0, stream>>>(fuse_w, OFF_WFUSE, 1024*384);
  cvt_pitch1024<<<dim3(256), 256, 0, stream>>>(cls_w1, OFF_WW1, 512*1024);
  cvt_flat<<<dim3(256), 256, 0, stream>>>(cls_w2, OFF_WW2, 256*512);

  // 1-2: KNN
  knn_scan<<<dim3(16,16,4), 256, 0, stream>>>(in, OFF_PK);
  knn_merge<<<dim3(256), 64, 0, stream>>>(OFF_PK, OFF_IDX);
  // 3-4: embedding
  emb1_kernel<<<dim3(64), 256, 0, stream>>>(in, emb_w1, emb_s1, emb_b1, OFF_X1);
  gemm_tok<EPI_RELU_SB,false><<<dim3(1,128,1), 256, 0, stream>>>(
      OFF_WEMB2, OFF_WEMB2, OFF_WEMB2, OFF_X0, OFF_X0, OFF_X0,
      OFF_X1, 128, 0, 128, 0, emb_s2, emb_b2,
      nullptr, 0, 0, 0, 0, 0, 128, 128);
  // 5-7: transformer blocks
  for (int i=0;i<3;i++){
    unsigned wq = OFF_WQ + i*32768, wk = OFF_WK + i*32768;
    unsigned wv = OFF_WV + i*32768, wo = OFF_WO + i*32768;
    const float* wp = blk_wpos + i*128*3;
    const float* si = blk_s + i*128;
    const float* bi = blk_b + i*128;
    unsigned XiOff = (i==0) ? OFF_X0 : OFF_XCAT;
    int Xs = (i==0) ? 128 : 384;
    int Xo = (i==0) ? 0 : (i-1)*128;
    gemm_tok<EPI_PLAIN,false><<<dim3(1,128,3), 256, 0, stream>>>(
        wq, wk, wv, OFF_QB, OFF_KB, OFF_VB,
        XiOff, Xs, Xo, 128, 0, nullptr, nullptr,
        nullptr, 0, 0, 0, 0, 0, 128, 128);
    attn_kernel<<<dim3(4096), 256, 0, stream>>>(OFF_QB, OFF_KB, OFF_VB, OFF_IDX, in, wp, OFF_AGG);
    gemm_tok<EPI_RES,false><<<dim3(1,128,1), 256, 0, stream>>>(
        wo, wo, wo, OFF_XCAT, OFF_XCAT, OFF_XCAT,
        OFF_AGG, 128, 0, 384, i*128, si, bi,
        nullptr, 0, 0, XiOff, Xs, Xo, 128, 128);
  }
  // 8: fuse (leaky relu)
  gemm_tok<EPI_LEAKY,false><<<dim3(8,128,1), 256, 0, stream>>>(
      OFF_WFUSE, OFF_WFUSE, OFF_WFUSE, OFF_XF, OFF_XF, OFF_XF,
      OFF_XCAT, 384, 0, 1024, 0, fuse_s, fuse_b,
      nullptr, 0, 0, 0, 0, 0, 384, 384);
  // 9-10: pooling (two-stage) + broadcast-g term of cls1 (fp32)
  pool_part<<<dim3(512), 256, 0, stream>>>(OFF_XF, OFF_GP);
  pool_final<<<dim3(4), 256, 0, stream>>>(OFF_GP, OFF_G);
  gterm_kernel<<<dim3(8), 256, 0, stream>>>(cls_w1, cls_b1, OFF_G, OFF_GB);
  // 11: cls1 (K=1024 x-half of W1; gb = W1[:,1024:]@g + bias1 as extra)
  gemm_tok<EPI_CLS,false><<<dim3(4,128,1), 256, 0, stream>>>(
      OFF_WW1, OFF_WW1, OFF_WW1, OFF_C1, OFF_C1, OFF_C1,
      OFF_XF, 1024, 0, 512, 0, cls_s1, cls_sh1,
      nullptr, OFF_GB, 512, 0, 0, 0, 1024, 1024);
  // 12: cls2
  gemm_tok<EPI_CLS,true><<<dim3(2,128,1), 256, 0, stream>>>(
      OFF_WW2, OFF_WW2, OFF_WW2, OFF_C2, OFF_C2, OFF_C2,
      OFF_C1, 512, 0, 256, 0, cls_s2, cls_sh2,
      cls_b2, 0, 0, 0, 0, 0, 512, 512);
  // 13: cls3 -> d_out (fp32)
  cls3_kernel<<<dim3(256), 256, 0, stream>>>(OFF_C2, cls_w3, cls_b3, outp);
}

// Round 7
// 810.964 us; speedup vs baseline: 1.4174x; 1.4174x over previous
//
#include <hip/hip_runtime.h>

// PVDST semseg, MI355X/gfx950. FP32 I/O. Round-7: KNN spill fix.
//   - R6 post-mortem: u64 key[16] array was NOT promoted to VGPRs
//     (VGPR_Count=24 < 32 needed) -> scratch spill -> latency-bound
//     (VALUBusy 26%, occ 25%). Arrays out, predicates out.
//   - Now: 16 explicit u64 scalars + select-free sorted insert:
//     k_j = min(max(k_{j-1}, k), k_j)  (31 min/max = ~93 VALU, dep depth ~3).
//     Keys remain unique (mono(dist)<<32 | idx) => exact numpy-stable order.
// Rest unchanged from R6 (passed, absmax 2.9e-3; two-stage pool kept).

#define NB 4
#define NP 4096
#define NT 16384   // NB*NP tokens

#define SCRATCH_BYTES (132u*1024u*1024u)
__device__ __align__(256) unsigned char g_scratch[SCRATCH_BYTES];

typedef __attribute__((ext_vector_type(8))) short short8;   // 8 x bf16 MFMA frag
typedef __attribute__((ext_vector_type(4))) float f32x4;    // MFMA acc
typedef __attribute__((ext_vector_type(4))) unsigned short ushort4v;
typedef unsigned long long u64;

__device__ __forceinline__ float bf2f(unsigned short u){
  unsigned int v = ((unsigned int)u) << 16;
  return __builtin_bit_cast(float, v);
}
__device__ __forceinline__ unsigned short f2bf(float f){
  unsigned int x = __builtin_bit_cast(unsigned int, f);
  x += 0x7fffu + ((x >> 16) & 1u);     // RNE
  return (unsigned short)(x >> 16);
}
// numpy-matched: ((x*x)+(y*y))+(z*z), each op rounded (no fma contraction)
__device__ __forceinline__ float sq3(float x, float y, float z){
  return __fadd_rn(__fadd_rn(__fmul_rn(x,x), __fmul_rn(y,y)), __fmul_rn(z,z));
}
// monotone float->u32 (total order)
__device__ __forceinline__ unsigned fmono(float f){
  unsigned bits = __builtin_bit_cast(unsigned, f);
  unsigned mask = (unsigned)(((int)bits) >> 31) | 0x80000000u;
  return bits ^ mask;
}
__device__ __forceinline__ u64 minu64(u64 a, u64 b){ return a < b ? a : b; }
__device__ __forceinline__ u64 maxu64(u64 a, u64 b){ return a > b ? a : b; }

// select-free sorted-ascending insert into scalars k0..k15 (old values read,
// then all slots rewritten -- lines independent, exact for unique keys)
#define KDECL u64 k0=~0ull,k1=~0ull,k2=~0ull,k3=~0ull,k4=~0ull,k5=~0ull,\
  k6=~0ull,k7=~0ull,k8=~0ull,k9=~0ull,k10=~0ull,k11=~0ull,k12=~0ull,\
  k13=~0ull,k14=~0ull,k15=~0ull
#define KINS(kk) do{ u64 _k=(kk); \
  k15=minu64(maxu64(k14,_k),k15); \
  k14=minu64(maxu64(k13,_k),k14); \
  k13=minu64(maxu64(k12,_k),k13); \
  k12=minu64(maxu64(k11,_k),k12); \
  k11=minu64(maxu64(k10,_k),k11); \
  k10=minu64(maxu64(k9 ,_k),k10); \
  k9 =minu64(maxu64(k8 ,_k),k9 ); \
  k8 =minu64(maxu64(k7 ,_k),k8 ); \
  k7 =minu64(maxu64(k6 ,_k),k7 ); \
  k6 =minu64(maxu64(k5 ,_k),k6 ); \
  k5 =minu64(maxu64(k4 ,_k),k5 ); \
  k4 =minu64(maxu64(k3 ,_k),k4 ); \
  k3 =minu64(maxu64(k2 ,_k),k3 ); \
  k2 =minu64(maxu64(k1 ,_k),k2 ); \
  k1 =minu64(maxu64(k0 ,_k),k1 ); \
  k0 =minu64(k0,_k); }while(0)
#define KSTORE(p,o) do{ (p)[(o)+0]=k0;(p)[(o)+1]=k1;(p)[(o)+2]=k2;(p)[(o)+3]=k3;\
  (p)[(o)+4]=k4;(p)[(o)+5]=k5;(p)[(o)+6]=k6;(p)[(o)+7]=k7;\
  (p)[(o)+8]=k8;(p)[(o)+9]=k9;(p)[(o)+10]=k10;(p)[(o)+11]=k11;\
  (p)[(o)+12]=k12;(p)[(o)+13]=k13;(p)[(o)+14]=k14;(p)[(o)+15]=k15; }while(0)

// ---------------- weight fp32 -> bf16 conversion prepass ----------------
__global__ __launch_bounds__(256) void cvt_flat(const float* __restrict__ src,
                                                unsigned dstOff, int n)
{
  unsigned short* dst = (unsigned short*)(g_scratch + dstOff);
  for (int i = blockIdx.x*256 + threadIdx.x; i < n; i += gridDim.x*256)
    dst[i] = f2bf(src[i]);
}
// cls_w1 x-half: rows x 1024 cols out of pitch-3072 rows
__global__ __launch_bounds__(256) void cvt_pitch1024(const float* __restrict__ src,
                                                     unsigned dstOff, int n /*rows<<10*/)
{
  unsigned short* dst = (unsigned short*)(g_scratch + dstOff);
  for (int i = blockIdx.x*256 + threadIdx.x; i < n; i += gridDim.x*256){
    int r = i >> 10, c = i & 1023;
    dst[i] = f2bf(src[(size_t)r*3072 + c]);
  }
}

// ---------------- KNN (exact fp32, packed u64 keys, scalar regs) ----------------
// grid (16 qchunks, 16 cchunks, B), block 256. One thread = one query vs 256
// candidates staged in LDS as float4(x,y,z,sq). 1024 blocks -> 4/CU.
__global__ __launch_bounds__(256) void knn_scan(const float* __restrict__ in,
                                                unsigned pkOff)
{
  u64* pkeys = (u64*)(g_scratch + pkOff);
  __shared__ float4 sp[256];
  int b = blockIdx.z, qc = blockIdx.x, cc = blockIdx.y;
  const float* xb = in + (size_t)b*9*NP;
  int base = cc*256;
  {
    int i = threadIdx.x;
    float x = xb[base+i], y = xb[NP+base+i], z = xb[2*NP+base+i];
    sp[i] = make_float4(x,y,z,sq3(x,y,z));
  }
  __syncthreads();
  int n = qc*256 + threadIdx.x;
  float xn=xb[n], yn=xb[NP+n], zn=xb[2*NP+n];
  float sqn = sq3(xn,yn,zn);
  KDECL;
  for (int mm=0; mm<256; ++mm){
    float4 p = sp[mm];
    float dot = __fadd_rn(__fadd_rn(__fmul_rn(xn,p.x), __fmul_rn(yn,p.y)), __fmul_rn(zn,p.z));
    float d = __fsub_rn(__fadd_rn(sqn, p.w), __fmul_rn(2.0f, dot));
    u64 kk = ((u64)fmono(d) << 32) | (unsigned)(base + mm);
    KINS(kk);
  }
  size_t o = ((size_t)((b*16 + cc)*NP + n))*16;
  KSTORE(pkeys, o);
}

// grid 256 x 64: merge 16 sorted key lists per query. Early-break: sorted
// list whose next key >= current 16th cannot contribute.
__global__ __launch_bounds__(64) void knn_merge(unsigned pkOff, unsigned idxOff)
{
  const u64* pkeys = (const u64*)(g_scratch + pkOff);
  int*       idxOut= (int*)(g_scratch + idxOff);
  int t = blockIdx.x*64 + threadIdx.x;
  int b = t >> 12, n = t & 4095;
  KDECL;
  for (int cc=0; cc<16; ++cc){
    size_t o = ((size_t)((b*16 + cc)*NP + n))*16;
    #pragma unroll 1
    for (int j=0;j<16;j++){
      u64 kk = pkeys[o+j];
      if (kk >= k15) break;
      KINS(kk);
    }
  }
  idxOut[t*16+ 0]=(int)(k0 &0xffffffffu); idxOut[t*16+ 1]=(int)(k1 &0xffffffffu);
  idxOut[t*16+ 2]=(int)(k2 &0xffffffffu); idxOut[t*16+ 3]=(int)(k3 &0xffffffffu);
  idxOut[t*16+ 4]=(int)(k4 &0xffffffffu); idxOut[t*16+ 5]=(int)(k5 &0xffffffffu);
  idxOut[t*16+ 6]=(int)(k6 &0xffffffffu); idxOut[t*16+ 7]=(int)(k7 &0xffffffffu);
  idxOut[t*16+ 8]=(int)(k8 &0xffffffffu); idxOut[t*16+ 9]=(int)(k9 &0xffffffffu);
  idxOut[t*16+10]=(int)(k10&0xffffffffu); idxOut[t*16+11]=(int)(k11&0xffffffffu);
  idxOut[t*16+12]=(int)(k12&0xffffffffu); idxOut[t*16+13]=(int)(k13&0xffffffffu);
  idxOut[t*16+14]=(int)(k14&0xffffffffu); idxOut[t*16+15]=(int)(k15&0xffffffffu);
}

// ---------------- embedding conv1 (Cin=9), fp32 in -> bf16 out ----------------
__global__ __launch_bounds__(256) void emb1_kernel(const float* __restrict__ in,
                                                   const float* __restrict__ w1,
                                                   const float* __restrict__ s1,
                                                   const float* __restrict__ b1,
                                                   unsigned x1Off)
{
  unsigned short* x1 = (unsigned short*)(g_scratch + x1Off);
  __shared__ float wf[128*9], sf[128], bf_[128];
  for (int i=threadIdx.x;i<128*9;i+=256) wf[i]=w1[i];
  if (threadIdx.x < 128){ sf[threadIdx.x]=s1[threadIdx.x]; bf_[threadIdx.x]=b1[threadIdx.x]; }
  __syncthreads();
  int t = blockIdx.x*256 + threadIdx.x;
  int b = t >> 12, n = t & 4095;
  float v[9];
  #pragma unroll
  for (int c=0;c<9;c++) v[c] = in[((size_t)b*9 + c)*NP + n];
  for (int o=0;o<128;o+=2){
    float a0=0.f, a1=0.f;
    #pragma unroll
    for (int c=0;c<9;c++){ a0 += wf[o*9+c]*v[c]; a1 += wf[(o+1)*9+c]*v[c]; }
    a0 = fmaxf(sf[o]*a0 + bf_[o], 0.f);
    a1 = fmaxf(sf[o+1]*a1 + bf_[o+1], 0.f);
    unsigned pk = (unsigned)f2bf(a0) | ((unsigned)f2bf(a1) << 16);
    *(unsigned*)(x1 + (size_t)t*128 + o) = pk;
  }
}

// ---------------- generic token-major MFMA GEMM (bf16 in/out) ----------------
enum { EPI_PLAIN=0, EPI_RELU_SB=1, EPI_RES=2, EPI_LEAKY=3, EPI_CLS=4 };

template<int EPI, bool EXB>
__global__ __launch_bounds__(256) void gemm_tok(
    unsigned W0off, unsigned W1off, unsigned W2off,
    unsigned O0off, unsigned O1off, unsigned O2off,
    unsigned XoffB, int Xstride, int Xoff,
    int outStride, int outOff,
    const float* sPtr, const float* bPtr,
    const float* extraIn, unsigned extraOffB, int extraStride,
    unsigned resOffB, int resStride, int resOff,
    int K, int Astride)
{
  const unsigned short* X = (const unsigned short*)(g_scratch + XoffB);
  unsigned wOffB   = (blockIdx.z==0) ? W0off : ((blockIdx.z==1) ? W1off : W2off);
  unsigned outOffB = (blockIdx.z==0) ? O0off : ((blockIdx.z==1) ? O1off : O2off);
  const unsigned short* W = (const unsigned short*)(g_scratch + wOffB);
  unsigned short* out = (unsigned short*)(g_scratch + outOffB);
  int lane = threadIdx.x & 63, wave = threadIdx.x >> 6;
  int r = lane & 15, q = lane >> 4;
  int M0 = blockIdx.x*128 + (wave>>1)*64;
  int T0 = blockIdx.y*128 + (wave&1)*64;

  f32x4 acc[4][4];
  #pragma unroll
  for (int i=0;i<4;i++)
    #pragma unroll
    for (int j=0;j<4;j++)
      #pragma unroll
      for (int u=0;u<4;u++) acc[i][j][u] = 0.f;

  const unsigned short* Arow[4]; const unsigned short* Brow[4];
  #pragma unroll
  for (int i=0;i<4;i++) Arow[i] = W + (size_t)(M0 + i*16 + r)*Astride + q*8;
  #pragma unroll
  for (int j=0;j<4;j++) Brow[j] = X + (size_t)(T0 + j*16 + r)*Xstride + Xoff + q*8;

  for (int k0=0; k0<K; k0+=32){
    short8 a[4], bfr[4];
    #pragma unroll
    for (int i=0;i<4;i++) a[i]   = *(const short8*)(Arow[i] + k0);
    #pragma unroll
    for (int j=0;j<4;j++) bfr[j] = *(const short8*)(Brow[j] + k0);
    #pragma unroll
    for (int i=0;i<4;i++)
      #pragma unroll
      for (int j=0;j<4;j++)
        acc[i][j] = __builtin_amdgcn_mfma_f32_16x16x32_bf16(a[i], bfr[j], acc[i][j], 0, 0, 0);
  }

  // epilogue: D layout col=lane&15 (token), row=q*4+reg (channel)
  #pragma unroll
  for (int i=0;i<4;i++){
    int m = M0 + i*16 + q*4;
    float sv[4], bv[4];
    if constexpr (EPI != EPI_PLAIN){
      #pragma unroll
      for (int u=0;u<4;u++){ sv[u]=sPtr[m+u]; bv[u]=bPtr[m+u]; }
    }
    #pragma unroll
    for (int j=0;j<4;j++){
      int token = T0 + j*16 + r;
      float ex[4];
      if constexpr (EPI == EPI_CLS){
        int bb = token >> 12;
        #pragma unroll
        for (int u=0;u<4;u++)
          ex[u] = EXB ? extraIn[bb*extraStride + m + u]
                      : ((const float*)(g_scratch + extraOffB))[bb*extraStride + m + u];
      }
      float resv[4];
      if constexpr (EPI == EPI_RES){
        const unsigned short* resPtr = (const unsigned short*)(g_scratch + resOffB);
        ushort4v rv = *(const ushort4v*)(resPtr + (size_t)token*resStride + resOff + m);
        #pragma unroll
        for (int u=0;u<4;u++) resv[u]=bf2f(rv[u]);
      }
      ushort4v ov;
      #pragma unroll
      for (int u=0;u<4;u++){
        float a = acc[i][j][u];
        float vo;
        if constexpr (EPI == EPI_PLAIN)        vo = a;
        else if constexpr (EPI == EPI_RELU_SB) vo = fmaxf(sv[u]*a + bv[u], 0.f);
        else if constexpr (EPI == EPI_RES)     vo = resv[u] + fmaxf(sv[u]*a + bv[u], 0.f);
        else if constexpr (EPI == EPI_LEAKY){  float tt = sv[u]*a + bv[u]; vo = tt>0.f ? tt : 0.2f*tt; }
        else { /*EPI_CLS: relu(s*(acc+extra)+sh), bPtr=sh*/ vo = fmaxf(sv[u]*(a + ex[u]) + bv[u], 0.f); }
        ov[u] = f2bf(vo);
      }
      *(ushort4v*)(out + (size_t)token*outStride + outOff + m) = ov;
    }
  }
}

// ---------------- attention (one wave per query, 2 channels/lane) ----------------
__global__ __launch_bounds__(256) void attn_kernel(
  unsigned qOff, unsigned kOff, unsigned vOff, unsigned idxOff,
  const float* __restrict__ in, const float* __restrict__ wpos,
  unsigned aggOff)
{
  const unsigned short* Q  = (const unsigned short*)(g_scratch + qOff);
  const unsigned short* Kf = (const unsigned short*)(g_scratch + kOff);
  const unsigned short* V  = (const unsigned short*)(g_scratch + vOff);
  const int* idx           = (const int*)(g_scratch + idxOff);
  unsigned short* agg      = (unsigned short*)(g_scratch + aggOff);

  int lane = threadIdx.x & 63, wv = threadIdx.x >> 6;
  int t = blockIdx.x*4 + wv;
  int b = t >> 12, n = t & 4095;
  const float* xb = in + (size_t)b*9*NP;
  int c0 = lane*2;

  unsigned qv = *(const unsigned*)(Q + (size_t)t*128 + c0);
  float q0 = bf2f((unsigned short)(qv & 0xffff)), q1 = bf2f((unsigned short)(qv >> 16));
  float xn = xb[n], yn = xb[NP+n], zn = xb[2*NP+n];
  float wp00=wpos[c0*3+0],     wp01=wpos[c0*3+1],     wp02=wpos[c0*3+2];
  float wp10=wpos[(c0+1)*3+0], wp11=wpos[(c0+1)*3+1], wp12=wpos[(c0+1)*3+2];

  int mi[16]; float s[16];
  #pragma unroll
  for (int j=0;j<16;j++) mi[j] = idx[(size_t)t*16 + j] & 4095;  // mask: never OOB
  #pragma unroll
  for (int j=0;j<16;j++){
    unsigned kv = *(const unsigned*)(Kf + ((size_t)(b<<12) + mi[j])*128 + c0);
    float p = q0*bf2f((unsigned short)(kv & 0xffff)) + q1*bf2f((unsigned short)(kv >> 16));
    #pragma unroll
    for (int o=32;o>=1;o>>=1) p += __shfl_xor(p, o, 64);
    s[j] = p;
  }
  const float scale = 0.08838834764831845f; // 1/sqrt(128)
  float mx = s[0];
  #pragma unroll
  for (int j=1;j<16;j++) mx = fmaxf(mx, s[j]);
  float e[16], sum = 0.f;
  #pragma unroll
  for (int j=0;j<16;j++){ e[j] = __expf((s[j]-mx)*scale); sum += e[j]; }
  float inv = 1.f / sum;

  float a0=0.f, a1=0.f;
  #pragma unroll
  for (int j=0;j<16;j++){
    int m = mi[j];
    float w = e[j]*inv;
    unsigned vv = *(const unsigned*)(V + ((size_t)(b<<12) + m)*128 + c0);
    float rx = xn - xb[m];
    float ry = yn - xb[NP+m];
    float rz = zn - xb[2*NP+m];
    float p0 = wp00*rx + wp01*ry + wp02*rz;
    float p1 = wp10*rx + wp11*ry + wp12*rz;
    a0 += w*(bf2f((unsigned short)(vv & 0xffff)) + p0);
    a1 += w*(bf2f((unsigned short)(vv >> 16)) + p1);
  }
  unsigned pk = (unsigned)f2bf(a0) | ((unsigned)f2bf(a1) << 16);
  *(unsigned*)(agg + (size_t)t*128 + c0) = pk;
}

// ---------------- max/mean pool over tokens (two-stage) ----------------
// stage1 grid 512 (b*128 + cblk*8 + tseg), block 256 = 64 ch x 4 tg
__global__ __launch_bounds__(256) void pool_part(unsigned xfOff, unsigned gpOff)
{
  const unsigned short* xf = (const unsigned short*)(g_scratch + xfOff);
  float* gp = (float*)(g_scratch + gpOff);   // [b][seg][2][1024]
  int b = blockIdx.x >> 7, cblk = (blockIdx.x >> 3) & 15, seg = blockIdx.x & 7;
  int cl = threadIdx.x & 63, tg = threadIdx.x >> 6;
  int c = cblk*64 + cl;
  float mx = -3.0e38f, sm = 0.f;
  for (int n = seg*512 + tg; n < (seg+1)*512; n += 4){
    float v = bf2f(xf[((size_t)(b<<12) + n)*1024 + c]);
    mx = fmaxf(mx, v); sm += v;
  }
  __shared__ float smx[4][64], ssm[4][64];
  smx[tg][cl]=mx; ssm[tg][cl]=sm;
  __syncthreads();
  if (tg==0){
    #pragma unroll
    for (int k=1;k<4;k++){ mx = fmaxf(mx, smx[k][cl]); sm += ssm[k][cl]; }
    gp[((b*8 + seg)*2 + 0)*1024 + c] = mx;
    gp[((b*8 + seg)*2 + 1)*1024 + c] = sm;
  }
}
// stage2 grid 4 (b), block 256: each thread 4 channels
__global__ __launch_bounds__(256) void pool_final(unsigned gpOff, unsigned gOff)
{
  const float* gp = (const float*)(g_scratch + gpOff);
  float* g = (float*)(g_scratch + gOff);
  int b = blockIdx.x;
  for (int c = threadIdx.x; c < 1024; c += 256){
    float mx = -3.0e38f, sm = 0.f;
    #pragma unroll
    for (int seg=0; seg<8; ++seg){
      mx = fmaxf(mx, gp[((b*8 + seg)*2 + 0)*1024 + c]);
      sm += gp[((b*8 + seg)*2 + 1)*1024 + c];
    }
    g[b*2048 + c] = mx;
    g[b*2048 + 1024 + c] = sm * (1.f/4096.f);
  }
}

// gb[b][o] = cls_bias1[o] + sum_c W1[o][1024+c]*g[b][c]  (fp32; grid 8 x 256)
__global__ __launch_bounds__(256) void gterm_kernel(const float* __restrict__ w1,
                                                    const float* __restrict__ bias1,
                                                    unsigned gOff, unsigned gbOff)
{
  const float* g = (const float*)(g_scratch + gOff);
  float* gb = (float*)(g_scratch + gbOff);
  int b = blockIdx.x >> 1;
  int o = (blockIdx.x & 1)*256 + threadIdx.x;
  const float* wrow = w1 + (size_t)o*3072 + 1024;
  const float* gp = g + b*2048;
  float acc = 0.f;
  for (int c=0;c<2048;c+=4){
    float4 wv4 = *(const float4*)(wrow + c);
    acc += wv4.x*gp[c] + wv4.y*gp[c+1] + wv4.z*gp[c+2] + wv4.w*gp[c+3];
  }
  gb[b*512 + o] = acc + bias1[o];
}

// ---------------- classifier head (O=13), fp32 out ----------------
__global__ __launch_bounds__(256) void cls3_kernel(unsigned c2Off,
                                                   const float* __restrict__ w3,
                                                   const float* __restrict__ bias3,
                                                   float* __restrict__ outp)
{
  const unsigned short* c2 = (const unsigned short*)(g_scratch + c2Off);
  __shared__ float wf[13*256];
  __shared__ float bf3[13];
  for (int i=threadIdx.x;i<13*256;i+=256) wf[i]=w3[i];
  if (threadIdx.x < 13) bf3[threadIdx.x]=bias3[threadIdx.x];
  __syncthreads();
  int lane = threadIdx.x & 63, wv = threadIdx.x >> 6;
  int tl = lane >> 2, cq = lane & 3;
  int t = blockIdx.x*64 + wv*16 + tl;
  const unsigned short* xrow = c2 + (size_t)t*256 + cq*64;
  float acc[13];
  #pragma unroll
  for (int o=0;o<13;o++) acc[o]=0.f;
  for (int c=0;c<64;c+=8){
    short8 xv = *(const short8*)(xrow + c);
    float xs[8];
    #pragma unroll
    for (int u=0;u<8;u++) xs[u]=bf2f((unsigned short)xv[u]);
    #pragma unroll
    for (int o=0;o<13;o++){
      const float* wr = wf + o*256 + cq*64 + c;
      #pragma unroll
      for (int u=0;u<8;u++) acc[o] += wr[u]*xs[u];
    }
  }
  #pragma unroll
  for (int o=0;o<13;o++){
    acc[o] += __shfl_xor(acc[o], 1, 64);
    acc[o] += __shfl_xor(acc[o], 2, 64);
  }
  if (cq==0){
    int b = t >> 12, n = t & 4095;
    #pragma unroll
    for (int o=0;o<13;o++)
      outp[((size_t)b*13 + o)*NP + n] = acc[o] + bf3[o];
  }
}

// ---------------- launch ----------------
extern "C" void kernel_launch(void* const* d_in, const int* in_sizes, int n_in,
                              void* d_out, int out_size, void* d_ws, size_t ws_size,
                              hipStream_t stream) {
  (void)in_sizes; (void)n_in; (void)out_size; (void)d_ws; (void)ws_size;
  const float* in      = (const float*)d_in[0];
  const float* emb_w1  = (const float*)d_in[1];
  const float* emb_s1  = (const float*)d_in[2];
  const float* emb_b1  = (const float*)d_in[3];
  const float* emb_w2  = (const float*)d_in[4];
  const float* emb_s2  = (const float*)d_in[5];
  const float* emb_b2  = (const float*)d_in[6];
  const float* blk_wq  = (const float*)d_in[7];
  const float* blk_wk  = (const float*)d_in[8];
  const float* blk_wv  = (const float*)d_in[9];
  const float* blk_wpos= (const float*)d_in[10];
  const float* blk_wo  = (const float*)d_in[11];
  const float* blk_s   = (const float*)d_in[12];
  const float* blk_b   = (const float*)d_in[13];
  const float* fuse_w  = (const float*)d_in[14];
  const float* fuse_s  = (const float*)d_in[15];
  const float* fuse_b  = (const float*)d_in[16];
  const float* cls_w1  = (const float*)d_in[17];
  const float* cls_b1  = (const float*)d_in[18];
  const float* cls_s1  = (const float*)d_in[19];
  const float* cls_sh1 = (const float*)d_in[20];
  const float* cls_w2  = (const float*)d_in[21];
  const float* cls_b2  = (const float*)d_in[22];
  const float* cls_s2  = (const float*)d_in[23];
  const float* cls_sh2 = (const float*)d_in[24];
  const float* cls_w3  = (const float*)d_in[25];
  const float* cls_b3  = (const float*)d_in[26];

  // byte offsets into g_scratch (non-aliased)
  const unsigned MB = 1u<<20, KB = 1024u;
  const unsigned OFF_IDX   = 0;                 // 1 MB   int idx[T][16]
  const unsigned OFF_WQ    = 1*MB;              // 96 KB  bf16 (3,128,128)
  const unsigned OFF_WK    = 1*MB + 128*KB;     // 96 KB
  const unsigned OFF_WV    = 1*MB + 256*KB;     // 96 KB
  const unsigned OFF_WO    = 1*MB + 384*KB;     // 96 KB
  const unsigned OFF_WEMB2 = 1*MB + 512*KB;     // 32 KB  bf16 (128,128)
  const unsigned OFF_WFUSE = 1*MB + 576*KB;     // 768 KB bf16 (1024,384)
  const unsigned OFF_WW1   = 3*MB;              // 1 MB   bf16 (512,1024) x-half
  const unsigned OFF_WW2   = 4*MB;              // 256 KB bf16 (256,512)
  const unsigned OFF_X1    = 5*MB;              // 4 MB   bf16 (T,128)
  const unsigned OFF_X0    = 9*MB;              // 4 MB   bf16 (T,128)
  const unsigned OFF_XCAT  = 13*MB;             // 12 MB  bf16 (T,384)
  const unsigned OFF_QB    = 25*MB;             // 4 MB
  const unsigned OFF_KB    = 29*MB;             // 4 MB
  const unsigned OFF_VB    = 33*MB;             // 4 MB
  const unsigned OFF_AGG   = 37*MB;             // 4 MB
  const unsigned OFF_XF    = 41*MB;             // 32 MB  bf16 (T,1024)
  const unsigned OFF_C1    = 73*MB;             // 16 MB  bf16 (T,512)
  const unsigned OFF_C2    = 89*MB;             // 8 MB   bf16 (T,256)
  const unsigned OFF_G     = 97*MB;             // 32 KB  f32 (B,2048)
  const unsigned OFF_GB    = 97*MB + 64*KB;     // 8 KB   f32 (B,512)
  const unsigned OFF_GP    = 97*MB + 128*KB;    // 256 KB f32 pool partials
  const unsigned OFF_PK    = 98*MB;             // 32 MB  u64 knn keys (B,16,NP,16)
  float* outp = (float*)d_out;                  // (B,13,N) f32

  // 0: weight conversion prepass (fp32 -> bf16 into scratch)
  cvt_flat<<<dim3(64), 256, 0, stream>>>(emb_w2, OFF_WEMB2, 128*128);
  cvt_flat<<<dim3(192), 256, 0, stream>>>(blk_wq, OFF_WQ, 3*128*128);
  cvt_flat<<<dim3(192), 256, 0, stream>>>(blk_wk, OFF_WK, 3*128*128);
  cvt_flat<<<dim3(192), 256, 0, stream>>>(blk_wv, OFF_WV, 3*128*128);
  cvt_flat<<<dim3(192), 256, 0, stream>>>(blk_wo, OFF_WO, 3*128*128);
  cvt_flat<<<dim3(256), 256, 0, stream>>>(fuse_w, OFF_WFUSE, 1024*384);
  cvt_pitch1024<<<dim3(256), 256, 0, stream>>>(cls_w1, OFF_WW1, 512*1024);
  cvt_flat<<<dim3(256), 256, 0, stream>>>(cls_w2, OFF_WW2, 256*512);

  // 1-2: KNN
  knn_scan<<<dim3(16,16,4), 256, 0, stream>>>(in, OFF_PK);
  knn_merge<<<dim3(256), 64, 0, stream>>>(OFF_PK, OFF_IDX);
  // 3-4: embedding
  emb1_kernel<<<dim3(64), 256, 0, stream>>>(in, emb_w1, emb_s1, emb_b1, OFF_X1);
  gemm_tok<EPI_RELU_SB,false><<<dim3(1,128,1), 256, 0, stream>>>(
      OFF_WEMB2, OFF_WEMB2, OFF_WEMB2, OFF_X0, OFF_X0, OFF_X0,
      OFF_X1, 128, 0, 128, 0, emb_s2, emb_b2,
      nullptr, 0, 0, 0, 0, 0, 128, 128);
  // 5-7: transformer blocks
  for (int i=0;i<3;i++){
    unsigned wq = OFF_WQ + i*32768, wk = OFF_WK + i*32768;
    unsigned wv = OFF_WV + i*32768, wo = OFF_WO + i*32768;
    const float* wp = blk_wpos + i*128*3;
    const float* si = blk_s + i*128;
    const float* bi = blk_b + i*128;
    unsigned XiOff = (i==0) ? OFF_X0 : OFF_XCAT;
    int Xs = (i==0) ? 128 : 384;
    int Xo = (i==0) ? 0 : (i-1)*128;
    gemm_tok<EPI_PLAIN,false><<<dim3(1,128,3), 256, 0, stream>>>(
        wq, wk, wv, OFF_QB, OFF_KB, OFF_VB,
        XiOff, Xs, Xo, 128, 0, nullptr, nullptr,
        nullptr, 0, 0, 0, 0, 0, 128, 128);
    attn_kernel<<<dim3(4096), 256, 0, stream>>>(OFF_QB, OFF_KB, OFF_VB, OFF_IDX, in, wp, OFF_AGG);
    gemm_tok<EPI_RES,false><<<dim3(1,128,1), 256, 0, stream>>>(
        wo, wo, wo, OFF_XCAT, OFF_XCAT, OFF_XCAT,
        OFF_AGG, 128, 0, 384, i*128, si, bi,
        nullptr, 0, 0, XiOff, Xs, Xo, 128, 128);
  }
  // 8: fuse (leaky relu)
  gemm_tok<EPI_LEAKY,false><<<dim3(8,128,1), 256, 0, stream>>>(
      OFF_WFUSE, OFF_WFUSE, OFF_WFUSE, OFF_XF, OFF_XF, OFF_XF,
      OFF_XCAT, 384, 0, 1024, 0, fuse_s, fuse_b,
      nullptr, 0, 0, 0, 0, 0, 384, 384);
  // 9-10: pooling (two-stage) + broadcast-g term of cls1 (fp32)
  pool_part<<<dim3(512), 256, 0, stream>>>(OFF_XF, OFF_GP);
  pool_final<<<dim3(4), 256, 0, stream>>>(OFF_GP, OFF_G);
  gterm_kernel<<<dim3(8), 256, 0, stream>>>(cls_w1, cls_b1, OFF_G, OFF_GB);
  // 11: cls1 (K=1024 x-half of W1; gb = W1[:,1024:]@g + bias1 as extra)
  gemm_tok<EPI_CLS,false><<<dim3(4,128,1), 256, 0, stream>>>(
      OFF_WW1, OFF_WW1, OFF_WW1, OFF_C1, OFF_C1, OFF_C1,
      OFF_XF, 1024, 0, 512, 0, cls_s1, cls_sh1,
      nullptr, OFF_GB, 512, 0, 0, 0, 1024, 1024);
  // 12: cls2
  gemm_tok<EPI_CLS,true><<<dim3(2,128,1), 256, 0, stream>>>(
      OFF_WW2, OFF_WW2, OFF_WW2, OFF_C2, OFF_C2, OFF_C2,
      OFF_C1, 512, 0, 256, 0, cls_s2, cls_sh2,
      cls_b2, 0, 0, 0, 0, 0, 512, 512);
  // 13: cls3 -> d_out (fp32)
  cls3_kernel<<<dim3(256), 256, 0, stream>>>(OFF_C2, cls_w3, cls_b3, outp);
}

// Round 8
// 782.088 us; speedup vs baseline: 1.4698x; 1.0369x over previous
//
#include <hip/hip_runtime.h>

// PVDST semseg, MI355X/gfx950. FP32 I/O. Round-8: KNN 32-bit insert.
//   - R7 post-mortem: u64 keys cost ~212 VALU/candidate because gfx950 has
//     NO 64-bit integer VOPC compares (emulated, ~5 instr each) -> each u64
//     min/max ~7 instr. Fix: fp32 dists (native v_min/max_f32, 1 instr) +
//     int32 idx via v_cmp_lt_f32 + 2 cndmask, <=2 live predicates,
//     descending-order scalar macro. ~90 VALU/candidate.
//   - Tie semantics: strict <, ascending candidate/chunk order => lower
//     index first (numpy-stable); min/max identity is duplicate-safe.
//   - 8 cvt launches fused into 1.
// Rest unchanged from R7 (passed, absmax 2.9e-3).

#define NB 4
#define NP 4096
#define NT 16384   // NB*NP tokens

#define SCRATCH_BYTES (132u*1024u*1024u)
__device__ __align__(256) unsigned char g_scratch[SCRATCH_BYTES];

typedef __attribute__((ext_vector_type(8))) short short8;   // 8 x bf16 MFMA frag
typedef __attribute__((ext_vector_type(4))) float f32x4;    // MFMA acc
typedef __attribute__((ext_vector_type(4))) unsigned short ushort4v;

__device__ __forceinline__ float bf2f(unsigned short u){
  unsigned int v = ((unsigned int)u) << 16;
  return __builtin_bit_cast(float, v);
}
__device__ __forceinline__ unsigned short f2bf(float f){
  unsigned int x = __builtin_bit_cast(unsigned int, f);
  x += 0x7fffu + ((x >> 16) & 1u);     // RNE
  return (unsigned short)(x >> 16);
}
// numpy-matched: ((x*x)+(y*y))+(z*z), each op rounded (no fma contraction)
__device__ __forceinline__ float sq3(float x, float y, float z){
  return __fadd_rn(__fadd_rn(__fmul_rn(x,x), __fmul_rn(y,y)), __fmul_rn(z,z));
}

// 16-entry sorted-ascending (dist,idx) insert, all 32-bit scalars.
// dist via duplicate-safe min/max identity (native f32 min/max); idx via
// 2 cndmask on c_j = d < d_j (strict < => incumbent/lower index wins ties).
// Descending update order keeps old lower-slot values live as needed.
#define KDECL float d0=3.0e38f,d1=3.0e38f,d2=3.0e38f,d3=3.0e38f,d4=3.0e38f,\
  d5=3.0e38f,d6=3.0e38f,d7=3.0e38f,d8=3.0e38f,d9=3.0e38f,d10=3.0e38f,\
  d11=3.0e38f,d12=3.0e38f,d13=3.0e38f,d14=3.0e38f,d15=3.0e38f;\
  int i0=0,i1=0,i2=0,i3=0,i4=0,i5=0,i6=0,i7=0,i8=0,i9=0,i10=0,i11=0,\
  i12=0,i13=0,i14=0,i15=0
#define KINS(dd,mm) do{ float _d=(dd); int _m=(mm); \
  bool c15 = _d < d15; \
  bool c14 = _d < d14;  i15 = c14 ? i14 : (c15 ? _m : i15);  d15 = fminf(fmaxf(d14,_d), d15); \
  bool c13 = _d < d13;  i14 = c13 ? i13 : (c14 ? _m : i14);  d14 = fminf(fmaxf(d13,_d), d14); \
  bool c12 = _d < d12;  i13 = c12 ? i12 : (c13 ? _m : i13);  d13 = fminf(fmaxf(d12,_d), d13); \
  bool c11 = _d < d11;  i12 = c11 ? i11 : (c12 ? _m : i12);  d12 = fminf(fmaxf(d11,_d), d12); \
  bool c10 = _d < d10;  i11 = c10 ? i10 : (c11 ? _m : i11);  d11 = fminf(fmaxf(d10,_d), d11); \
  bool c9  = _d < d9;   i10 = c9  ? i9  : (c10 ? _m : i10);  d10 = fminf(fmaxf(d9 ,_d), d10); \
  bool c8  = _d < d8;   i9  = c8  ? i8  : (c9  ? _m : i9 );  d9  = fminf(fmaxf(d8 ,_d), d9 ); \
  bool c7  = _d < d7;   i8  = c7  ? i7  : (c8  ? _m : i8 );  d8  = fminf(fmaxf(d7 ,_d), d8 ); \
  bool c6  = _d < d6;   i7  = c6  ? i6  : (c7  ? _m : i7 );  d7  = fminf(fmaxf(d6 ,_d), d7 ); \
  bool c5  = _d < d5;   i6  = c5  ? i5  : (c6  ? _m : i6 );  d6  = fminf(fmaxf(d5 ,_d), d6 ); \
  bool c4  = _d < d4;   i5  = c4  ? i4  : (c5  ? _m : i5 );  d5  = fminf(fmaxf(d4 ,_d), d5 ); \
  bool c3  = _d < d3;   i4  = c3  ? i3  : (c4  ? _m : i4 );  d4  = fminf(fmaxf(d3 ,_d), d4 ); \
  bool c2  = _d < d2;   i3  = c2  ? i2  : (c3  ? _m : i3 );  d3  = fminf(fmaxf(d2 ,_d), d3 ); \
  bool c1  = _d < d1;   i2  = c1  ? i1  : (c2  ? _m : i2 );  d2  = fminf(fmaxf(d1 ,_d), d2 ); \
  bool c0  = _d < d0;   i1  = c0  ? i0  : (c1  ? _m : i1 );  d1  = fminf(fmaxf(d0 ,_d), d1 ); \
  i0 = c0 ? _m : i0;  d0 = fminf(d0,_d); }while(0)
#define KSTORED(p,o) do{ (p)[(o)+0]=d0;(p)[(o)+1]=d1;(p)[(o)+2]=d2;(p)[(o)+3]=d3;\
  (p)[(o)+4]=d4;(p)[(o)+5]=d5;(p)[(o)+6]=d6;(p)[(o)+7]=d7;\
  (p)[(o)+8]=d8;(p)[(o)+9]=d9;(p)[(o)+10]=d10;(p)[(o)+11]=d11;\
  (p)[(o)+12]=d12;(p)[(o)+13]=d13;(p)[(o)+14]=d14;(p)[(o)+15]=d15; }while(0)
#define KSTOREI(p,o) do{ (p)[(o)+0]=i0;(p)[(o)+1]=i1;(p)[(o)+2]=i2;(p)[(o)+3]=i3;\
  (p)[(o)+4]=i4;(p)[(o)+5]=i5;(p)[(o)+6]=i6;(p)[(o)+7]=i7;\
  (p)[(o)+8]=i8;(p)[(o)+9]=i9;(p)[(o)+10]=i10;(p)[(o)+11]=i11;\
  (p)[(o)+12]=i12;(p)[(o)+13]=i13;(p)[(o)+14]=i14;(p)[(o)+15]=i15; }while(0)

// ---------------- fused weight fp32 -> bf16 conversion prepass ----------------
struct CvtArgs {
  const float* src[8];
  unsigned dstOff[8];
  int n[8];
};
// grid (64, 8): y selects weight; y==7 is cls_w1 x-half (pitch 3072, 1024 cols)
__global__ __launch_bounds__(256) void cvt_all(CvtArgs a)
{
  int y = blockIdx.y;
  const float* src = a.src[y];
  unsigned short* dst = (unsigned short*)(g_scratch + a.dstOff[y]);
  int n = a.n[y];
  if (y == 7){
    for (int i = blockIdx.x*256 + threadIdx.x; i < n; i += gridDim.x*256){
      int r = i >> 10, c = i & 1023;
      dst[i] = f2bf(src[(size_t)r*3072 + c]);
    }
  } else {
    for (int i = blockIdx.x*256 + threadIdx.x; i < n; i += gridDim.x*256)
      dst[i] = f2bf(src[i]);
  }
}

// ---------------- KNN (exact fp32, 32-bit state) ----------------
// grid (16 qchunks, 16 cchunks, B), block 256. One thread = one query vs 256
// candidates staged in LDS as float4(x,y,z,sq). 1024 blocks -> 4/CU.
__global__ __launch_bounds__(256) void knn_scan(const float* __restrict__ in,
                                                unsigned pdOff, unsigned piOff)
{
  float* pdist = (float*)(g_scratch + pdOff);
  int*   pidx  = (int*)  (g_scratch + piOff);
  __shared__ float4 sp[256];
  int b = blockIdx.z, qc = blockIdx.x, cc = blockIdx.y;
  const float* xb = in + (size_t)b*9*NP;
  int base = cc*256;
  {
    int i = threadIdx.x;
    float x = xb[base+i], y = xb[NP+base+i], z = xb[2*NP+base+i];
    sp[i] = make_float4(x,y,z,sq3(x,y,z));
  }
  __syncthreads();
  int n = qc*256 + threadIdx.x;
  float xn=xb[n], yn=xb[NP+n], zn=xb[2*NP+n];
  float sqn = sq3(xn,yn,zn);
  KDECL;
  for (int mm=0; mm<256; ++mm){
    float4 p = sp[mm];
    float dot = __fadd_rn(__fadd_rn(__fmul_rn(xn,p.x), __fmul_rn(yn,p.y)), __fmul_rn(zn,p.z));
    float d = __fsub_rn(__fadd_rn(sqn, p.w), __fmul_rn(2.0f, dot));
    KINS(d, base+mm);
  }
  size_t o = ((size_t)((b*16 + cc)*NP + n))*16;
  KSTORED(pdist, o);
  KSTOREI(pidx, o);
}

// grid 256 x 64: merge 16 sorted chunk lists per query. Early-break: sorted
// list whose next dist >= current 16th cannot contribute.
__global__ __launch_bounds__(64) void knn_merge(unsigned pdOff, unsigned piOff, unsigned idxOff)
{
  const float* pdist = (const float*)(g_scratch + pdOff);
  const int*   pidx  = (const int*)  (g_scratch + piOff);
  int*         idxOut= (int*)(g_scratch + idxOff);
  int t = blockIdx.x*64 + threadIdx.x;
  int b = t >> 12, n = t & 4095;
  KDECL;
  for (int cc=0; cc<16; ++cc){
    size_t o = ((size_t)((b*16 + cc)*NP + n))*16;
    #pragma unroll 1
    for (int j=0;j<16;j++){
      float pd = pdist[o+j];
      if (pd >= d15) break;
      KINS(pd, pidx[o+j]);
    }
  }
  idxOut[t*16+ 0]=i0;  idxOut[t*16+ 1]=i1;  idxOut[t*16+ 2]=i2;  idxOut[t*16+ 3]=i3;
  idxOut[t*16+ 4]=i4;  idxOut[t*16+ 5]=i5;  idxOut[t*16+ 6]=i6;  idxOut[t*16+ 7]=i7;
  idxOut[t*16+ 8]=i8;  idxOut[t*16+ 9]=i9;  idxOut[t*16+10]=i10; idxOut[t*16+11]=i11;
  idxOut[t*16+12]=i12; idxOut[t*16+13]=i13; idxOut[t*16+14]=i14; idxOut[t*16+15]=i15;
}

// ---------------- embedding conv1 (Cin=9), fp32 in -> bf16 out ----------------
__global__ __launch_bounds__(256) void emb1_kernel(const float* __restrict__ in,
                                                   const float* __restrict__ w1,
                                                   const float* __restrict__ s1,
                                                   const float* __restrict__ b1,
                                                   unsigned x1Off)
{
  unsigned short* x1 = (unsigned short*)(g_scratch + x1Off);
  __shared__ float wf[128*9], sf[128], bf_[128];
  for (int i=threadIdx.x;i<128*9;i+=256) wf[i]=w1[i];
  if (threadIdx.x < 128){ sf[threadIdx.x]=s1[threadIdx.x]; bf_[threadIdx.x]=b1[threadIdx.x]; }
  __syncthreads();
  int t = blockIdx.x*256 + threadIdx.x;
  int b = t >> 12, n = t & 4095;
  float v[9];
  #pragma unroll
  for (int c=0;c<9;c++) v[c] = in[((size_t)b*9 + c)*NP + n];
  for (int o=0;o<128;o+=2){
    float a0=0.f, a1=0.f;
    #pragma unroll
    for (int c=0;c<9;c++){ a0 += wf[o*9+c]*v[c]; a1 += wf[(o+1)*9+c]*v[c]; }
    a0 = fmaxf(sf[o]*a0 + bf_[o], 0.f);
    a1 = fmaxf(sf[o+1]*a1 + bf_[o+1], 0.f);
    unsigned pk = (unsigned)f2bf(a0) | ((unsigned)f2bf(a1) << 16);
    *(unsigned*)(x1 + (size_t)t*128 + o) = pk;
  }
}

// ---------------- generic token-major MFMA GEMM (bf16 in/out) ----------------
enum { EPI_PLAIN=0, EPI_RELU_SB=1, EPI_RES=2, EPI_LEAKY=3, EPI_CLS=4 };

template<int EPI, bool EXB>
__global__ __launch_bounds__(256) void gemm_tok(
    unsigned W0off, unsigned W1off, unsigned W2off,
    unsigned O0off, unsigned O1off, unsigned O2off,
    unsigned XoffB, int Xstride, int Xoff,
    int outStride, int outOff,
    const float* sPtr, const float* bPtr,
    const float* extraIn, unsigned extraOffB, int extraStride,
    unsigned resOffB, int resStride, int resOff,
    int K, int Astride)
{
  const unsigned short* X = (const unsigned short*)(g_scratch + XoffB);
  unsigned wOffB   = (blockIdx.z==0) ? W0off : ((blockIdx.z==1) ? W1off : W2off);
  unsigned outOffB = (blockIdx.z==0) ? O0off : ((blockIdx.z==1) ? O1off : O2off);
  const unsigned short* W = (const unsigned short*)(g_scratch + wOffB);
  unsigned short* out = (unsigned short*)(g_scratch + outOffB);
  int lane = threadIdx.x & 63, wave = threadIdx.x >> 6;
  int r = lane & 15, q = lane >> 4;
  int M0 = blockIdx.x*128 + (wave>>1)*64;
  int T0 = blockIdx.y*128 + (wave&1)*64;

  f32x4 acc[4][4];
  #pragma unroll
  for (int i=0;i<4;i++)
    #pragma unroll
    for (int j=0;j<4;j++)
      #pragma unroll
      for (int u=0;u<4;u++) acc[i][j][u] = 0.f;

  const unsigned short* Arow[4]; const unsigned short* Brow[4];
  #pragma unroll
  for (int i=0;i<4;i++) Arow[i] = W + (size_t)(M0 + i*16 + r)*Astride + q*8;
  #pragma unroll
  for (int j=0;j<4;j++) Brow[j] = X + (size_t)(T0 + j*16 + r)*Xstride + Xoff + q*8;

  for (int k0=0; k0<K; k0+=32){
    short8 a[4], bfr[4];
    #pragma unroll
    for (int i=0;i<4;i++) a[i]   = *(const short8*)(Arow[i] + k0);
    #pragma unroll
    for (int j=0;j<4;j++) bfr[j] = *(const short8*)(Brow[j] + k0);
    #pragma unroll
    for (int i=0;i<4;i++)
      #pragma unroll
      for (int j=0;j<4;j++)
        acc[i][j] = __builtin_amdgcn_mfma_f32_16x16x32_bf16(a[i], bfr[j], acc[i][j], 0, 0, 0);
  }

  // epilogue: D layout col=lane&15 (token), row=q*4+reg (channel)
  #pragma unroll
  for (int i=0;i<4;i++){
    int m = M0 + i*16 + q*4;
    float sv[4], bv[4];
    if constexpr (EPI != EPI_PLAIN){
      #pragma unroll
      for (int u=0;u<4;u++){ sv[u]=sPtr[m+u]; bv[u]=bPtr[m+u]; }
    }
    #pragma unroll
    for (int j=0;j<4;j++){
      int token = T0 + j*16 + r;
      float ex[4];
      if constexpr (EPI == EPI_CLS){
        int bb = token >> 12;
        #pragma unroll
        for (int u=0;u<4;u++)
          ex[u] = EXB ? extraIn[bb*extraStride + m + u]
                      : ((const float*)(g_scratch + extraOffB))[bb*extraStride + m + u];
      }
      float resv[4];
      if constexpr (EPI == EPI_RES){
        const unsigned short* resPtr = (const unsigned short*)(g_scratch + resOffB);
        ushort4v rv = *(const ushort4v*)(resPtr + (size_t)token*resStride + resOff + m);
        #pragma unroll
        for (int u=0;u<4;u++) resv[u]=bf2f(rv[u]);
      }
      ushort4v ov;
      #pragma unroll
      for (int u=0;u<4;u++){
        float a = acc[i][j][u];
        float vo;
        if constexpr (EPI == EPI_PLAIN)        vo = a;
        else if constexpr (EPI == EPI_RELU_SB) vo = fmaxf(sv[u]*a + bv[u], 0.f);
        else if constexpr (EPI == EPI_RES)     vo = resv[u] + fmaxf(sv[u]*a + bv[u], 0.f);
        else if constexpr (EPI == EPI_LEAKY){  float tt = sv[u]*a + bv[u]; vo = tt>0.f ? tt : 0.2f*tt; }
        else { /*EPI_CLS: relu(s*(acc+extra)+sh), bPtr=sh*/ vo = fmaxf(sv[u]*(a + ex[u]) + bv[u], 0.f); }
        ov[u] = f2bf(vo);
      }
      *(ushort4v*)(out + (size_t)token*outStride + outOff + m) = ov;
    }
  }
}

// ---------------- attention (one wave per query, 2 channels/lane) ----------------
__global__ __launch_bounds__(256) void attn_kernel(
  unsigned qOff, unsigned kOff, unsigned vOff, unsigned idxOff,
  const float* __restrict__ in, const float* __restrict__ wpos,
  unsigned aggOff)
{
  const unsigned short* Q  = (const unsigned short*)(g_scratch + qOff);
  const unsigned short* Kf = (const unsigned short*)(g_scratch + kOff);
  const unsigned short* V  = (const unsigned short*)(g_scratch + vOff);
  const int* idx           = (const int*)(g_scratch + idxOff);
  unsigned short* agg      = (unsigned short*)(g_scratch + aggOff);

  int lane = threadIdx.x & 63, wv = threadIdx.x >> 6;
  int t = blockIdx.x*4 + wv;
  int b = t >> 12, n = t & 4095;
  const float* xb = in + (size_t)b*9*NP;
  int c0 = lane*2;

  unsigned qv = *(const unsigned*)(Q + (size_t)t*128 + c0);
  float q0 = bf2f((unsigned short)(qv & 0xffff)), q1 = bf2f((unsigned short)(qv >> 16));
  float xn = xb[n], yn = xb[NP+n], zn = xb[2*NP+n];
  float wp00=wpos[c0*3+0],     wp01=wpos[c0*3+1],     wp02=wpos[c0*3+2];
  float wp10=wpos[(c0+1)*3+0], wp11=wpos[(c0+1)*3+1], wp12=wpos[(c0+1)*3+2];

  int mi[16]; float s[16];
  #pragma unroll
  for (int j=0;j<16;j++) mi[j] = idx[(size_t)t*16 + j] & 4095;  // mask: never OOB
  #pragma unroll
  for (int j=0;j<16;j++){
    unsigned kv = *(const unsigned*)(Kf + ((size_t)(b<<12) + mi[j])*128 + c0);
    float p = q0*bf2f((unsigned short)(kv & 0xffff)) + q1*bf2f((unsigned short)(kv >> 16));
    #pragma unroll
    for (int o=32;o>=1;o>>=1) p += __shfl_xor(p, o, 64);
    s[j] = p;
  }
  const float scale = 0.08838834764831845f; // 1/sqrt(128)
  float mx = s[0];
  #pragma unroll
  for (int j=1;j<16;j++) mx = fmaxf(mx, s[j]);
  float e[16], sum = 0.f;
  #pragma unroll
  for (int j=0;j<16;j++){ e[j] = __expf((s[j]-mx)*scale); sum += e[j]; }
  float inv = 1.f / sum;

  float a0=0.f, a1=0.f;
  #pragma unroll
  for (int j=0;j<16;j++){
    int m = mi[j];
    float w = e[j]*inv;
    unsigned vv = *(const unsigned*)(V + ((size_t)(b<<12) + m)*128 + c0);
    float rx = xn - xb[m];
    float ry = yn - xb[NP+m];
    float rz = zn - xb[2*NP+m];
    float p0 = wp00*rx + wp01*ry + wp02*rz;
    float p1 = wp10*rx + wp11*ry + wp12*rz;
    a0 += w*(bf2f((unsigned short)(vv & 0xffff)) + p0);
    a1 += w*(bf2f((unsigned short)(vv >> 16)) + p1);
  }
  unsigned pk = (unsigned)f2bf(a0) | ((unsigned)f2bf(a1) << 16);
  *(unsigned*)(agg + (size_t)t*128 + c0) = pk;
}

// ---------------- max/mean pool over tokens (two-stage) ----------------
// stage1 grid 512 (b*128 + cblk*8 + tseg), block 256 = 64 ch x 4 tg
__global__ __launch_bounds__(256) void pool_part(unsigned xfOff, unsigned gpOff)
{
  const unsigned short* xf = (const unsigned short*)(g_scratch + xfOff);
  float* gp = (float*)(g_scratch + gpOff);   // [b][seg][2][1024]
  int b = blockIdx.x >> 7, cblk = (blockIdx.x >> 3) & 15, seg = blockIdx.x & 7;
  int cl = threadIdx.x & 63, tg = threadIdx.x >> 6;
  int c = cblk*64 + cl;
  float mx = -3.0e38f, sm = 0.f;
  for (int n = seg*512 + tg; n < (seg+1)*512; n += 4){
    float v = bf2f(xf[((size_t)(b<<12) + n)*1024 + c]);
    mx = fmaxf(mx, v); sm += v;
  }
  __shared__ float smx[4][64], ssm[4][64];
  smx[tg][cl]=mx; ssm[tg][cl]=sm;
  __syncthreads();
  if (tg==0){
    #pragma unroll
    for (int k=1;k<4;k++){ mx = fmaxf(mx, smx[k][cl]); sm += ssm[k][cl]; }
    gp[((b*8 + seg)*2 + 0)*1024 + c] = mx;
    gp[((b*8 + seg)*2 + 1)*1024 + c] = sm;
  }
}
// stage2 grid 4 (b), block 256: each thread 4 channels
__global__ __launch_bounds__(256) void pool_final(unsigned gpOff, unsigned gOff)
{
  const float* gp = (const float*)(g_scratch + gpOff);
  float* g = (float*)(g_scratch + gOff);
  int b = blockIdx.x;
  for (int c = threadIdx.x; c < 1024; c += 256){
    float mx = -3.0e38f, sm = 0.f;
    #pragma unroll
    for (int seg=0; seg<8; ++seg){
      mx = fmaxf(mx, gp[((b*8 + seg)*2 + 0)*1024 + c]);
      sm += gp[((b*8 + seg)*2 + 1)*1024 + c];
    }
    g[b*2048 + c] = mx;
    g[b*2048 + 1024 + c] = sm * (1.f/4096.f);
  }
}

// gb[b][o] = cls_bias1[o] + sum_c W1[o][1024+c]*g[b][c]  (fp32; grid 8 x 256)
__global__ __launch_bounds__(256) void gterm_kernel(const float* __restrict__ w1,
                                                    const float* __restrict__ bias1,
                                                    unsigned gOff, unsigned gbOff)
{
  const float* g = (const float*)(g_scratch + gOff);
  float* gb = (float*)(g_scratch + gbOff);
  int b = blockIdx.x >> 1;
  int o = (blockIdx.x & 1)*256 + threadIdx.x;
  const float* wrow = w1 + (size_t)o*3072 + 1024;
  const float* gp = g + b*2048;
  float acc = 0.f;
  for (int c=0;c<2048;c+=4){
    float4 wv4 = *(const float4*)(wrow + c);
    acc += wv4.x*gp[c] + wv4.y*gp[c+1] + wv4.z*gp[c+2] + wv4.w*gp[c+3];
  }
  gb[b*512 + o] = acc + bias1[o];
}

// ---------------- classifier head (O=13), fp32 out ----------------
__global__ __launch_bounds__(256) void cls3_kernel(unsigned c2Off,
                                                   const float* __restrict__ w3,
                                                   const float* __restrict__ bias3,
                                                   float* __restrict__ outp)
{
  const unsigned short* c2 = (const unsigned short*)(g_scratch + c2Off);
  __shared__ float wf[13*256];
  __shared__ float bf3[13];
  for (int i=threadIdx.x;i<13*256;i+=256) wf[i]=w3[i];
  if (threadIdx.x < 13) bf3[threadIdx.x]=bias3[threadIdx.x];
  __syncthreads();
  int lane = threadIdx.x & 63, wv = threadIdx.x >> 6;
  int tl = lane >> 2, cq = lane & 3;
  int t = blockIdx.x*64 + wv*16 + tl;
  const unsigned short* xrow = c2 + (size_t)t*256 + cq*64;
  float acc[13];
  #pragma unroll
  for (int o=0;o<13;o++) acc[o]=0.f;
  for (int c=0;c<64;c+=8){
    short8 xv = *(const short8*)(xrow + c);
    float xs[8];
    #pragma unroll
    for (int u=0;u<8;u++) xs[u]=bf2f((unsigned short)xv[u]);
    #pragma unroll
    for (int o=0;o<13;o++){
      const float* wr = wf + o*256 + cq*64 + c;
      #pragma unroll
      for (int u=0;u<8;u++) acc[o] += wr[u]*xs[u];
    }
  }
  #pragma unroll
  for (int o=0;o<13;o++){
    acc[o] += __shfl_xor(acc[o], 1, 64);
    acc[o] += __shfl_xor(acc[o], 2, 64);
  }
  if (cq==0){
    int b = t >> 12, n = t & 4095;
    #pragma unroll
    for (int o=0;o<13;o++)
      outp[((size_t)b*13 + o)*NP + n] = acc[o] + bf3[o];
  }
}

// ---------------- launch ----------------
extern "C" void kernel_launch(void* const* d_in, const int* in_sizes, int n_in,
                              void* d_out, int out_size, void* d_ws, size_t ws_size,
                              hipStream_t stream) {
  (void)in_sizes; (void)n_in; (void)out_size; (void)d_ws; (void)ws_size;
  const float* in      = (const float*)d_in[0];
  const float* emb_w1  = (const float*)d_in[1];
  const float* emb_s1  = (const float*)d_in[2];
  const float* emb_b1  = (const float*)d_in[3];
  const float* emb_w2  = (const float*)d_in[4];
  const float* emb_s2  = (const float*)d_in[5];
  const float* emb_b2  = (const float*)d_in[6];
  const float* blk_wq  = (const float*)d_in[7];
  const float* blk_wk  = (const float*)d_in[8];
  const float* blk_wv  = (const float*)d_in[9];
  const float* blk_wpos= (const float*)d_in[10];
  const float* blk_wo  = (const float*)d_in[11];
  const float* blk_s   = (const float*)d_in[12];
  const float* blk_b   = (const float*)d_in[13];
  const float* fuse_w  = (const float*)d_in[14];
  const float* fuse_s  = (const float*)d_in[15];
  const float* fuse_b  = (const float*)d_in[16];
  const float* cls_w1  = (const float*)d_in[17];
  const float* cls_b1  = (const float*)d_in[18];
  const float* cls_s1  = (const float*)d_in[19];
  const float* cls_sh1 = (const float*)d_in[20];
  const float* cls_w2  = (const float*)d_in[21];
  const float* cls_b2  = (const float*)d_in[22];
  const float* cls_s2  = (const float*)d_in[23];
  const float* cls_sh2 = (const float*)d_in[24];
  const float* cls_w3  = (const float*)d_in[25];
  const float* cls_b3  = (const float*)d_in[26];

  // byte offsets into g_scratch (non-aliased)
  const unsigned MB = 1u<<20, KB = 1024u;
  const unsigned OFF_IDX   = 0;                 // 1 MB   int idx[T][16]
  const unsigned OFF_WQ    = 1*MB;              // 96 KB  bf16 (3,128,128)
  const unsigned OFF_WK    = 1*MB + 128*KB;     // 96 KB
  const unsigned OFF_WV    = 1*MB + 256*KB;     // 96 KB
  const unsigned OFF_WO    = 1*MB + 384*KB;     // 96 KB
  const unsigned OFF_WEMB2 = 1*MB + 512*KB;     // 32 KB  bf16 (128,128)
  const unsigned OFF_WFUSE = 1*MB + 576*KB;     // 768 KB bf16 (1024,384)
  const unsigned OFF_WW1   = 3*MB;              // 1 MB   bf16 (512,1024) x-half
  const unsigned OFF_WW2   = 4*MB;              // 256 KB bf16 (256,512)
  const unsigned OFF_X1    = 5*MB;              // 4 MB   bf16 (T,128)
  const unsigned OFF_X0    = 9*MB;              // 4 MB   bf16 (T,128)
  const unsigned OFF_XCAT  = 13*MB;             // 12 MB  bf16 (T,384)
  const unsigned OFF_QB    = 25*MB;             // 4 MB
  const unsigned OFF_KB    = 29*MB;             // 4 MB
  const unsigned OFF_VB    = 33*MB;             // 4 MB
  const unsigned OFF_AGG   = 37*MB;             // 4 MB
  const unsigned OFF_XF    = 41*MB;             // 32 MB  bf16 (T,1024)
  const unsigned OFF_C1    = 73*MB;             // 16 MB  bf16 (T,512)
  const unsigned OFF_C2    = 89*MB;             // 8 MB   bf16 (T,256)
  const unsigned OFF_G     = 97*MB;             // 32 KB  f32 (B,2048)
  const unsigned OFF_GB    = 97*MB + 64*KB;     // 8 KB   f32 (B,512)
  const unsigned OFF_GP    = 97*MB + 128*KB;    // 256 KB f32 pool partials
  const unsigned OFF_PD    = 98*MB;             // 16 MB  f32 knn partial dist (B,16,NP,16)
  const unsigned OFF_PI    = 114*MB;            // 16 MB  int knn partial idx
  float* outp = (float*)d_out;                  // (B,13,N) f32

  // 0: fused weight conversion prepass (fp32 -> bf16 into scratch)
  CvtArgs ca;
  ca.src[0]=emb_w2;  ca.dstOff[0]=OFF_WEMB2; ca.n[0]=128*128;
  ca.src[1]=blk_wq;  ca.dstOff[1]=OFF_WQ;    ca.n[1]=3*128*128;
  ca.src[2]=blk_wk;  ca.dstOff[2]=OFF_WK;    ca.n[2]=3*128*128;
  ca.src[3]=blk_wv;  ca.dstOff[3]=OFF_WV;    ca.n[3]=3*128*128;
  ca.src[4]=blk_wo;  ca.dstOff[4]=OFF_WO;    ca.n[4]=3*128*128;
  ca.src[5]=fuse_w;  ca.dstOff[5]=OFF_WFUSE; ca.n[5]=1024*384;
  ca.src[6]=cls_w2;  ca.dstOff[6]=OFF_WW2;   ca.n[6]=256*512;
  ca.src[7]=cls_w1;  ca.dstOff[7]=OFF_WW1;   ca.n[7]=512*1024;
  cvt_all<<<dim3(64,8), 256, 0, stream>>>(ca);

  // 1-2: KNN
  knn_scan<<<dim3(16,16,4), 256, 0, stream>>>(in, OFF_PD, OFF_PI);
  knn_merge<<<dim3(256), 64, 0, stream>>>(OFF_PD, OFF_PI, OFF_IDX);
  // 3-4: embedding
  emb1_kernel<<<dim3(64), 256, 0, stream>>>(in, emb_w1, emb_s1, emb_b1, OFF_X1);
  gemm_tok<EPI_RELU_SB,false><<<dim3(1,128,1), 256, 0, stream>>>(
      OFF_WEMB2, OFF_WEMB2, OFF_WEMB2, OFF_X0, OFF_X0, OFF_X0,
      OFF_X1, 128, 0, 128, 0, emb_s2, emb_b2,
      nullptr, 0, 0, 0, 0, 0, 128, 128);
  // 5-7: transformer blocks
  for (int i=0;i<3;i++){
    unsigned wq = OFF_WQ + i*32768, wk = OFF_WK + i*32768;
    unsigned wv = OFF_WV + i*32768, wo = OFF_WO + i*32768;
    const float* wp = blk_wpos + i*128*3;
    const float* si = blk_s + i*128;
    const float* bi = blk_b + i*128;
    unsigned XiOff = (i==0) ? OFF_X0 : OFF_XCAT;
    int Xs = (i==0) ? 128 : 384;
    int Xo = (i==0) ? 0 : (i-1)*128;
    gemm_tok<EPI_PLAIN,false><<<dim3(1,128,3), 256, 0, stream>>>(
        wq, wk, wv, OFF_QB, OFF_KB, OFF_VB,
        XiOff, Xs, Xo, 128, 0, nullptr, nullptr,
        nullptr, 0, 0, 0, 0, 0, 128, 128);
    attn_kernel<<<dim3(4096), 256, 0, stream>>>(OFF_QB, OFF_KB, OFF_VB, OFF_IDX, in, wp, OFF_AGG);
    gemm_tok<EPI_RES,false><<<dim3(1,128,1), 256, 0, stream>>>(
        wo, wo, wo, OFF_XCAT, OFF_XCAT, OFF_XCAT,
        OFF_AGG, 128, 0, 384, i*128, si, bi,
        nullptr, 0, 0, XiOff, Xs, Xo, 128, 128);
  }
  // 8: fuse (leaky relu)
  gemm_tok<EPI_LEAKY,false><<<dim3(8,128,1), 256, 0, stream>>>(
      OFF_WFUSE, OFF_WFUSE, OFF_WFUSE, OFF_XF, OFF_XF, OFF_XF,
      OFF_XCAT, 384, 0, 1024, 0, fuse_s, fuse_b,
      nullptr, 0, 0, 0, 0, 0, 384, 384);
  // 9-10: pooling (two-stage) + broadcast-g term of cls1 (fp32)
  pool_part<<<dim3(512), 256, 0, stream>>>(OFF_XF, OFF_GP);
  pool_final<<<dim3(4), 256, 0, stream>>>(OFF_GP, OFF_G);
  gterm_kernel<<<dim3(8), 256, 0, stream>>>(cls_w1, cls_b1, OFF_G, OFF_GB);
  // 11: cls1 (K=1024 x-half of W1; gb = W1[:,1024:]@g + bias1 as extra)
  gemm_tok<EPI_CLS,false><<<dim3(4,128,1), 256, 0, stream>>>(
      OFF_WW1, OFF_WW1, OFF_WW1, OFF_C1, OFF_C1, OFF_C1,
      OFF_XF, 1024, 0, 512, 0, cls_s1, cls_sh1,
      nullptr, OFF_GB, 512, 0, 0, 0, 1024, 1024);
  // 12: cls2
  gemm_tok<EPI_CLS,true><<<dim3(2,128,1), 256, 0, stream>>>(
      OFF_WW2, OFF_WW2, OFF_WW2, OFF_C2, OFF_C2, OFF_C2,
      OFF_C1, 512, 0, 256, 0, cls_s2, cls_sh2,
      cls_b2, 0, 0, 0, 0, 0, 512, 512);
  // 13: cls3 -> d_out (fp32)
  cls3_kernel<<<dim3(256), 256, 0, stream>>>(OFF_C2, cls_w3, cls_b3, outp);
}

// Round 10
// 748.555 us; speedup vs baseline: 1.5356x; 1.0448x over previous
//
#include <hip/hip_runtime.h>

// PVDST semseg, MI355X/gfx950. FP32 I/O. Round-10: fix R9's emb1 LDS bug.
//   - R9 failed (absmax 7.08): output-split emb1 loaded 288 LDS floats with
//     a single `if (tid < 288)` guard on a 256-thread block -> wf[256..287]
//     uninitialized -> channels og+28..31 garbage. Fix: strided load loop.
//   - KNN threshold two-pass (R9 design, re-audited correct): pass1 dist-only
//     min/max top-16 (no masks), thr = exact 16th-smallest, pass2 guarded
//     (d,i)-insert, sparse merge. Stability: strict < + ascending order.
//   - gemm_small (64Mx128T, 2-wave) for M=128/256 GEMMs; gterm 32 blocks.

#define NB 4
#define NP 4096
#define NT 16384   // NB*NP tokens

#define SCRATCH_BYTES (132u*1024u*1024u)
__device__ __align__(256) unsigned char g_scratch[SCRATCH_BYTES];

typedef __attribute__((ext_vector_type(8))) short short8;   // 8 x bf16 MFMA frag
typedef __attribute__((ext_vector_type(4))) float f32x4;    // MFMA acc
typedef __attribute__((ext_vector_type(4))) unsigned short ushort4v;

__device__ __forceinline__ float bf2f(unsigned short u){
  unsigned int v = ((unsigned int)u) << 16;
  return __builtin_bit_cast(float, v);
}
__device__ __forceinline__ unsigned short f2bf(float f){
  unsigned int x = __builtin_bit_cast(unsigned int, f);
  x += 0x7fffu + ((x >> 16) & 1u);     // RNE
  return (unsigned short)(x >> 16);
}
// numpy-matched: ((x*x)+(y*y))+(z*z), each op rounded (no fma contraction)
__device__ __forceinline__ float sq3(float x, float y, float z){
  return __fadd_rn(__fadd_rn(__fmul_rn(x,x), __fmul_rn(y,y)), __fmul_rn(z,z));
}

// dist-only sorted-ascending top-16: pure native min/max, no masks.
#define KDECLD float d0=3.0e38f,d1=3.0e38f,d2=3.0e38f,d3=3.0e38f,d4=3.0e38f,\
  d5=3.0e38f,d6=3.0e38f,d7=3.0e38f,d8=3.0e38f,d9=3.0e38f,d10=3.0e38f,\
  d11=3.0e38f,d12=3.0e38f,d13=3.0e38f,d14=3.0e38f,d15=3.0e38f
#define KINSD(dd) do{ float _d=(dd); \
  d15=fminf(fmaxf(d14,_d),d15); d14=fminf(fmaxf(d13,_d),d14); \
  d13=fminf(fmaxf(d12,_d),d13); d12=fminf(fmaxf(d11,_d),d12); \
  d11=fminf(fmaxf(d10,_d),d11); d10=fminf(fmaxf(d9 ,_d),d10); \
  d9 =fminf(fmaxf(d8 ,_d),d9 ); d8 =fminf(fmaxf(d7 ,_d),d8 ); \
  d7 =fminf(fmaxf(d6 ,_d),d7 ); d6 =fminf(fmaxf(d5 ,_d),d6 ); \
  d5 =fminf(fmaxf(d4 ,_d),d5 ); d4 =fminf(fmaxf(d3 ,_d),d4 ); \
  d3 =fminf(fmaxf(d2 ,_d),d3 ); d2 =fminf(fmaxf(d1 ,_d),d2 ); \
  d1 =fminf(fmaxf(d0 ,_d),d1 ); d0 =fminf(d0,_d); }while(0)

// full (dist,idx) insert (only on the rare qualifying path / merges)
#define KDECL KDECLD; int i0=0,i1=0,i2=0,i3=0,i4=0,i5=0,i6=0,i7=0,i8=0,\
  i9=0,i10=0,i11=0,i12=0,i13=0,i14=0,i15=0
#define KINS(dd,mm) do{ float _d=(dd); int _m=(mm); \
  bool c15 = _d < d15; \
  bool c14 = _d < d14;  i15 = c14 ? i14 : (c15 ? _m : i15);  d15 = fminf(fmaxf(d14,_d), d15); \
  bool c13 = _d < d13;  i14 = c13 ? i13 : (c14 ? _m : i14);  d14 = fminf(fmaxf(d13,_d), d14); \
  bool c12 = _d < d12;  i13 = c12 ? i12 : (c13 ? _m : i13);  d13 = fminf(fmaxf(d12,_d), d13); \
  bool c11 = _d < d11;  i12 = c11 ? i11 : (c12 ? _m : i12);  d12 = fminf(fmaxf(d11,_d), d12); \
  bool c10 = _d < d10;  i11 = c10 ? i10 : (c11 ? _m : i11);  d11 = fminf(fmaxf(d10,_d), d11); \
  bool c9  = _d < d9;   i10 = c9  ? i9  : (c10 ? _m : i10);  d10 = fminf(fmaxf(d9 ,_d), d10); \
  bool c8  = _d < d8;   i9  = c8  ? i8  : (c9  ? _m : i9 );  d9  = fminf(fmaxf(d8 ,_d), d9 ); \
  bool c7  = _d < d7;   i8  = c7  ? i7  : (c8  ? _m : i8 );  d8  = fminf(fmaxf(d7 ,_d), d8 ); \
  bool c6  = _d < d6;   i7  = c6  ? i6  : (c7  ? _m : i7 );  d7  = fminf(fmaxf(d6 ,_d), d7 ); \
  bool c5  = _d < d5;   i6  = c5  ? i5  : (c6  ? _m : i6 );  d6  = fminf(fmaxf(d5 ,_d), d6 ); \
  bool c4  = _d < d4;   i5  = c4  ? i4  : (c5  ? _m : i5 );  d5  = fminf(fmaxf(d4 ,_d), d5 ); \
  bool c3  = _d < d3;   i4  = c3  ? i3  : (c4  ? _m : i4 );  d4  = fminf(fmaxf(d3 ,_d), d4 ); \
  bool c2  = _d < d2;   i3  = c2  ? i2  : (c3  ? _m : i3 );  d3  = fminf(fmaxf(d2 ,_d), d3 ); \
  bool c1  = _d < d1;   i2  = c1  ? i1  : (c2  ? _m : i2 );  d2  = fminf(fmaxf(d1 ,_d), d2 ); \
  bool c0  = _d < d0;   i1  = c0  ? i0  : (c1  ? _m : i1 );  d1  = fminf(fmaxf(d0 ,_d), d1 ); \
  i0 = c0 ? _m : i0;  d0 = fminf(d0,_d); }while(0)
#define KSTORED(p,o) do{ (p)[(o)+0]=d0;(p)[(o)+1]=d1;(p)[(o)+2]=d2;(p)[(o)+3]=d3;\
  (p)[(o)+4]=d4;(p)[(o)+5]=d5;(p)[(o)+6]=d6;(p)[(o)+7]=d7;\
  (p)[(o)+8]=d8;(p)[(o)+9]=d9;(p)[(o)+10]=d10;(p)[(o)+11]=d11;\
  (p)[(o)+12]=d12;(p)[(o)+13]=d13;(p)[(o)+14]=d14;(p)[(o)+15]=d15; }while(0)
#define KSTOREI(p,o) do{ (p)[(o)+0]=i0;(p)[(o)+1]=i1;(p)[(o)+2]=i2;(p)[(o)+3]=i3;\
  (p)[(o)+4]=i4;(p)[(o)+5]=i5;(p)[(o)+6]=i6;(p)[(o)+7]=i7;\
  (p)[(o)+8]=i8;(p)[(o)+9]=i9;(p)[(o)+10]=i10;(p)[(o)+11]=i11;\
  (p)[(o)+12]=i12;(p)[(o)+13]=i13;(p)[(o)+14]=i14;(p)[(o)+15]=i15; }while(0)

// ---------------- fused weight fp32 -> bf16 conversion prepass ----------------
struct CvtArgs {
  const float* src[8];
  unsigned dstOff[8];
  int n[8];
};
__global__ __launch_bounds__(256) void cvt_all(CvtArgs a)
{
  int y = blockIdx.y;
  const float* src = a.src[y];
  unsigned short* dst = (unsigned short*)(g_scratch + a.dstOff[y]);
  int n = a.n[y];
  if (y == 7){
    for (int i = blockIdx.x*256 + threadIdx.x; i < n; i += gridDim.x*256){
      int r = i >> 10, c = i & 1023;
      dst[i] = f2bf(src[(size_t)r*3072 + c]);
    }
  } else {
    for (int i = blockIdx.x*256 + threadIdx.x; i < n; i += gridDim.x*256)
      dst[i] = f2bf(src[i]);
  }
}

// ---------------- KNN pass1: dist-only chunk scan ----------------
// grid (16 qchunks, 16 cchunks, B), block 256.
__global__ __launch_bounds__(256) void knn_p1(const float* __restrict__ in,
                                              unsigned pdOff)
{
  float* pdist = (float*)(g_scratch + pdOff);
  __shared__ float4 sp[256];
  int b = blockIdx.z, qc = blockIdx.x, cc = blockIdx.y;
  const float* xb = in + (size_t)b*9*NP;
  int base = cc*256;
  {
    int i = threadIdx.x;
    float x = xb[base+i], y = xb[NP+base+i], z = xb[2*NP+base+i];
    sp[i] = make_float4(x,y,z,sq3(x,y,z));
  }
  __syncthreads();
  int n = qc*256 + threadIdx.x;
  float xn=xb[n], yn=xb[NP+n], zn=xb[2*NP+n];
  float sqn = sq3(xn,yn,zn);
  KDECLD;
  for (int mm=0; mm<256; ++mm){
    float4 p = sp[mm];
    float dot = __fadd_rn(__fadd_rn(__fmul_rn(xn,p.x), __fmul_rn(yn,p.y)), __fmul_rn(zn,p.z));
    float d = __fsub_rn(__fadd_rn(sqn, p.w), __fmul_rn(2.0f, dot));
    KINSD(d);
  }
  size_t o = ((size_t)((b*16 + cc)*NP + n))*16;
  KSTORED(pdist, o);
}

// ---------------- KNN thr: 16th-smallest per query ----------------
// grid 256 x 64
__global__ __launch_bounds__(64) void knn_thr(unsigned pdOff, unsigned thrOff)
{
  const float* pdist = (const float*)(g_scratch + pdOff);
  float* thr = (float*)(g_scratch + thrOff);
  int t = blockIdx.x*64 + threadIdx.x;
  int b = t >> 12, n = t & 4095;
  KDECLD;
  for (int cc=0; cc<16; ++cc){
    size_t o = ((size_t)((b*16 + cc)*NP + n))*16;
    #pragma unroll 1
    for (int j=0;j<16;j++){
      float pd = pdist[o+j];
      if (pd >= d15) break;
      KINSD(pd);
    }
  }
  thr[t] = d15;
}

// ---------------- KNN pass2: threshold-guarded (d,i) collection ----------------
// grid (16,16,B), block 256. Writes sentinel-padded sorted chunk lists.
__global__ __launch_bounds__(256) void knn_p2(const float* __restrict__ in,
                                              unsigned thrOff, unsigned pdOff, unsigned piOff)
{
  const float* thr = (const float*)(g_scratch + thrOff);
  float* pdist = (float*)(g_scratch + pdOff);
  int*   pidx  = (int*)  (g_scratch + piOff);
  __shared__ float4 sp[256];
  int b = blockIdx.z, qc = blockIdx.x, cc = blockIdx.y;
  const float* xb = in + (size_t)b*9*NP;
  int base = cc*256;
  {
    int i = threadIdx.x;
    float x = xb[base+i], y = xb[NP+base+i], z = xb[2*NP+base+i];
    sp[i] = make_float4(x,y,z,sq3(x,y,z));
  }
  __syncthreads();
  int n = qc*256 + threadIdx.x;
  float xn=xb[n], yn=xb[NP+n], zn=xb[2*NP+n];
  float sqn = sq3(xn,yn,zn);
  float th = thr[(b<<12) + n];
  KDECL;
  for (int mm=0; mm<256; ++mm){
    float4 p = sp[mm];
    float dot = __fadd_rn(__fadd_rn(__fmul_rn(xn,p.x), __fmul_rn(yn,p.y)), __fmul_rn(zn,p.z));
    float d = __fsub_rn(__fadd_rn(sqn, p.w), __fmul_rn(2.0f, dot));
    if (d <= th){ KINS(d, base+mm); }
  }
  size_t o = ((size_t)((b*16 + cc)*NP + n))*16;
  KSTORED(pdist, o);
  KSTOREI(pidx, o);
}

// ---------------- KNN final merge (sparse lists) ----------------
// grid 256 x 64
__global__ __launch_bounds__(64) void knn_mrg(unsigned pdOff, unsigned piOff, unsigned idxOff)
{
  const float* pdist = (const float*)(g_scratch + pdOff);
  const int*   pidx  = (const int*)  (g_scratch + piOff);
  int*         idxOut= (int*)(g_scratch + idxOff);
  int t = blockIdx.x*64 + threadIdx.x;
  int b = t >> 12, n = t & 4095;
  KDECL;
  for (int cc=0; cc<16; ++cc){
    size_t o = ((size_t)((b*16 + cc)*NP + n))*16;
    #pragma unroll 1
    for (int j=0;j<16;j++){
      float pd = pdist[o+j];
      if (pd >= d15) break;
      KINS(pd, pidx[o+j]);
    }
  }
  idxOut[t*16+ 0]=i0;  idxOut[t*16+ 1]=i1;  idxOut[t*16+ 2]=i2;  idxOut[t*16+ 3]=i3;
  idxOut[t*16+ 4]=i4;  idxOut[t*16+ 5]=i5;  idxOut[t*16+ 6]=i6;  idxOut[t*16+ 7]=i7;
  idxOut[t*16+ 8]=i8;  idxOut[t*16+ 9]=i9;  idxOut[t*16+10]=i10; idxOut[t*16+11]=i11;
  idxOut[t*16+12]=i12; idxOut[t*16+13]=i13; idxOut[t*16+14]=i14; idxOut[t*16+15]=i15;
}

// ---------------- embedding conv1 (Cin=9), output-split ----------------
// grid (64 tokens/256, 4 ogroups), block 256: one thread per token x 32 outs.
__global__ __launch_bounds__(256) void emb1_kernel(const float* __restrict__ in,
                                                   const float* __restrict__ w1,
                                                   const float* __restrict__ s1,
                                                   const float* __restrict__ b1,
                                                   unsigned x1Off)
{
  unsigned short* x1 = (unsigned short*)(g_scratch + x1Off);
  int og = blockIdx.y*32;
  __shared__ float wf[32*9], sf[32], bf_[32];
  for (int i = threadIdx.x; i < 32*9; i += 256) wf[i] = w1[og*9 + i];  // R10 fix
  if (threadIdx.x < 32){ sf[threadIdx.x]=s1[og+threadIdx.x]; bf_[threadIdx.x]=b1[og+threadIdx.x]; }
  __syncthreads();
  int t = blockIdx.x*256 + threadIdx.x;
  int b = t >> 12, n = t & 4095;
  float v[9];
  #pragma unroll
  for (int c=0;c<9;c++) v[c] = in[((size_t)b*9 + c)*NP + n];
  for (int o=0;o<32;o+=2){
    float a0=0.f, a1=0.f;
    #pragma unroll
    for (int c=0;c<9;c++){ a0 += wf[o*9+c]*v[c]; a1 += wf[(o+1)*9+c]*v[c]; }
    a0 = fmaxf(sf[o]*a0 + bf_[o], 0.f);
    a1 = fmaxf(sf[o+1]*a1 + bf_[o+1], 0.f);
    unsigned pk = (unsigned)f2bf(a0) | ((unsigned)f2bf(a1) << 16);
    *(unsigned*)(x1 + (size_t)t*128 + og + o) = pk;
  }
}

// ---------------- generic token-major MFMA GEMM (bf16 in/out) ----------------
enum { EPI_PLAIN=0, EPI_RELU_SB=1, EPI_RES=2, EPI_LEAKY=3, EPI_CLS=4 };

template<int EPI, bool EXB>
__device__ __forceinline__ void gemm_body(
    int M0, int T0,
    const unsigned short* W, const unsigned short* X, unsigned short* out,
    int Xstride, int Xoff, int outStride, int outOff,
    const float* sPtr, const float* bPtr,
    const float* extraIn, unsigned extraOffB, int extraStride,
    unsigned resOffB, int resStride, int resOff,
    int K, int Astride, int lane)
{
  int r = lane & 15, q = lane >> 4;
  f32x4 acc[4][4];
  #pragma unroll
  for (int i=0;i<4;i++)
    #pragma unroll
    for (int j=0;j<4;j++)
      #pragma unroll
      for (int u=0;u<4;u++) acc[i][j][u] = 0.f;

  const unsigned short* Arow[4]; const unsigned short* Brow[4];
  #pragma unroll
  for (int i=0;i<4;i++) Arow[i] = W + (size_t)(M0 + i*16 + r)*Astride + q*8;
  #pragma unroll
  for (int j=0;j<4;j++) Brow[j] = X + (size_t)(T0 + j*16 + r)*Xstride + Xoff + q*8;

  for (int k0=0; k0<K; k0+=32){
    short8 a[4], bfr[4];
    #pragma unroll
    for (int i=0;i<4;i++) a[i]   = *(const short8*)(Arow[i] + k0);
    #pragma unroll
    for (int j=0;j<4;j++) bfr[j] = *(const short8*)(Brow[j] + k0);
    #pragma unroll
    for (int i=0;i<4;i++)
      #pragma unroll
      for (int j=0;j<4;j++)
        acc[i][j] = __builtin_amdgcn_mfma_f32_16x16x32_bf16(a[i], bfr[j], acc[i][j], 0, 0, 0);
  }

  // epilogue: D layout col=lane&15 (token), row=q*4+reg (channel)
  #pragma unroll
  for (int i=0;i<4;i++){
    int m = M0 + i*16 + q*4;
    float sv[4], bv[4];
    if constexpr (EPI != EPI_PLAIN){
      #pragma unroll
      for (int u=0;u<4;u++){ sv[u]=sPtr[m+u]; bv[u]=bPtr[m+u]; }
    }
    #pragma unroll
    for (int j=0;j<4;j++){
      int token = T0 + j*16 + r;
      float ex[4];
      if constexpr (EPI == EPI_CLS){
        int bb = token >> 12;
        #pragma unroll
        for (int u=0;u<4;u++)
          ex[u] = EXB ? extraIn[bb*extraStride + m + u]
                      : ((const float*)(g_scratch + extraOffB))[bb*extraStride + m + u];
      }
      float resv[4];
      if constexpr (EPI == EPI_RES){
        const unsigned short* resPtr = (const unsigned short*)(g_scratch + resOffB);
        ushort4v rv = *(const ushort4v*)(resPtr + (size_t)token*resStride + resOff + m);
        #pragma unroll
        for (int u=0;u<4;u++) resv[u]=bf2f(rv[u]);
      }
      ushort4v ov;
      #pragma unroll
      for (int u=0;u<4;u++){
        float a = acc[i][j][u];
        float vo;
        if constexpr (EPI == EPI_PLAIN)        vo = a;
        else if constexpr (EPI == EPI_RELU_SB) vo = fmaxf(sv[u]*a + bv[u], 0.f);
        else if constexpr (EPI == EPI_RES)     vo = resv[u] + fmaxf(sv[u]*a + bv[u], 0.f);
        else if constexpr (EPI == EPI_LEAKY){  float tt = sv[u]*a + bv[u]; vo = tt>0.f ? tt : 0.2f*tt; }
        else { vo = fmaxf(sv[u]*(a + ex[u]) + bv[u], 0.f); }
        ov[u] = f2bf(vo);
      }
      *(ushort4v*)(out + (size_t)token*outStride + outOff + m) = ov;
    }
  }
}

// 4-wave 128Mx128T (fuse, cls1)
template<int EPI, bool EXB>
__global__ __launch_bounds__(256) void gemm_tok(
    unsigned W0off, unsigned W1off, unsigned W2off,
    unsigned O0off, unsigned O1off, unsigned O2off,
    unsigned XoffB, int Xstride, int Xoff,
    int outStride, int outOff,
    const float* sPtr, const float* bPtr,
    const float* extraIn, unsigned extraOffB, int extraStride,
    unsigned resOffB, int resStride, int resOff,
    int K, int Astride)
{
  const unsigned short* X = (const unsigned short*)(g_scratch + XoffB);
  unsigned wOffB   = (blockIdx.z==0) ? W0off : ((blockIdx.z==1) ? W1off : W2off);
  unsigned outOffB = (blockIdx.z==0) ? O0off : ((blockIdx.z==1) ? O1off : O2off);
  const unsigned short* W = (const unsigned short*)(g_scratch + wOffB);
  unsigned short* out = (unsigned short*)(g_scratch + outOffB);
  int lane = threadIdx.x & 63, wave = threadIdx.x >> 6;
  int M0 = blockIdx.x*128 + (wave>>1)*64;
  int T0 = blockIdx.y*128 + (wave&1)*64;
  gemm_body<EPI,EXB>(M0, T0, W, X, out, Xstride, Xoff, outStride, outOff,
                     sPtr, bPtr, extraIn, extraOffB, extraStride,
                     resOffB, resStride, resOff, K, Astride, lane);
}

// 2-wave 64Mx128T (emb2, qkv, wo, cls2) -> 2x block count
template<int EPI, bool EXB>
__global__ __launch_bounds__(128) void gemm_small(
    unsigned W0off, unsigned W1off, unsigned W2off,
    unsigned O0off, unsigned O1off, unsigned O2off,
    unsigned XoffB, int Xstride, int Xoff,
    int outStride, int outOff,
    const float* sPtr, const float* bPtr,
    const float* extraIn, unsigned extraOffB, int extraStride,
    unsigned resOffB, int resStride, int resOff,
    int K, int Astride)
{
  const unsigned short* X = (const unsigned short*)(g_scratch + XoffB);
  unsigned wOffB   = (blockIdx.z==0) ? W0off : ((blockIdx.z==1) ? W1off : W2off);
  unsigned outOffB = (blockIdx.z==0) ? O0off : ((blockIdx.z==1) ? O1off : O2off);
  const unsigned short* W = (const unsigned short*)(g_scratch + wOffB);
  unsigned short* out = (unsigned short*)(g_scratch + outOffB);
  int lane = threadIdx.x & 63, wave = threadIdx.x >> 6;  // 0/1
  int M0 = blockIdx.x*64;
  int T0 = blockIdx.y*128 + wave*64;
  gemm_body<EPI,EXB>(M0, T0, W, X, out, Xstride, Xoff, outStride, outOff,
                     sPtr, bPtr, extraIn, extraOffB, extraStride,
                     resOffB, resStride, resOff, K, Astride, lane);
}

// ---------------- attention (one wave per query, 2 channels/lane) ----------------
__global__ __launch_bounds__(256) void attn_kernel(
  unsigned qOff, unsigned kOff, unsigned vOff, unsigned idxOff,
  const float* __restrict__ in, const float* __restrict__ wpos,
  unsigned aggOff)
{
  const unsigned short* Q  = (const unsigned short*)(g_scratch + qOff);
  const unsigned short* Kf = (const unsigned short*)(g_scratch + kOff);
  const unsigned short* V  = (const unsigned short*)(g_scratch + vOff);
  const int* idx           = (const int*)(g_scratch + idxOff);
  unsigned short* agg      = (unsigned short*)(g_scratch + aggOff);

  int lane = threadIdx.x & 63, wv = threadIdx.x >> 6;
  int t = blockIdx.x*4 + wv;
  int b = t >> 12, n = t & 4095;
  const float* xb = in + (size_t)b*9*NP;
  int c0 = lane*2;

  unsigned qv = *(const unsigned*)(Q + (size_t)t*128 + c0);
  float q0 = bf2f((unsigned short)(qv & 0xffff)), q1 = bf2f((unsigned short)(qv >> 16));
  float xn = xb[n], yn = xb[NP+n], zn = xb[2*NP+n];
  float wp00=wpos[c0*3+0],     wp01=wpos[c0*3+1],     wp02=wpos[c0*3+2];
  float wp10=wpos[(c0+1)*3+0], wp11=wpos[(c0+1)*3+1], wp12=wpos[(c0+1)*3+2];

  int mi[16]; float s[16];
  #pragma unroll
  for (int j=0;j<16;j++) mi[j] = idx[(size_t)t*16 + j] & 4095;  // mask: never OOB
  #pragma unroll
  for (int j=0;j<16;j++){
    unsigned kv = *(const unsigned*)(Kf + ((size_t)(b<<12) + mi[j])*128 + c0);
    float p = q0*bf2f((unsigned short)(kv & 0xffff)) + q1*bf2f((unsigned short)(kv >> 16));
    #pragma unroll
    for (int o=32;o>=1;o>>=1) p += __shfl_xor(p, o, 64);
    s[j] = p;
  }
  const float scale = 0.08838834764831845f; // 1/sqrt(128)
  float mx = s[0];
  #pragma unroll
  for (int j=1;j<16;j++) mx = fmaxf(mx, s[j]);
  float e[16], sum = 0.f;
  #pragma unroll
  for (int j=0;j<16;j++){ e[j] = __expf((s[j]-mx)*scale); sum += e[j]; }
  float inv = 1.f / sum;

  float a0=0.f, a1=0.f;
  #pragma unroll
  for (int j=0;j<16;j++){
    int m = mi[j];
    float w = e[j]*inv;
    unsigned vv = *(const unsigned*)(V + ((size_t)(b<<12) + m)*128 + c0);
    float rx = xn - xb[m];
    float ry = yn - xb[NP+m];
    float rz = zn - xb[2*NP+m];
    float p0 = wp00*rx + wp01*ry + wp02*rz;
    float p1 = wp10*rx + wp11*ry + wp12*rz;
    a0 += w*(bf2f((unsigned short)(vv & 0xffff)) + p0);
    a1 += w*(bf2f((unsigned short)(vv >> 16)) + p1);
  }
  unsigned pk = (unsigned)f2bf(a0) | ((unsigned)f2bf(a1) << 16);
  *(unsigned*)(agg + (size_t)t*128 + c0) = pk;
}

// ---------------- max/mean pool over tokens (two-stage) ----------------
__global__ __launch_bounds__(256) void pool_part(unsigned xfOff, unsigned gpOff)
{
  const unsigned short* xf = (const unsigned short*)(g_scratch + xfOff);
  float* gp = (float*)(g_scratch + gpOff);   // [b][seg][2][1024]
  int b = blockIdx.x >> 7, cblk = (blockIdx.x >> 3) & 15, seg = blockIdx.x & 7;
  int cl = threadIdx.x & 63, tg = threadIdx.x >> 6;
  int c = cblk*64 + cl;
  float mx = -3.0e38f, sm = 0.f;
  for (int n = seg*512 + tg; n < (seg+1)*512; n += 4){
    float v = bf2f(xf[((size_t)(b<<12) + n)*1024 + c]);
    mx = fmaxf(mx, v); sm += v;
  }
  __shared__ float smx[4][64], ssm[4][64];
  smx[tg][cl]=mx; ssm[tg][cl]=sm;
  __syncthreads();
  if (tg==0){
    #pragma unroll
    for (int k=1;k<4;k++){ mx = fmaxf(mx, smx[k][cl]); sm += ssm[k][cl]; }
    gp[((b*8 + seg)*2 + 0)*1024 + c] = mx;
    gp[((b*8 + seg)*2 + 1)*1024 + c] = sm;
  }
}
__global__ __launch_bounds__(256) void pool_final(unsigned gpOff, unsigned gOff)
{
  const float* gp = (const float*)(g_scratch + gpOff);
  float* g = (float*)(g_scratch + gOff);
  int b = blockIdx.x;
  for (int c = threadIdx.x; c < 1024; c += 256){
    float mx = -3.0e38f, sm = 0.f;
    #pragma unroll
    for (int seg=0; seg<8; ++seg){
      mx = fmaxf(mx, gp[((b*8 + seg)*2 + 0)*1024 + c]);
      sm += gp[((b*8 + seg)*2 + 1)*1024 + c];
    }
    g[b*2048 + c] = mx;
    g[b*2048 + 1024 + c] = sm * (1.f/4096.f);
  }
}

// gb[b][o] = cls_bias1[o] + sum_c W1[o][1024+c]*g[b][c]
// grid 32 (b*8 + og), block 256 = 64 outputs x 4 c-quarters, LDS reduce
__global__ __launch_bounds__(256) void gterm_kernel(const float* __restrict__ w1,
                                                    const float* __restrict__ bias1,
                                                    unsigned gOff, unsigned gbOff)
{
  const float* g = (const float*)(g_scratch + gOff);
  float* gb = (float*)(g_scratch + gbOff);
  int b = blockIdx.x >> 3, og = (blockIdx.x & 7)*64;
  int ol = threadIdx.x & 63, cq = threadIdx.x >> 6;
  int o = og + ol;
  const float* wrow = w1 + (size_t)o*3072 + 1024 + cq*512;
  const float* gp = g + b*2048 + cq*512;
  float acc = 0.f;
  for (int c=0;c<512;c+=4){
    float4 wv4 = *(const float4*)(wrow + c);
    acc += wv4.x*gp[c] + wv4.y*gp[c+1] + wv4.z*gp[c+2] + wv4.w*gp[c+3];
  }
  __shared__ float sred[4][64];
  sred[cq][ol] = acc;
  __syncthreads();
  if (cq==0){
    acc += sred[1][ol] + sred[2][ol] + sred[3][ol];
    gb[b*512 + o] = acc + bias1[o];
  }
}

// ---------------- classifier head (O=13), fp32 out ----------------
__global__ __launch_bounds__(256) void cls3_kernel(unsigned c2Off,
                                                   const float* __restrict__ w3,
                                                   const float* __restrict__ bias3,
                                                   float* __restrict__ outp)
{
  const unsigned short* c2 = (const unsigned short*)(g_scratch + c2Off);
  __shared__ float wf[13*256];
  __shared__ float bf3[13];
  for (int i=threadIdx.x;i<13*256;i+=256) wf[i]=w3[i];
  if (threadIdx.x < 13) bf3[threadIdx.x]=bias3[threadIdx.x];
  __syncthreads();
  int lane = threadIdx.x & 63, wv = threadIdx.x >> 6;
  int tl = lane >> 2, cq = lane & 3;
  int t = blockIdx.x*64 + wv*16 + tl;
  const unsigned short* xrow = c2 + (size_t)t*256 + cq*64;
  float acc[13];
  #pragma unroll
  for (int o=0;o<13;o++) acc[o]=0.f;
  for (int c=0;c<64;c+=8){
    short8 xv = *(const short8*)(xrow + c);
    float xs[8];
    #pragma unroll
    for (int u=0;u<8;u++) xs[u]=bf2f((unsigned short)xv[u]);
    #pragma unroll
    for (int o=0;o<13;o++){
      const float* wr = wf + o*256 + cq*64 + c;
      #pragma unroll
      for (int u=0;u<8;u++) acc[o] += wr[u]*xs[u];
    }
  }
  #pragma unroll
  for (int o=0;o<13;o++){
    acc[o] += __shfl_xor(acc[o], 1, 64);
    acc[o] += __shfl_xor(acc[o], 2, 64);
  }
  if (cq==0){
    int b = t >> 12, n = t & 4095;
    #pragma unroll
    for (int o=0;o<13;o++)
      outp[((size_t)b*13 + o)*NP + n] = acc[o] + bf3[o];
  }
}

// ---------------- launch ----------------
extern "C" void kernel_launch(void* const* d_in, const int* in_sizes, int n_in,
                              void* d_out, int out_size, void* d_ws, size_t ws_size,
                              hipStream_t stream) {
  (void)in_sizes; (void)n_in; (void)out_size; (void)d_ws; (void)ws_size;
  const float* in      = (const float*)d_in[0];
  const float* emb_w1  = (const float*)d_in[1];
  const float* emb_s1  = (const float*)d_in[2];
  const float* emb_b1  = (const float*)d_in[3];
  const float* emb_w2  = (const float*)d_in[4];
  const float* emb_s2  = (const float*)d_in[5];
  const float* emb_b2  = (const float*)d_in[6];
  const float* blk_wq  = (const float*)d_in[7];
  const float* blk_wk  = (const float*)d_in[8];
  const float* blk_wv  = (const float*)d_in[9];
  const float* blk_wpos= (const float*)d_in[10];
  const float* blk_wo  = (const float*)d_in[11];
  const float* blk_s   = (const float*)d_in[12];
  const float* blk_b   = (const float*)d_in[13];
  const float* fuse_w  = (const float*)d_in[14];
  const float* fuse_s  = (const float*)d_in[15];
  const float* fuse_b  = (const float*)d_in[16];
  const float* cls_w1  = (const float*)d_in[17];
  const float* cls_b1  = (const float*)d_in[18];
  const float* cls_s1  = (const float*)d_in[19];
  const float* cls_sh1 = (const float*)d_in[20];
  const float* cls_w2  = (const float*)d_in[21];
  const float* cls_b2  = (const float*)d_in[22];
  const float* cls_s2  = (const float*)d_in[23];
  const float* cls_sh2 = (const float*)d_in[24];
  const float* cls_w3  = (const float*)d_in[25];
  const float* cls_b3  = (const float*)d_in[26];

  // byte offsets into g_scratch
  const unsigned MB = 1u<<20, KB = 1024u;
  const unsigned OFF_IDX   = 0;                 // 1 MB   int idx[T][16]
  const unsigned OFF_WQ    = 1*MB;              // 96 KB  bf16 (3,128,128)
  const unsigned OFF_WK    = 1*MB + 128*KB;     // 96 KB
  const unsigned OFF_WV    = 1*MB + 256*KB;     // 96 KB
  const unsigned OFF_WO    = 1*MB + 384*KB;     // 96 KB
  const unsigned OFF_WEMB2 = 1*MB + 512*KB;     // 32 KB  bf16 (128,128)
  const unsigned OFF_WFUSE = 1*MB + 576*KB;     // 768 KB bf16 (1024,384)
  const unsigned OFF_WW1   = 3*MB;              // 1 MB   bf16 (512,1024) x-half
  const unsigned OFF_WW2   = 4*MB;              // 256 KB bf16 (256,512)
  const unsigned OFF_X1    = 5*MB;              // 4 MB   bf16 (T,128)
  const unsigned OFF_X0    = 9*MB;              // 4 MB   bf16 (T,128)
  const unsigned OFF_XCAT  = 13*MB;             // 12 MB  bf16 (T,384)
  const unsigned OFF_QB    = 25*MB;             // 4 MB
  const unsigned OFF_KB    = 29*MB;             // 4 MB
  const unsigned OFF_VB    = 33*MB;             // 4 MB
  const unsigned OFF_AGG   = 37*MB;             // 4 MB
  const unsigned OFF_XF    = 41*MB;             // 32 MB  bf16 (T,1024)
  const unsigned OFF_C1    = 73*MB;             // 16 MB  bf16 (T,512)
  const unsigned OFF_C2    = 89*MB;             // 8 MB   bf16 (T,256)
  const unsigned OFF_G     = 97*MB;             // 32 KB  f32 (B,2048)
  const unsigned OFF_GB    = 97*MB + 64*KB;     // 8 KB   f32 (B,512)
  const unsigned OFF_GP    = 97*MB + 128*KB;    // 256 KB f32 pool partials
  const unsigned OFF_THR   = 97*MB + 512*KB;    // 64 KB  f32 thr[T]
  const unsigned OFF_PD    = 98*MB;             // 16 MB  f32 knn dists (p1, reused by p2)
  const unsigned OFF_PI    = 114*MB;            // 16 MB  int knn idx (p2)
  float* outp = (float*)d_out;                  // (B,13,N) f32

  // 0: fused weight conversion prepass (fp32 -> bf16 into scratch)
  CvtArgs ca;
  ca.src[0]=emb_w2;  ca.dstOff[0]=OFF_WEMB2; ca.n[0]=128*128;
  ca.src[1]=blk_wq;  ca.dstOff[1]=OFF_WQ;    ca.n[1]=3*128*128;
  ca.src[2]=blk_wk;  ca.dstOff[2]=OFF_WK;    ca.n[2]=3*128*128;
  ca.src[3]=blk_wv;  ca.dstOff[3]=OFF_WV;    ca.n[3]=3*128*128;
  ca.src[4]=blk_wo;  ca.dstOff[4]=OFF_WO;    ca.n[4]=3*128*128;
  ca.src[5]=fuse_w;  ca.dstOff[5]=OFF_WFUSE; ca.n[5]=1024*384;
  ca.src[6]=cls_w2;  ca.dstOff[6]=OFF_WW2;   ca.n[6]=256*512;
  ca.src[7]=cls_w1;  ca.dstOff[7]=OFF_WW1;   ca.n[7]=512*1024;
  cvt_all<<<dim3(64,8), 256, 0, stream>>>(ca);

  // 1-4: KNN (threshold two-pass)
  knn_p1<<<dim3(16,16,4), 256, 0, stream>>>(in, OFF_PD);
  knn_thr<<<dim3(256), 64, 0, stream>>>(OFF_PD, OFF_THR);
  knn_p2<<<dim3(16,16,4), 256, 0, stream>>>(in, OFF_THR, OFF_PD, OFF_PI);
  knn_mrg<<<dim3(256), 64, 0, stream>>>(OFF_PD, OFF_PI, OFF_IDX);
  // 5-6: embedding
  emb1_kernel<<<dim3(64,4), 256, 0, stream>>>(in, emb_w1, emb_s1, emb_b1, OFF_X1);
  gemm_small<EPI_RELU_SB,false><<<dim3(2,128,1), 128, 0, stream>>>(
      OFF_WEMB2, OFF_WEMB2, OFF_WEMB2, OFF_X0, OFF_X0, OFF_X0,
      OFF_X1, 128, 0, 128, 0, emb_s2, emb_b2,
      nullptr, 0, 0, 0, 0, 0, 128, 128);
  // 7-9: transformer blocks
  for (int i=0;i<3;i++){
    unsigned wq = OFF_WQ + i*32768, wk = OFF_WK + i*32768;
    unsigned wv = OFF_WV + i*32768, wo = OFF_WO + i*32768;
    const float* wp = blk_wpos + i*128*3;
    const float* si = blk_s + i*128;
    const float* bi = blk_b + i*128;
    unsigned XiOff = (i==0) ? OFF_X0 : OFF_XCAT;
    int Xs = (i==0) ? 128 : 384;
    int Xo = (i==0) ? 0 : (i-1)*128;
    gemm_small<EPI_PLAIN,false><<<dim3(2,128,3), 128, 0, stream>>>(
        wq, wk, wv, OFF_QB, OFF_KB, OFF_VB,
        XiOff, Xs, Xo, 128, 0, nullptr, nullptr,
        nullptr, 0, 0, 0, 0, 0, 128, 128);
    attn_kernel<<<dim3(4096), 256, 0, stream>>>(OFF_QB, OFF_KB, OFF_VB, OFF_IDX, in, wp, OFF_AGG);
    gemm_small<EPI_RES,false><<<dim3(2,128,1), 128, 0, stream>>>(
        wo, wo, wo, OFF_XCAT, OFF_XCAT, OFF_XCAT,
        OFF_AGG, 128, 0, 384, i*128, si, bi,
        nullptr, 0, 0, XiOff, Xs, Xo, 128, 128);
  }
  // 10: fuse (leaky relu)
  gemm_tok<EPI_LEAKY,false><<<dim3(8,128,1), 256, 0, stream>>>(
      OFF_WFUSE, OFF_WFUSE, OFF_WFUSE, OFF_XF, OFF_XF, OFF_XF,
      OFF_XCAT, 384, 0, 1024, 0, fuse_s, fuse_b,
      nullptr, 0, 0, 0, 0, 0, 384, 384);
  // 11-13: pooling (two-stage) + broadcast-g term of cls1 (fp32)
  pool_part<<<dim3(512), 256, 0, stream>>>(OFF_XF, OFF_GP);
  pool_final<<<dim3(4), 256, 0, stream>>>(OFF_GP, OFF_G);
  gterm_kernel<<<dim3(32), 256, 0, stream>>>(cls_w1, cls_b1, OFF_G, OFF_GB);
  // 14: cls1 (K=1024 x-half of W1; gb = W1[:,1024:]@g + bias1 as extra)
  gemm_tok<EPI_CLS,false><<<dim3(4,128,1), 256, 0, stream>>>(
      OFF_WW1, OFF_WW1, OFF_WW1, OFF_C1, OFF_C1, OFF_C1,
      OFF_XF, 1024, 0, 512, 0, cls_s1, cls_sh1,
      nullptr, OFF_GB, 512, 0, 0, 0, 1024, 1024);
  // 15: cls2
  gemm_small<EPI_CLS,true><<<dim3(4,128,1), 128, 0, stream>>>(
      OFF_WW2, OFF_WW2, OFF_WW2, OFF_C2, OFF_C2, OFF_C2,
      OFF_C1, 512, 0, 256, 0, cls_s2, cls_sh2,
      cls_b2, 0, 0, 0, 0, 0, 512, 512);
  // 16: cls3 -> d_out (fp32)
  cls3_kernel<<<dim3(256), 256, 0, stream>>>(OFF_C2, cls_w3, cls_b3, outp);
}

// Round 11
// 610.494 us; speedup vs baseline: 1.8829x; 1.2261x over previous
//
#include <hip/hip_runtime.h>

// PVDST semseg, MI355X/gfx950. FP32 I/O. Round-11: cheap-threshold KNN.
//   - p1 only needs an UPPER BOUND on d16: four sorted-4 lists (7 min/max
//     per candidate vs 31) whose 16-value union's 16th-smallest is provably
//     >= d16 (missing members only inflate). p1 dist uses contracted fma
//     (margin 2e-4 >> 1.6e-5 max fma-vs-rn cancellation error).
//   - p2: append qualifying (d<=thr) candidates in index order (no sorted
//     insert at all), exact _rn dist; merge breaks on sentinel only.
//   - Exactness: merge does stable strict-< top-16 over a superset of the
//     true top-16; ascending index order preserved end-to-end.

#define NB 4
#define NP 4096
#define NT 16384   // NB*NP tokens

#define SCRATCH_BYTES (132u*1024u*1024u)
__device__ __align__(256) unsigned char g_scratch[SCRATCH_BYTES];

typedef __attribute__((ext_vector_type(8))) short short8;   // 8 x bf16 MFMA frag
typedef __attribute__((ext_vector_type(4))) float f32x4;    // MFMA acc
typedef __attribute__((ext_vector_type(4))) unsigned short ushort4v;

__device__ __forceinline__ float bf2f(unsigned short u){
  unsigned int v = ((unsigned int)u) << 16;
  return __builtin_bit_cast(float, v);
}
__device__ __forceinline__ unsigned short f2bf(float f){
  unsigned int x = __builtin_bit_cast(unsigned int, f);
  x += 0x7fffu + ((x >> 16) & 1u);     // RNE
  return (unsigned short)(x >> 16);
}
// numpy-matched: ((x*x)+(y*y))+(z*z), each op rounded (no fma contraction)
__device__ __forceinline__ float sq3(float x, float y, float z){
  return __fadd_rn(__fadd_rn(__fmul_rn(x,x), __fmul_rn(y,y)), __fmul_rn(z,z));
}

// sorted-4 insert: 7 native min/max, no masks
#define KINS4(a0,a1,a2,a3,dd) do{ float _d=(dd);\
  a3=fminf(fmaxf(a2,_d),a3); a2=fminf(fmaxf(a1,_d),a2);\
  a1=fminf(fmaxf(a0,_d),a1); a0=fminf(a0,_d);}while(0)

// dist-only sorted-ascending top-16 (thr kernel)
#define KDECLD float d0=3.0e38f,d1=3.0e38f,d2=3.0e38f,d3=3.0e38f,d4=3.0e38f,\
  d5=3.0e38f,d6=3.0e38f,d7=3.0e38f,d8=3.0e38f,d9=3.0e38f,d10=3.0e38f,\
  d11=3.0e38f,d12=3.0e38f,d13=3.0e38f,d14=3.0e38f,d15=3.0e38f
#define KINSD(dd) do{ float _d=(dd); \
  d15=fminf(fmaxf(d14,_d),d15); d14=fminf(fmaxf(d13,_d),d14); \
  d13=fminf(fmaxf(d12,_d),d13); d12=fminf(fmaxf(d11,_d),d12); \
  d11=fminf(fmaxf(d10,_d),d11); d10=fminf(fmaxf(d9 ,_d),d10); \
  d9 =fminf(fmaxf(d8 ,_d),d9 ); d8 =fminf(fmaxf(d7 ,_d),d8 ); \
  d7 =fminf(fmaxf(d6 ,_d),d7 ); d6 =fminf(fmaxf(d5 ,_d),d6 ); \
  d5 =fminf(fmaxf(d4 ,_d),d5 ); d4 =fminf(fmaxf(d3 ,_d),d4 ); \
  d3 =fminf(fmaxf(d2 ,_d),d3 ); d2 =fminf(fmaxf(d1 ,_d),d2 ); \
  d1 =fminf(fmaxf(d0 ,_d),d1 ); d0 =fminf(d0,_d); }while(0)

// full (dist,idx) stable insert (merge only; strict < => lower index wins)
#define KDECL KDECLD; int i0=0,i1=0,i2=0,i3=0,i4=0,i5=0,i6=0,i7=0,i8=0,\
  i9=0,i10=0,i11=0,i12=0,i13=0,i14=0,i15=0
#define KINS(dd,mm) do{ float _d=(dd); int _m=(mm); \
  bool c15 = _d < d15; \
  bool c14 = _d < d14;  i15 = c14 ? i14 : (c15 ? _m : i15);  d15 = fminf(fmaxf(d14,_d), d15); \
  bool c13 = _d < d13;  i14 = c13 ? i13 : (c14 ? _m : i14);  d14 = fminf(fmaxf(d13,_d), d14); \
  bool c12 = _d < d12;  i13 = c12 ? i12 : (c13 ? _m : i13);  d13 = fminf(fmaxf(d12,_d), d13); \
  bool c11 = _d < d11;  i12 = c11 ? i11 : (c12 ? _m : i12);  d12 = fminf(fmaxf(d11,_d), d12); \
  bool c10 = _d < d10;  i11 = c10 ? i10 : (c11 ? _m : i11);  d11 = fminf(fmaxf(d10,_d), d11); \
  bool c9  = _d < d9;   i10 = c9  ? i9  : (c10 ? _m : i10);  d10 = fminf(fmaxf(d9 ,_d), d10); \
  bool c8  = _d < d8;   i9  = c8  ? i8  : (c9  ? _m : i9 );  d9  = fminf(fmaxf(d8 ,_d), d9 ); \
  bool c7  = _d < d7;   i8  = c7  ? i7  : (c8  ? _m : i8 );  d8  = fminf(fmaxf(d7 ,_d), d8 ); \
  bool c6  = _d < d6;   i7  = c6  ? i6  : (c7  ? _m : i7 );  d7  = fminf(fmaxf(d6 ,_d), d7 ); \
  bool c5  = _d < d5;   i6  = c5  ? i5  : (c6  ? _m : i6 );  d6  = fminf(fmaxf(d5 ,_d), d6 ); \
  bool c4  = _d < d4;   i5  = c4  ? i4  : (c5  ? _m : i5 );  d5  = fminf(fmaxf(d4 ,_d), d5 ); \
  bool c3  = _d < d3;   i4  = c3  ? i3  : (c4  ? _m : i4 );  d4  = fminf(fmaxf(d3 ,_d), d4 ); \
  bool c2  = _d < d2;   i3  = c2  ? i2  : (c3  ? _m : i3 );  d3  = fminf(fmaxf(d2 ,_d), d3 ); \
  bool c1  = _d < d1;   i2  = c1  ? i1  : (c2  ? _m : i2 );  d2  = fminf(fmaxf(d1 ,_d), d2 ); \
  bool c0  = _d < d0;   i1  = c0  ? i0  : (c1  ? _m : i1 );  d1  = fminf(fmaxf(d0 ,_d), d1 ); \
  i0 = c0 ? _m : i0;  d0 = fminf(d0,_d); }while(0)

// ---------------- fused weight fp32 -> bf16 conversion prepass ----------------
struct CvtArgs {
  const float* src[8];
  unsigned dstOff[8];
  int n[8];
};
__global__ __launch_bounds__(256) void cvt_all(CvtArgs a)
{
  int y = blockIdx.y;
  const float* src = a.src[y];
  unsigned short* dst = (unsigned short*)(g_scratch + a.dstOff[y]);
  int n = a.n[y];
  if (y == 7){
    for (int i = blockIdx.x*256 + threadIdx.x; i < n; i += gridDim.x*256){
      int r = i >> 10, c = i & 1023;
      dst[i] = f2bf(src[(size_t)r*3072 + c]);
    }
  } else {
    for (int i = blockIdx.x*256 + threadIdx.x; i < n; i += gridDim.x*256)
      dst[i] = f2bf(src[i]);
  }
}

// ---------------- KNN pass1: 4x sorted-4 bound lists, fma dist ----------------
// grid (16 qchunks, 16 cchunks, B), block 256. Layout [b][cc][j(16)][NP].
__global__ __launch_bounds__(256) void knn_p1(const float* __restrict__ in,
                                              unsigned pdOff)
{
  float* pdist = (float*)(g_scratch + pdOff);
  __shared__ float4 sp[256];
  int b = blockIdx.z, qc = blockIdx.x, cc = blockIdx.y;
  const float* xb = in + (size_t)b*9*NP;
  int base = cc*256;
  {
    int i = threadIdx.x;
    float x = xb[base+i], y = xb[NP+base+i], z = xb[2*NP+base+i];
    sp[i] = make_float4(x,y,z, x*x+y*y+z*z);
  }
  __syncthreads();
  int n = qc*256 + threadIdx.x;
  float xn=xb[n], yn=xb[NP+n], zn=xb[2*NP+n];
  float sqn = xn*xn + yn*yn + zn*zn;
  float A0=3e38f,A1=3e38f,A2=3e38f,A3=3e38f;
  float B0=3e38f,B1=3e38f,B2=3e38f,B3=3e38f;
  float C0=3e38f,C1=3e38f,C2=3e38f,C3=3e38f;
  float D0=3e38f,D1=3e38f,D2=3e38f,D3=3e38f;
  for (int mm=0; mm<256; mm+=4){
    float4 p0 = sp[mm], p1 = sp[mm+1], p2 = sp[mm+2], p3 = sp[mm+3];
    float e0 = sqn + p0.w - 2.f*(xn*p0.x + yn*p0.y + zn*p0.z);
    float e1 = sqn + p1.w - 2.f*(xn*p1.x + yn*p1.y + zn*p1.z);
    float e2 = sqn + p2.w - 2.f*(xn*p2.x + yn*p2.y + zn*p2.z);
    float e3 = sqn + p3.w - 2.f*(xn*p3.x + yn*p3.y + zn*p3.z);
    KINS4(A0,A1,A2,A3,e0);
    KINS4(B0,B1,B2,B3,e1);
    KINS4(C0,C1,C2,C3,e2);
    KINS4(D0,D1,D2,D3,e3);
  }
  size_t ob = ((size_t)(b*16+cc)*16)*NP + n;
  pdist[ob+ 0*(size_t)NP]=A0; pdist[ob+ 1*(size_t)NP]=A1; pdist[ob+ 2*(size_t)NP]=A2; pdist[ob+ 3*(size_t)NP]=A3;
  pdist[ob+ 4*(size_t)NP]=B0; pdist[ob+ 5*(size_t)NP]=B1; pdist[ob+ 6*(size_t)NP]=B2; pdist[ob+ 7*(size_t)NP]=B3;
  pdist[ob+ 8*(size_t)NP]=C0; pdist[ob+ 9*(size_t)NP]=C1; pdist[ob+10*(size_t)NP]=C2; pdist[ob+11*(size_t)NP]=C3;
  pdist[ob+12*(size_t)NP]=D0; pdist[ob+13*(size_t)NP]=D1; pdist[ob+14*(size_t)NP]=D2; pdist[ob+15*(size_t)NP]=D3;
}

// ---------------- KNN thr: 16th-smallest of the 256 bound values + margin ----
// grid 64 x 256 (values unsorted -> full scan, coalesced [cc][j][n] reads)
__global__ __launch_bounds__(256) void knn_thr(unsigned pdOff, unsigned thrOff)
{
  const float* pdist = (const float*)(g_scratch + pdOff);
  float* thr = (float*)(g_scratch + thrOff);
  int t = blockIdx.x*256 + threadIdx.x;
  int b = t >> 12, n = t & 4095;
  KDECLD;
  for (int cc=0; cc<16; ++cc){
    size_t ob = ((size_t)(b*16+cc)*16)*NP + n;
    #pragma unroll
    for (int j=0;j<16;j++){ KINSD(pdist[ob + (size_t)j*NP]); }
  }
  // margin covers fma-vs-_rn cancellation error (<=~1.6e-5 absolute)
  thr[t] = d15*1.000002f + 2e-4f;
}

// ---------------- KNN pass2: append qualifying (d,i), exact _rn dist --------
// grid (16,16,B), block 256. Per-(query,chunk) 16-slot index-ordered list.
__global__ __launch_bounds__(256) void knn_p2(const float* __restrict__ in,
                                              unsigned thrOff, unsigned pdOff, unsigned piOff)
{
  const float* thr = (const float*)(g_scratch + thrOff);
  float* pdist = (float*)(g_scratch + pdOff);
  int*   pidx  = (int*)  (g_scratch + piOff);
  __shared__ float4 sp[256];
  int b = blockIdx.z, qc = blockIdx.x, cc = blockIdx.y;
  const float* xb = in + (size_t)b*9*NP;
  int base = cc*256;
  {
    int i = threadIdx.x;
    float x = xb[base+i], y = xb[NP+base+i], z = xb[2*NP+base+i];
    sp[i] = make_float4(x,y,z,sq3(x,y,z));
  }
  __syncthreads();
  int n = qc*256 + threadIdx.x;
  float xn=xb[n], yn=xb[NP+n], zn=xb[2*NP+n];
  float sqn = sq3(xn,yn,zn);
  float th = thr[(b<<12) + n];
  size_t o = ((size_t)((b*16 + cc)*NP + n))*16;
  int cnt = 0;
  for (int mm=0; mm<256; ++mm){
    float4 p = sp[mm];
    float dot = __fadd_rn(__fadd_rn(__fmul_rn(xn,p.x), __fmul_rn(yn,p.y)), __fmul_rn(zn,p.z));
    float d = __fsub_rn(__fadd_rn(sqn, p.w), __fmul_rn(2.0f, dot));
    if (d <= th && cnt < 16){
      pdist[o+cnt] = d;
      pidx[o+cnt] = base + mm;
      cnt++;
    }
  }
  if (cnt < 16) pdist[o+cnt] = 3.0e38f;   // sentinel terminator
}

// ---------------- KNN final merge (index-ordered sparse lists) ----------------
// grid 256 x 64. Break on sentinel only (lists are index-ordered, not d-sorted).
__global__ __launch_bounds__(64) void knn_mrg(unsigned pdOff, unsigned piOff, unsigned idxOff)
{
  const float* pdist = (const float*)(g_scratch + pdOff);
  const int*   pidx  = (const int*)  (g_scratch + piOff);
  int*         idxOut= (int*)(g_scratch + idxOff);
  int t = blockIdx.x*64 + threadIdx.x;
  int b = t >> 12, n = t & 4095;
  KDECL;
  for (int cc=0; cc<16; ++cc){
    size_t o = ((size_t)((b*16 + cc)*NP + n))*16;
    #pragma unroll 1
    for (int j=0;j<16;j++){
      float pd = pdist[o+j];
      if (pd >= 1.0e38f) break;          // sentinel
      KINS(pd, pidx[o+j]);
    }
  }
  idxOut[t*16+ 0]=i0;  idxOut[t*16+ 1]=i1;  idxOut[t*16+ 2]=i2;  idxOut[t*16+ 3]=i3;
  idxOut[t*16+ 4]=i4;  idxOut[t*16+ 5]=i5;  idxOut[t*16+ 6]=i6;  idxOut[t*16+ 7]=i7;
  idxOut[t*16+ 8]=i8;  idxOut[t*16+ 9]=i9;  idxOut[t*16+10]=i10; idxOut[t*16+11]=i11;
  idxOut[t*16+12]=i12; idxOut[t*16+13]=i13; idxOut[t*16+14]=i14; idxOut[t*16+15]=i15;
}

// ---------------- embedding conv1 (Cin=9), output-split ----------------
__global__ __launch_bounds__(256) void emb1_kernel(const float* __restrict__ in,
                                                   const float* __restrict__ w1,
                                                   const float* __restrict__ s1,
                                                   const float* __restrict__ b1,
                                                   unsigned x1Off)
{
  unsigned short* x1 = (unsigned short*)(g_scratch + x1Off);
  int og = blockIdx.y*32;
  __shared__ float wf[32*9], sf[32], bf_[32];
  for (int i = threadIdx.x; i < 32*9; i += 256) wf[i] = w1[og*9 + i];
  if (threadIdx.x < 32){ sf[threadIdx.x]=s1[og+threadIdx.x]; bf_[threadIdx.x]=b1[og+threadIdx.x]; }
  __syncthreads();
  int t = blockIdx.x*256 + threadIdx.x;
  int b = t >> 12, n = t & 4095;
  float v[9];
  #pragma unroll
  for (int c=0;c<9;c++) v[c] = in[((size_t)b*9 + c)*NP + n];
  for (int o=0;o<32;o+=2){
    float a0=0.f, a1=0.f;
    #pragma unroll
    for (int c=0;c<9;c++){ a0 += wf[o*9+c]*v[c]; a1 += wf[(o+1)*9+c]*v[c]; }
    a0 = fmaxf(sf[o]*a0 + bf_[o], 0.f);
    a1 = fmaxf(sf[o+1]*a1 + bf_[o+1], 0.f);
    unsigned pk = (unsigned)f2bf(a0) | ((unsigned)f2bf(a1) << 16);
    *(unsigned*)(x1 + (size_t)t*128 + og + o) = pk;
  }
}

// ---------------- generic token-major MFMA GEMM (bf16 in/out) ----------------
enum { EPI_PLAIN=0, EPI_RELU_SB=1, EPI_RES=2, EPI_LEAKY=3, EPI_CLS=4 };

template<int EPI, bool EXB>
__device__ __forceinline__ void gemm_body(
    int M0, int T0,
    const unsigned short* W, const unsigned short* X, unsigned short* out,
    int Xstride, int Xoff, int outStride, int outOff,
    const float* sPtr, const float* bPtr,
    const float* extraIn, unsigned extraOffB, int extraStride,
    unsigned resOffB, int resStride, int resOff,
    int K, int Astride, int lane)
{
  int r = lane & 15, q = lane >> 4;
  f32x4 acc[4][4];
  #pragma unroll
  for (int i=0;i<4;i++)
    #pragma unroll
    for (int j=0;j<4;j++)
      #pragma unroll
      for (int u=0;u<4;u++) acc[i][j][u] = 0.f;

  const unsigned short* Arow[4]; const unsigned short* Brow[4];
  #pragma unroll
  for (int i=0;i<4;i++) Arow[i] = W + (size_t)(M0 + i*16 + r)*Astride + q*8;
  #pragma unroll
  for (int j=0;j<4;j++) Brow[j] = X + (size_t)(T0 + j*16 + r)*Xstride + Xoff + q*8;

  for (int k0=0; k0<K; k0+=32){
    short8 a[4], bfr[4];
    #pragma unroll
    for (int i=0;i<4;i++) a[i]   = *(const short8*)(Arow[i] + k0);
    #pragma unroll
    for (int j=0;j<4;j++) bfr[j] = *(const short8*)(Brow[j] + k0);
    #pragma unroll
    for (int i=0;i<4;i++)
      #pragma unroll
      for (int j=0;j<4;j++)
        acc[i][j] = __builtin_amdgcn_mfma_f32_16x16x32_bf16(a[i], bfr[j], acc[i][j], 0, 0, 0);
  }

  // epilogue: D layout col=lane&15 (token), row=q*4+reg (channel)
  #pragma unroll
  for (int i=0;i<4;i++){
    int m = M0 + i*16 + q*4;
    float sv[4], bv[4];
    if constexpr (EPI != EPI_PLAIN){
      #pragma unroll
      for (int u=0;u<4;u++){ sv[u]=sPtr[m+u]; bv[u]=bPtr[m+u]; }
    }
    #pragma unroll
    for (int j=0;j<4;j++){
      int token = T0 + j*16 + r;
      float ex[4];
      if constexpr (EPI == EPI_CLS){
        int bb = token >> 12;
        #pragma unroll
        for (int u=0;u<4;u++)
          ex[u] = EXB ? extraIn[bb*extraStride + m + u]
                      : ((const float*)(g_scratch + extraOffB))[bb*extraStride + m + u];
      }
      float resv[4];
      if constexpr (EPI == EPI_RES){
        const unsigned short* resPtr = (const unsigned short*)(g_scratch + resOffB);
        ushort4v rv = *(const ushort4v*)(resPtr + (size_t)token*resStride + resOff + m);
        #pragma unroll
        for (int u=0;u<4;u++) resv[u]=bf2f(rv[u]);
      }
      ushort4v ov;
      #pragma unroll
      for (int u=0;u<4;u++){
        float a = acc[i][j][u];
        float vo;
        if constexpr (EPI == EPI_PLAIN)        vo = a;
        else if constexpr (EPI == EPI_RELU_SB) vo = fmaxf(sv[u]*a + bv[u], 0.f);
        else if constexpr (EPI == EPI_RES)     vo = resv[u] + fmaxf(sv[u]*a + bv[u], 0.f);
        else if constexpr (EPI == EPI_LEAKY){  float tt = sv[u]*a + bv[u]; vo = tt>0.f ? tt : 0.2f*tt; }
        else { vo = fmaxf(sv[u]*(a + ex[u]) + bv[u], 0.f); }
        ov[u] = f2bf(vo);
      }
      *(ushort4v*)(out + (size_t)token*outStride + outOff + m) = ov;
    }
  }
}

// 4-wave 128Mx128T (fuse, cls1)
template<int EPI, bool EXB>
__global__ __launch_bounds__(256) void gemm_tok(
    unsigned W0off, unsigned W1off, unsigned W2off,
    unsigned O0off, unsigned O1off, unsigned O2off,
    unsigned XoffB, int Xstride, int Xoff,
    int outStride, int outOff,
    const float* sPtr, const float* bPtr,
    const float* extraIn, unsigned extraOffB, int extraStride,
    unsigned resOffB, int resStride, int resOff,
    int K, int Astride)
{
  const unsigned short* X = (const unsigned short*)(g_scratch + XoffB);
  unsigned wOffB   = (blockIdx.z==0) ? W0off : ((blockIdx.z==1) ? W1off : W2off);
  unsigned outOffB = (blockIdx.z==0) ? O0off : ((blockIdx.z==1) ? O1off : O2off);
  const unsigned short* W = (const unsigned short*)(g_scratch + wOffB);
  unsigned short* out = (unsigned short*)(g_scratch + outOffB);
  int lane = threadIdx.x & 63, wave = threadIdx.x >> 6;
  int M0 = blockIdx.x*128 + (wave>>1)*64;
  int T0 = blockIdx.y*128 + (wave&1)*64;
  gemm_body<EPI,EXB>(M0, T0, W, X, out, Xstride, Xoff, outStride, outOff,
                     sPtr, bPtr, extraIn, extraOffB, extraStride,
                     resOffB, resStride, resOff, K, Astride, lane);
}

// 2-wave 64Mx128T (emb2, qkv, wo, cls2)
template<int EPI, bool EXB>
__global__ __launch_bounds__(128) void gemm_small(
    unsigned W0off, unsigned W1off, unsigned W2off,
    unsigned O0off, unsigned O1off, unsigned O2off,
    unsigned XoffB, int Xstride, int Xoff,
    int outStride, int outOff,
    const float* sPtr, const float* bPtr,
    const float* extraIn, unsigned extraOffB, int extraStride,
    unsigned resOffB, int resStride, int resOff,
    int K, int Astride)
{
  const unsigned short* X = (const unsigned short*)(g_scratch + XoffB);
  unsigned wOffB   = (blockIdx.z==0) ? W0off : ((blockIdx.z==1) ? W1off : W2off);
  unsigned outOffB = (blockIdx.z==0) ? O0off : ((blockIdx.z==1) ? O1off : O2off);
  const unsigned short* W = (const unsigned short*)(g_scratch + wOffB);
  unsigned short* out = (unsigned short*)(g_scratch + outOffB);
  int lane = threadIdx.x & 63, wave = threadIdx.x >> 6;  // 0/1
  int M0 = blockIdx.x*64;
  int T0 = blockIdx.y*128 + wave*64;
  gemm_body<EPI,EXB>(M0, T0, W, X, out, Xstride, Xoff, outStride, outOff,
                     sPtr, bPtr, extraIn, extraOffB, extraStride,
                     resOffB, resStride, resOff, K, Astride, lane);
}

// ---------------- attention (one wave per query, 2 channels/lane) ----------------
__global__ __launch_bounds__(256) void attn_kernel(
  unsigned qOff, unsigned kOff, unsigned vOff, unsigned idxOff,
  const float* __restrict__ in, const float* __restrict__ wpos,
  unsigned aggOff)
{
  const unsigned short* Q  = (const unsigned short*)(g_scratch + qOff);
  const unsigned short* Kf = (const unsigned short*)(g_scratch + kOff);
  const unsigned short* V  = (const unsigned short*)(g_scratch + vOff);
  const int* idx           = (const int*)(g_scratch + idxOff);
  unsigned short* agg      = (unsigned short*)(g_scratch + aggOff);

  int lane = threadIdx.x & 63, wv = threadIdx.x >> 6;
  int t = blockIdx.x*4 + wv;
  int b = t >> 12, n = t & 4095;
  const float* xb = in + (size_t)b*9*NP;
  int c0 = lane*2;

  unsigned qv = *(const unsigned*)(Q + (size_t)t*128 + c0);
  float q0 = bf2f((unsigned short)(qv & 0xffff)), q1 = bf2f((unsigned short)(qv >> 16));
  float xn = xb[n], yn = xb[NP+n], zn = xb[2*NP+n];
  float wp00=wpos[c0*3+0],     wp01=wpos[c0*3+1],     wp02=wpos[c0*3+2];
  float wp10=wpos[(c0+1)*3+0], wp11=wpos[(c0+1)*3+1], wp12=wpos[(c0+1)*3+2];

  int mi[16]; float s[16];
  #pragma unroll
  for (int j=0;j<16;j++) mi[j] = idx[(size_t)t*16 + j] & 4095;  // mask: never OOB
  #pragma unroll
  for (int j=0;j<16;j++){
    unsigned kv = *(const unsigned*)(Kf + ((size_t)(b<<12) + mi[j])*128 + c0);
    float p = q0*bf2f((unsigned short)(kv & 0xffff)) + q1*bf2f((unsigned short)(kv >> 16));
    #pragma unroll
    for (int o=32;o>=1;o>>=1) p += __shfl_xor(p, o, 64);
    s[j] = p;
  }
  const float scale = 0.08838834764831845f; // 1/sqrt(128)
  float mx = s[0];
  #pragma unroll
  for (int j=1;j<16;j++) mx = fmaxf(mx, s[j]);
  float e[16], sum = 0.f;
  #pragma unroll
  for (int j=0;j<16;j++){ e[j] = __expf((s[j]-mx)*scale); sum += e[j]; }
  float inv = 1.f / sum;

  float a0=0.f, a1=0.f;
  #pragma unroll
  for (int j=0;j<16;j++){
    int m = mi[j];
    float w = e[j]*inv;
    unsigned vv = *(const unsigned*)(V + ((size_t)(b<<12) + m)*128 + c0);
    float rx = xn - xb[m];
    float ry = yn - xb[NP+m];
    float rz = zn - xb[2*NP+m];
    float p0 = wp00*rx + wp01*ry + wp02*rz;
    float p1 = wp10*rx + wp11*ry + wp12*rz;
    a0 += w*(bf2f((unsigned short)(vv & 0xffff)) + p0);
    a1 += w*(bf2f((unsigned short)(vv >> 16)) + p1);
  }
  unsigned pk = (unsigned)f2bf(a0) | ((unsigned)f2bf(a1) << 16);
  *(unsigned*)(agg + (size_t)t*128 + c0) = pk;
}

// ---------------- max/mean pool over tokens (two-stage) ----------------
__global__ __launch_bounds__(256) void pool_part(unsigned xfOff, unsigned gpOff)
{
  const unsigned short* xf = (const unsigned short*)(g_scratch + xfOff);
  float* gp = (float*)(g_scratch + gpOff);   // [b][seg][2][1024]
  int b = blockIdx.x >> 7, cblk = (blockIdx.x >> 3) & 15, seg = blockIdx.x & 7;
  int cl = threadIdx.x & 63, tg = threadIdx.x >> 6;
  int c = cblk*64 + cl;
  float mx = -3.0e38f, sm = 0.f;
  for (int n = seg*512 + tg; n < (seg+1)*512; n += 4){
    float v = bf2f(xf[((size_t)(b<<12) + n)*1024 + c]);
    mx = fmaxf(mx, v); sm += v;
  }
  __shared__ float smx[4][64], ssm[4][64];
  smx[tg][cl]=mx; ssm[tg][cl]=sm;
  __syncthreads();
  if (tg==0){
    #pragma unroll
    for (int k=1;k<4;k++){ mx = fmaxf(mx, smx[k][cl]); sm += ssm[k][cl]; }
    gp[((b*8 + seg)*2 + 0)*1024 + c] = mx;
    gp[((b*8 + seg)*2 + 1)*1024 + c] = sm;
  }
}
__global__ __launch_bounds__(256) void pool_final(unsigned gpOff, unsigned gOff)
{
  const float* gp = (const float*)(g_scratch + gpOff);
  float* g = (float*)(g_scratch + gOff);
  int b = blockIdx.x;
  for (int c = threadIdx.x; c < 1024; c += 256){
    float mx = -3.0e38f, sm = 0.f;
    #pragma unroll
    for (int seg=0; seg<8; ++seg){
      mx = fmaxf(mx, gp[((b*8 + seg)*2 + 0)*1024 + c]);
      sm += gp[((b*8 + seg)*2 + 1)*1024 + c];
    }
    g[b*2048 + c] = mx;
    g[b*2048 + 1024 + c] = sm * (1.f/4096.f);
  }
}

// gb[b][o] = cls_bias1[o] + sum_c W1[o][1024+c]*g[b][c]
__global__ __launch_bounds__(256) void gterm_kernel(const float* __restrict__ w1,
                                                    const float* __restrict__ bias1,
                                                    unsigned gOff, unsigned gbOff)
{
  const float* g = (const float*)(g_scratch + gOff);
  float* gb = (float*)(g_scratch + gbOff);
  int b = blockIdx.x >> 3, og = (blockIdx.x & 7)*64;
  int ol = threadIdx.x & 63, cq = threadIdx.x >> 6;
  int o = og + ol;
  const float* wrow = w1 + (size_t)o*3072 + 1024 + cq*512;
  const float* gp = g + b*2048 + cq*512;
  float acc = 0.f;
  for (int c=0;c<512;c+=4){
    float4 wv4 = *(const float4*)(wrow + c);
    acc += wv4.x*gp[c] + wv4.y*gp[c+1] + wv4.z*gp[c+2] + wv4.w*gp[c+3];
  }
  __shared__ float sred[4][64];
  sred[cq][ol] = acc;
  __syncthreads();
  if (cq==0){
    acc += sred[1][ol] + sred[2][ol] + sred[3][ol];
    gb[b*512 + o] = acc + bias1[o];
  }
}

// ---------------- classifier head (O=13), fp32 out ----------------
__global__ __launch_bounds__(256) void cls3_kernel(unsigned c2Off,
                                                   const float* __restrict__ w3,
                                                   const float* __restrict__ bias3,
                                                   float* __restrict__ outp)
{
  const unsigned short* c2 = (const unsigned short*)(g_scratch + c2Off);
  __shared__ float wf[13*256];
  __shared__ float bf3[13];
  for (int i=threadIdx.x;i<13*256;i+=256) wf[i]=w3[i];
  if (threadIdx.x < 13) bf3[threadIdx.x]=bias3[threadIdx.x];
  __syncthreads();
  int lane = threadIdx.x & 63, wv = threadIdx.x >> 6;
  int tl = lane >> 2, cq = lane & 3;
  int t = blockIdx.x*64 + wv*16 + tl;
  const unsigned short* xrow = c2 + (size_t)t*256 + cq*64;
  float acc[13];
  #pragma unroll
  for (int o=0;o<13;o++) acc[o]=0.f;
  for (int c=0;c<64;c+=8){
    short8 xv = *(const short8*)(xrow + c);
    float xs[8];
    #pragma unroll
    for (int u=0;u<8;u++) xs[u]=bf2f((unsigned short)xv[u]);
    #pragma unroll
    for (int o=0;o<13;o++){
      const float* wr = wf + o*256 + cq*64 + c;
      #pragma unroll
      for (int u=0;u<8;u++) acc[o] += wr[u]*xs[u];
    }
  }
  #pragma unroll
  for (int o=0;o<13;o++){
    acc[o] += __shfl_xor(acc[o], 1, 64);
    acc[o] += __shfl_xor(acc[o], 2, 64);
  }
  if (cq==0){
    int b = t >> 12, n = t & 4095;
    #pragma unroll
    for (int o=0;o<13;o++)
      outp[((size_t)b*13 + o)*NP + n] = acc[o] + bf3[o];
  }
}

// ---------------- launch ----------------
extern "C" void kernel_launch(void* const* d_in, const int* in_sizes, int n_in,
                              void* d_out, int out_size, void* d_ws, size_t ws_size,
                              hipStream_t stream) {
  (void)in_sizes; (void)n_in; (void)out_size; (void)d_ws; (void)ws_size;
  const float* in      = (const float*)d_in[0];
  const float* emb_w1  = (const float*)d_in[1];
  const float* emb_s1  = (const float*)d_in[2];
  const float* emb_b1  = (const float*)d_in[3];
  const float* emb_w2  = (const float*)d_in[4];
  const float* emb_s2  = (const float*)d_in[5];
  const float* emb_b2  = (const float*)d_in[6];
  const float* blk_wq  = (const float*)d_in[7];
  const float* blk_wk  = (const float*)d_in[8];
  const float* blk_wv  = (const float*)d_in[9];
  const float* blk_wpos= (const float*)d_in[10];
  const float* blk_wo  = (const float*)d_in[11];
  const float* blk_s   = (const float*)d_in[12];
  const float* blk_b   = (const float*)d_in[13];
  const float* fuse_w  = (const float*)d_in[14];
  const float* fuse_s  = (const float*)d_in[15];
  const float* fuse_b  = (const float*)d_in[16];
  const float* cls_w1  = (const float*)d_in[17];
  const float* cls_b1  = (const float*)d_in[18];
  const float* cls_s1  = (const float*)d_in[19];
  const float* cls_sh1 = (const float*)d_in[20];
  const float* cls_w2  = (const float*)d_in[21];
  const float* cls_b2  = (const float*)d_in[22];
  const float* cls_s2  = (const float*)d_in[23];
  const float* cls_sh2 = (const float*)d_in[24];
  const float* cls_w3  = (const float*)d_in[25];
  const float* cls_b3  = (const float*)d_in[26];

  // byte offsets into g_scratch
  const unsigned MB = 1u<<20, KB = 1024u;
  const unsigned OFF_IDX   = 0;                 // 1 MB   int idx[T][16]
  const unsigned OFF_WQ    = 1*MB;              // 96 KB  bf16 (3,128,128)
  const unsigned OFF_WK    = 1*MB + 128*KB;     // 96 KB
  const unsigned OFF_WV    = 1*MB + 256*KB;     // 96 KB
  const unsigned OFF_WO    = 1*MB + 384*KB;     // 96 KB
  const unsigned OFF_WEMB2 = 1*MB + 512*KB;     // 32 KB  bf16 (128,128)
  const unsigned OFF_WFUSE = 1*MB + 576*KB;     // 768 KB bf16 (1024,384)
  const unsigned OFF_WW1   = 3*MB;              // 1 MB   bf16 (512,1024) x-half
  const unsigned OFF_WW2   = 4*MB;              // 256 KB bf16 (256,512)
  const unsigned OFF_X1    = 5*MB;              // 4 MB   bf16 (T,128)
  const unsigned OFF_X0    = 9*MB;              // 4 MB   bf16 (T,128)
  const unsigned OFF_XCAT  = 13*MB;             // 12 MB  bf16 (T,384)
  const unsigned OFF_QB    = 25*MB;             // 4 MB
  const unsigned OFF_KB    = 29*MB;             // 4 MB
  const unsigned OFF_VB    = 33*MB;             // 4 MB
  const unsigned OFF_AGG   = 37*MB;             // 4 MB
  const unsigned OFF_XF    = 41*MB;             // 32 MB  bf16 (T,1024)
  const unsigned OFF_C1    = 73*MB;             // 16 MB  bf16 (T,512)
  const unsigned OFF_C2    = 89*MB;             // 8 MB   bf16 (T,256)
  const unsigned OFF_G     = 97*MB;             // 32 KB  f32 (B,2048)
  const unsigned OFF_GB    = 97*MB + 64*KB;     // 8 KB   f32 (B,512)
  const unsigned OFF_GP    = 97*MB + 128*KB;    // 256 KB f32 pool partials
  const unsigned OFF_THR   = 97*MB + 512*KB;    // 64 KB  f32 thr[T]
  const unsigned OFF_PD    = 98*MB;             // 16 MB  f32 knn bound vals / p2 dists
  const unsigned OFF_PI    = 114*MB;            // 16 MB  int knn idx (p2)
  float* outp = (float*)d_out;                  // (B,13,N) f32

  // 0: fused weight conversion prepass (fp32 -> bf16 into scratch)
  CvtArgs ca;
  ca.src[0]=emb_w2;  ca.dstOff[0]=OFF_WEMB2; ca.n[0]=128*128;
  ca.src[1]=blk_wq;  ca.dstOff[1]=OFF_WQ;    ca.n[1]=3*128*128;
  ca.src[2]=blk_wk;  ca.dstOff[2]=OFF_WK;    ca.n[2]=3*128*128;
  ca.src[3]=blk_wv;  ca.dstOff[3]=OFF_WV;    ca.n[3]=3*128*128;
  ca.src[4]=blk_wo;  ca.dstOff[4]=OFF_WO;    ca.n[4]=3*128*128;
  ca.src[5]=fuse_w;  ca.dstOff[5]=OFF_WFUSE; ca.n[5]=1024*384;
  ca.src[6]=cls_w2;  ca.dstOff[6]=OFF_WW2;   ca.n[6]=256*512;
  ca.src[7]=cls_w1;  ca.dstOff[7]=OFF_WW1;   ca.n[7]=512*1024;
  cvt_all<<<dim3(64,8), 256, 0, stream>>>(ca);

  // 1-4: KNN (cheap-threshold two-pass)
  knn_p1<<<dim3(16,16,4), 256, 0, stream>>>(in, OFF_PD);
  knn_thr<<<dim3(64), 256, 0, stream>>>(OFF_PD, OFF_THR);
  knn_p2<<<dim3(16,16,4), 256, 0, stream>>>(in, OFF_THR, OFF_PD, OFF_PI);
  knn_mrg<<<dim3(256), 64, 0, stream>>>(OFF_PD, OFF_PI, OFF_IDX);
  // 5-6: embedding
  emb1_kernel<<<dim3(64,4), 256, 0, stream>>>(in, emb_w1, emb_s1, emb_b1, OFF_X1);
  gemm_small<EPI_RELU_SB,false><<<dim3(2,128,1), 128, 0, stream>>>(
      OFF_WEMB2, OFF_WEMB2, OFF_WEMB2, OFF_X0, OFF_X0, OFF_X0,
      OFF_X1, 128, 0, 128, 0, emb_s2, emb_b2,
      nullptr, 0, 0, 0, 0, 0, 128, 128);
  // 7-9: transformer blocks
  for (int i=0;i<3;i++){
    unsigned wq = OFF_WQ + i*32768, wk = OFF_WK + i*32768;
    unsigned wv = OFF_WV + i*32768, wo = OFF_WO + i*32768;
    const float* wp = blk_wpos + i*128*3;
    const float* si = blk_s + i*128;
    const float* bi = blk_b + i*128;
    unsigned XiOff = (i==0) ? OFF_X0 : OFF_XCAT;
    int Xs = (i==0) ? 128 : 384;
    int Xo = (i==0) ? 0 : (i-1)*128;
    gemm_small<EPI_PLAIN,false><<<dim3(2,128,3), 128, 0, stream>>>(
        wq, wk, wv, OFF_QB, OFF_KB, OFF_VB,
        XiOff, Xs, Xo, 128, 0, nullptr, nullptr,
        nullptr, 0, 0, 0, 0, 0, 128, 128);
    attn_kernel<<<dim3(4096), 256, 0, stream>>>(OFF_QB, OFF_KB, OFF_VB, OFF_IDX, in, wp, OFF_AGG);
    gemm_small<EPI_RES,false><<<dim3(2,128,1), 128, 0, stream>>>(
        wo, wo, wo, OFF_XCAT, OFF_XCAT, OFF_XCAT,
        OFF_AGG, 128, 0, 384, i*128, si, bi,
        nullptr, 0, 0, XiOff, Xs, Xo, 128, 128);
  }
  // 10: fuse (leaky relu)
  gemm_tok<EPI_LEAKY,false><<<dim3(8,128,1), 256, 0, stream>>>(
      OFF_WFUSE, OFF_WFUSE, OFF_WFUSE, OFF_XF, OFF_XF, OFF_XF,
      OFF_XCAT, 384, 0, 1024, 0, fuse_s, fuse_b,
      nullptr, 0, 0, 0, 0, 0, 384, 384);
  // 11-13: pooling (two-stage) + broadcast-g term of cls1 (fp32)
  pool_part<<<dim3(512), 256, 0, stream>>>(OFF_XF, OFF_GP);
  pool_final<<<dim3(4), 256, 0, stream>>>(OFF_GP, OFF_G);
  gterm_kernel<<<dim3(32), 256, 0, stream>>>(cls_w1, cls_b1, OFF_G, OFF_GB);
  // 14: cls1 (K=1024 x-half of W1; gb = W1[:,1024:]@g + bias1 as extra)
  gemm_tok<EPI_CLS,false><<<dim3(4,128,1), 256, 0, stream>>>(
      OFF_WW1, OFF_WW1, OFF_WW1, OFF_C1, OFF_C1, OFF_C1,
      OFF_XF, 1024, 0, 512, 0, cls_s1, cls_sh1,
      nullptr, OFF_GB, 512, 0, 0, 0, 1024, 1024);
  // 15: cls2
  gemm_small<EPI_CLS,true><<<dim3(4,128,1), 128, 0, stream>>>(
      OFF_WW2, OFF_WW2, OFF_WW2, OFF_C2, OFF_C2, OFF_C2,
      OFF_C1, 512, 0, 256, 0, cls_s2, cls_sh2,
      cls_b2, 0, 0, 0, 0, 0, 512, 512);
  // 16: cls3 -> d_out (fp32)
  cls3_kernel<<<dim3(256), 256, 0, stream>>>(OFF_C2, cls_w3, cls_b3, outp);
}

// Round 12
// 601.685 us; speedup vs baseline: 1.9104x; 1.0146x over previous
//
#include <hip/hip_runtime.h>

// PVDST semseg, MI355X/gfx950. FP32 I/O. Round-12: GEMM latency + L2 fixes.
//   - R11 post-mortem: cls1 gemm 70us with MfmaUtil 9%, VALUBusy 20%, HBM 15%
//     -> latency-bound (2048 waves fixed by 64x64 wave tile = 25% occ max;
//     8 loads then 16 MFMAs serialized) + 2x XF over-fetch (FETCH 66.6 MB,
//     4 M-blocks/token-tile land on different XCDs, private L2s re-fetch).
//   - Fix 1: 2-stage software-pipelined K-loop (prefetch k+1 frags during
//     k's MFMAs) in shared gemm_body -> all GEMM call sites.
//   - Fix 2: XCD swizzle in gemm_tok (gy=128): XCD c (by %8 heuristic) gets
//     a 16-tile y-band = 4 MB X = one XCD-L2.
// KNN cheap-threshold two-pass unchanged (R11, passed absmax 2.9e-3).

#define NB 4
#define NP 4096
#define NT 16384   // NB*NP tokens

#define SCRATCH_BYTES (132u*1024u*1024u)
__device__ __align__(256) unsigned char g_scratch[SCRATCH_BYTES];

typedef __attribute__((ext_vector_type(8))) short short8;   // 8 x bf16 MFMA frag
typedef __attribute__((ext_vector_type(4))) float f32x4;    // MFMA acc
typedef __attribute__((ext_vector_type(4))) unsigned short ushort4v;

__device__ __forceinline__ float bf2f(unsigned short u){
  unsigned int v = ((unsigned int)u) << 16;
  return __builtin_bit_cast(float, v);
}
__device__ __forceinline__ unsigned short f2bf(float f){
  unsigned int x = __builtin_bit_cast(unsigned int, f);
  x += 0x7fffu + ((x >> 16) & 1u);     // RNE
  return (unsigned short)(x >> 16);
}
// numpy-matched: ((x*x)+(y*y))+(z*z), each op rounded (no fma contraction)
__device__ __forceinline__ float sq3(float x, float y, float z){
  return __fadd_rn(__fadd_rn(__fmul_rn(x,x), __fmul_rn(y,y)), __fmul_rn(z,z));
}

// sorted-4 insert: 7 native min/max, no masks
#define KINS4(a0,a1,a2,a3,dd) do{ float _d=(dd);\
  a3=fminf(fmaxf(a2,_d),a3); a2=fminf(fmaxf(a1,_d),a2);\
  a1=fminf(fmaxf(a0,_d),a1); a0=fminf(a0,_d);}while(0)

// dist-only sorted-ascending top-16 (thr kernel)
#define KDECLD float d0=3.0e38f,d1=3.0e38f,d2=3.0e38f,d3=3.0e38f,d4=3.0e38f,\
  d5=3.0e38f,d6=3.0e38f,d7=3.0e38f,d8=3.0e38f,d9=3.0e38f,d10=3.0e38f,\
  d11=3.0e38f,d12=3.0e38f,d13=3.0e38f,d14=3.0e38f,d15=3.0e38f
#define KINSD(dd) do{ float _d=(dd); \
  d15=fminf(fmaxf(d14,_d),d15); d14=fminf(fmaxf(d13,_d),d14); \
  d13=fminf(fmaxf(d12,_d),d13); d12=fminf(fmaxf(d11,_d),d12); \
  d11=fminf(fmaxf(d10,_d),d11); d10=fminf(fmaxf(d9 ,_d),d10); \
  d9 =fminf(fmaxf(d8 ,_d),d9 ); d8 =fminf(fmaxf(d7 ,_d),d8 ); \
  d7 =fminf(fmaxf(d6 ,_d),d7 ); d6 =fminf(fmaxf(d5 ,_d),d6 ); \
  d5 =fminf(fmaxf(d4 ,_d),d5 ); d4 =fminf(fmaxf(d3 ,_d),d4 ); \
  d3 =fminf(fmaxf(d2 ,_d),d3 ); d2 =fminf(fmaxf(d1 ,_d),d2 ); \
  d1 =fminf(fmaxf(d0 ,_d),d1 ); d0 =fminf(d0,_d); }while(0)

// full (dist,idx) stable insert (merge only; strict < => lower index wins)
#define KDECL KDECLD; int i0=0,i1=0,i2=0,i3=0,i4=0,i5=0,i6=0,i7=0,i8=0,\
  i9=0,i10=0,i11=0,i12=0,i13=0,i14=0,i15=0
#define KINS(dd,mm) do{ float _d=(dd); int _m=(mm); \
  bool c15 = _d < d15; \
  bool c14 = _d < d14;  i15 = c14 ? i14 : (c15 ? _m : i15);  d15 = fminf(fmaxf(d14,_d), d15); \
  bool c13 = _d < d13;  i14 = c13 ? i13 : (c14 ? _m : i14);  d14 = fminf(fmaxf(d13,_d), d14); \
  bool c12 = _d < d12;  i13 = c12 ? i12 : (c13 ? _m : i13);  d13 = fminf(fmaxf(d12,_d), d13); \
  bool c11 = _d < d11;  i12 = c11 ? i11 : (c12 ? _m : i12);  d12 = fminf(fmaxf(d11,_d), d12); \
  bool c10 = _d < d10;  i11 = c10 ? i10 : (c11 ? _m : i11);  d11 = fminf(fmaxf(d10,_d), d11); \
  bool c9  = _d < d9;   i10 = c9  ? i9  : (c10 ? _m : i10);  d10 = fminf(fmaxf(d9 ,_d), d10); \
  bool c8  = _d < d8;   i9  = c8  ? i8  : (c9  ? _m : i9 );  d9  = fminf(fmaxf(d8 ,_d), d9 ); \
  bool c7  = _d < d7;   i8  = c7  ? i7  : (c8  ? _m : i8 );  d8  = fminf(fmaxf(d7 ,_d), d8 ); \
  bool c6  = _d < d6;   i7  = c6  ? i6  : (c7  ? _m : i7 );  d7  = fminf(fmaxf(d6 ,_d), d7 ); \
  bool c5  = _d < d5;   i6  = c5  ? i5  : (c6  ? _m : i6 );  d6  = fminf(fmaxf(d5 ,_d), d6 ); \
  bool c4  = _d < d4;   i5  = c4  ? i4  : (c5  ? _m : i5 );  d5  = fminf(fmaxf(d4 ,_d), d5 ); \
  bool c3  = _d < d3;   i4  = c3  ? i3  : (c4  ? _m : i4 );  d4  = fminf(fmaxf(d3 ,_d), d4 ); \
  bool c2  = _d < d2;   i3  = c2  ? i2  : (c3  ? _m : i3 );  d3  = fminf(fmaxf(d2 ,_d), d3 ); \
  bool c1  = _d < d1;   i2  = c1  ? i1  : (c2  ? _m : i2 );  d2  = fminf(fmaxf(d1 ,_d), d2 ); \
  bool c0  = _d < d0;   i1  = c0  ? i0  : (c1  ? _m : i1 );  d1  = fminf(fmaxf(d0 ,_d), d1 ); \
  i0 = c0 ? _m : i0;  d0 = fminf(d0,_d); }while(0)

// ---------------- fused weight fp32 -> bf16 conversion prepass ----------------
struct CvtArgs {
  const float* src[8];
  unsigned dstOff[8];
  int n[8];
};
__global__ __launch_bounds__(256) void cvt_all(CvtArgs a)
{
  int y = blockIdx.y;
  const float* src = a.src[y];
  unsigned short* dst = (unsigned short*)(g_scratch + a.dstOff[y]);
  int n = a.n[y];
  if (y == 7){
    for (int i = blockIdx.x*256 + threadIdx.x; i < n; i += gridDim.x*256){
      int r = i >> 10, c = i & 1023;
      dst[i] = f2bf(src[(size_t)r*3072 + c]);
    }
  } else {
    for (int i = blockIdx.x*256 + threadIdx.x; i < n; i += gridDim.x*256)
      dst[i] = f2bf(src[i]);
  }
}

// ---------------- KNN pass1: 4x sorted-4 bound lists, fma dist ----------------
__global__ __launch_bounds__(256) void knn_p1(const float* __restrict__ in,
                                              unsigned pdOff)
{
  float* pdist = (float*)(g_scratch + pdOff);
  __shared__ float4 sp[256];
  int b = blockIdx.z, qc = blockIdx.x, cc = blockIdx.y;
  const float* xb = in + (size_t)b*9*NP;
  int base = cc*256;
  {
    int i = threadIdx.x;
    float x = xb[base+i], y = xb[NP+base+i], z = xb[2*NP+base+i];
    sp[i] = make_float4(x,y,z, x*x+y*y+z*z);
  }
  __syncthreads();
  int n = qc*256 + threadIdx.x;
  float xn=xb[n], yn=xb[NP+n], zn=xb[2*NP+n];
  float sqn = xn*xn + yn*yn + zn*zn;
  float A0=3e38f,A1=3e38f,A2=3e38f,A3=3e38f;
  float B0=3e38f,B1=3e38f,B2=3e38f,B3=3e38f;
  float C0=3e38f,C1=3e38f,C2=3e38f,C3=3e38f;
  float D0=3e38f,D1=3e38f,D2=3e38f,D3=3e38f;
  for (int mm=0; mm<256; mm+=4){
    float4 p0 = sp[mm], p1 = sp[mm+1], p2 = sp[mm+2], p3 = sp[mm+3];
    float e0 = sqn + p0.w - 2.f*(xn*p0.x + yn*p0.y + zn*p0.z);
    float e1 = sqn + p1.w - 2.f*(xn*p1.x + yn*p1.y + zn*p1.z);
    float e2 = sqn + p2.w - 2.f*(xn*p2.x + yn*p2.y + zn*p2.z);
    float e3 = sqn + p3.w - 2.f*(xn*p3.x + yn*p3.y + zn*p3.z);
    KINS4(A0,A1,A2,A3,e0);
    KINS4(B0,B1,B2,B3,e1);
    KINS4(C0,C1,C2,C3,e2);
    KINS4(D0,D1,D2,D3,e3);
  }
  size_t ob = ((size_t)(b*16+cc)*16)*NP + n;
  pdist[ob+ 0*(size_t)NP]=A0; pdist[ob+ 1*(size_t)NP]=A1; pdist[ob+ 2*(size_t)NP]=A2; pdist[ob+ 3*(size_t)NP]=A3;
  pdist[ob+ 4*(size_t)NP]=B0; pdist[ob+ 5*(size_t)NP]=B1; pdist[ob+ 6*(size_t)NP]=B2; pdist[ob+ 7*(size_t)NP]=B3;
  pdist[ob+ 8*(size_t)NP]=C0; pdist[ob+ 9*(size_t)NP]=C1; pdist[ob+10*(size_t)NP]=C2; pdist[ob+11*(size_t)NP]=C3;
  pdist[ob+12*(size_t)NP]=D0; pdist[ob+13*(size_t)NP]=D1; pdist[ob+14*(size_t)NP]=D2; pdist[ob+15*(size_t)NP]=D3;
}

// ---------------- KNN thr: 16th-smallest of the 256 bound values + margin ----
__global__ __launch_bounds__(256) void knn_thr(unsigned pdOff, unsigned thrOff)
{
  const float* pdist = (const float*)(g_scratch + pdOff);
  float* thr = (float*)(g_scratch + thrOff);
  int t = blockIdx.x*256 + threadIdx.x;
  int b = t >> 12, n = t & 4095;
  KDECLD;
  for (int cc=0; cc<16; ++cc){
    size_t ob = ((size_t)(b*16+cc)*16)*NP + n;
    #pragma unroll
    for (int j=0;j<16;j++){ KINSD(pdist[ob + (size_t)j*NP]); }
  }
  thr[t] = d15*1.000002f + 2e-4f;   // margin >> fma-vs-_rn error
}

// ---------------- KNN pass2: append qualifying (d,i), exact _rn dist --------
__global__ __launch_bounds__(256) void knn_p2(const float* __restrict__ in,
                                              unsigned thrOff, unsigned pdOff, unsigned piOff)
{
  const float* thr = (const float*)(g_scratch + thrOff);
  float* pdist = (float*)(g_scratch + pdOff);
  int*   pidx  = (int*)  (g_scratch + piOff);
  __shared__ float4 sp[256];
  int b = blockIdx.z, qc = blockIdx.x, cc = blockIdx.y;
  const float* xb = in + (size_t)b*9*NP;
  int base = cc*256;
  {
    int i = threadIdx.x;
    float x = xb[base+i], y = xb[NP+base+i], z = xb[2*NP+base+i];
    sp[i] = make_float4(x,y,z,sq3(x,y,z));
  }
  __syncthreads();
  int n = qc*256 + threadIdx.x;
  float xn=xb[n], yn=xb[NP+n], zn=xb[2*NP+n];
  float sqn = sq3(xn,yn,zn);
  float th = thr[(b<<12) + n];
  size_t o = ((size_t)((b*16 + cc)*NP + n))*16;
  int cnt = 0;
  for (int mm=0; mm<256; ++mm){
    float4 p = sp[mm];
    float dot = __fadd_rn(__fadd_rn(__fmul_rn(xn,p.x), __fmul_rn(yn,p.y)), __fmul_rn(zn,p.z));
    float d = __fsub_rn(__fadd_rn(sqn, p.w), __fmul_rn(2.0f, dot));
    if (d <= th && cnt < 16){
      pdist[o+cnt] = d;
      pidx[o+cnt] = base + mm;
      cnt++;
    }
  }
  if (cnt < 16) pdist[o+cnt] = 3.0e38f;   // sentinel terminator
}

// ---------------- KNN final merge (index-ordered sparse lists) ----------------
__global__ __launch_bounds__(64) void knn_mrg(unsigned pdOff, unsigned piOff, unsigned idxOff)
{
  const float* pdist = (const float*)(g_scratch + pdOff);
  const int*   pidx  = (const int*)  (g_scratch + piOff);
  int*         idxOut= (int*)(g_scratch + idxOff);
  int t = blockIdx.x*64 + threadIdx.x;
  int b = t >> 12, n = t & 4095;
  KDECL;
  for (int cc=0; cc<16; ++cc){
    size_t o = ((size_t)((b*16 + cc)*NP + n))*16;
    #pragma unroll 1
    for (int j=0;j<16;j++){
      float pd = pdist[o+j];
      if (pd >= 1.0e38f) break;          // sentinel
      KINS(pd, pidx[o+j]);
    }
  }
  idxOut[t*16+ 0]=i0;  idxOut[t*16+ 1]=i1;  idxOut[t*16+ 2]=i2;  idxOut[t*16+ 3]=i3;
  idxOut[t*16+ 4]=i4;  idxOut[t*16+ 5]=i5;  idxOut[t*16+ 6]=i6;  idxOut[t*16+ 7]=i7;
  idxOut[t*16+ 8]=i8;  idxOut[t*16+ 9]=i9;  idxOut[t*16+10]=i10; idxOut[t*16+11]=i11;
  idxOut[t*16+12]=i12; idxOut[t*16+13]=i13; idxOut[t*16+14]=i14; idxOut[t*16+15]=i15;
}

// ---------------- embedding conv1 (Cin=9), output-split ----------------
__global__ __launch_bounds__(256) void emb1_kernel(const float* __restrict__ in,
                                                   const float* __restrict__ w1,
                                                   const float* __restrict__ s1,
                                                   const float* __restrict__ b1,
                                                   unsigned x1Off)
{
  unsigned short* x1 = (unsigned short*)(g_scratch + x1Off);
  int og = blockIdx.y*32;
  __shared__ float wf[32*9], sf[32], bf_[32];
  for (int i = threadIdx.x; i < 32*9; i += 256) wf[i] = w1[og*9 + i];
  if (threadIdx.x < 32){ sf[threadIdx.x]=s1[og+threadIdx.x]; bf_[threadIdx.x]=b1[og+threadIdx.x]; }
  __syncthreads();
  int t = blockIdx.x*256 + threadIdx.x;
  int b = t >> 12, n = t & 4095;
  float v[9];
  #pragma unroll
  for (int c=0;c<9;c++) v[c] = in[((size_t)b*9 + c)*NP + n];
  for (int o=0;o<32;o+=2){
    float a0=0.f, a1=0.f;
    #pragma unroll
    for (int c=0;c<9;c++){ a0 += wf[o*9+c]*v[c]; a1 += wf[(o+1)*9+c]*v[c]; }
    a0 = fmaxf(sf[o]*a0 + bf_[o], 0.f);
    a1 = fmaxf(sf[o+1]*a1 + bf_[o+1], 0.f);
    unsigned pk = (unsigned)f2bf(a0) | ((unsigned)f2bf(a1) << 16);
    *(unsigned*)(x1 + (size_t)t*128 + og + o) = pk;
  }
}

// ---------------- generic token-major MFMA GEMM (bf16 in/out) ----------------
enum { EPI_PLAIN=0, EPI_RELU_SB=1, EPI_RES=2, EPI_LEAKY=3, EPI_CLS=4 };

template<int EPI, bool EXB>
__device__ __forceinline__ void gemm_body(
    int M0, int T0,
    const unsigned short* W, const unsigned short* X, unsigned short* out,
    int Xstride, int Xoff, int outStride, int outOff,
    const float* sPtr, const float* bPtr,
    const float* extraIn, unsigned extraOffB, int extraStride,
    unsigned resOffB, int resStride, int resOff,
    int K, int Astride, int lane)
{
  int r = lane & 15, q = lane >> 4;
  f32x4 acc[4][4];
  #pragma unroll
  for (int i=0;i<4;i++)
    #pragma unroll
    for (int j=0;j<4;j++)
      #pragma unroll
      for (int u=0;u<4;u++) acc[i][j][u] = 0.f;

  const unsigned short* Arow[4]; const unsigned short* Brow[4];
  #pragma unroll
  for (int i=0;i<4;i++) Arow[i] = W + (size_t)(M0 + i*16 + r)*Astride + q*8;
  #pragma unroll
  for (int j=0;j<4;j++) Brow[j] = X + (size_t)(T0 + j*16 + r)*Xstride + Xoff + q*8;

  // 2-stage software pipeline: prefetch k+1 fragments during k's MFMAs
  short8 a[4], bfr[4];
  #pragma unroll
  for (int i=0;i<4;i++) a[i]   = *(const short8*)(Arow[i]);
  #pragma unroll
  for (int j=0;j<4;j++) bfr[j] = *(const short8*)(Brow[j]);
  for (int k0=32; k0<K; k0+=32){
    short8 a2[4], b2[4];
    #pragma unroll
    for (int i=0;i<4;i++) a2[i] = *(const short8*)(Arow[i] + k0);
    #pragma unroll
    for (int j=0;j<4;j++) b2[j] = *(const short8*)(Brow[j] + k0);
    #pragma unroll
    for (int i=0;i<4;i++)
      #pragma unroll
      for (int j=0;j<4;j++)
        acc[i][j] = __builtin_amdgcn_mfma_f32_16x16x32_bf16(a[i], bfr[j], acc[i][j], 0, 0, 0);
    #pragma unroll
    for (int i=0;i<4;i++) a[i] = a2[i];
    #pragma unroll
    for (int j=0;j<4;j++) bfr[j] = b2[j];
  }
  #pragma unroll
  for (int i=0;i<4;i++)
    #pragma unroll
    for (int j=0;j<4;j++)
      acc[i][j] = __builtin_amdgcn_mfma_f32_16x16x32_bf16(a[i], bfr[j], acc[i][j], 0, 0, 0);

  // epilogue: D layout col=lane&15 (token), row=q*4+reg (channel)
  #pragma unroll
  for (int i=0;i<4;i++){
    int m = M0 + i*16 + q*4;
    float sv[4], bv[4];
    if constexpr (EPI != EPI_PLAIN){
      #pragma unroll
      for (int u=0;u<4;u++){ sv[u]=sPtr[m+u]; bv[u]=bPtr[m+u]; }
    }
    #pragma unroll
    for (int j=0;j<4;j++){
      int token = T0 + j*16 + r;
      float ex[4];
      if constexpr (EPI == EPI_CLS){
        int bb = token >> 12;
        #pragma unroll
        for (int u=0;u<4;u++)
          ex[u] = EXB ? extraIn[bb*extraStride + m + u]
                      : ((const float*)(g_scratch + extraOffB))[bb*extraStride + m + u];
      }
      float resv[4];
      if constexpr (EPI == EPI_RES){
        const unsigned short* resPtr = (const unsigned short*)(g_scratch + resOffB);
        ushort4v rv = *(const ushort4v*)(resPtr + (size_t)token*resStride + resOff + m);
        #pragma unroll
        for (int u=0;u<4;u++) resv[u]=bf2f(rv[u]);
      }
      ushort4v ov;
      #pragma unroll
      for (int u=0;u<4;u++){
        float aa = acc[i][j][u];
        float vo;
        if constexpr (EPI == EPI_PLAIN)        vo = aa;
        else if constexpr (EPI == EPI_RELU_SB) vo = fmaxf(sv[u]*aa + bv[u], 0.f);
        else if constexpr (EPI == EPI_RES)     vo = resv[u] + fmaxf(sv[u]*aa + bv[u], 0.f);
        else if constexpr (EPI == EPI_LEAKY){  float tt = sv[u]*aa + bv[u]; vo = tt>0.f ? tt : 0.2f*tt; }
        else { vo = fmaxf(sv[u]*(aa + ex[u]) + bv[u], 0.f); }
        ov[u] = f2bf(vo);
      }
      *(ushort4v*)(out + (size_t)token*outStride + outOff + m) = ov;
    }
  }
}

// 4-wave 128Mx128T (fuse, cls1) with XCD swizzle (gy must be 128)
template<int EPI, bool EXB>
__global__ __launch_bounds__(256) void gemm_tok(
    unsigned W0off, unsigned W1off, unsigned W2off,
    unsigned O0off, unsigned O1off, unsigned O2off,
    unsigned XoffB, int Xstride, int Xoff,
    int outStride, int outOff,
    const float* sPtr, const float* bPtr,
    const float* extraIn, unsigned extraOffB, int extraStride,
    unsigned resOffB, int resStride, int resOff,
    int K, int Astride)
{
  const unsigned short* X = (const unsigned short*)(g_scratch + XoffB);
  unsigned wOffB   = (blockIdx.z==0) ? W0off : ((blockIdx.z==1) ? W1off : W2off);
  unsigned outOffB = (blockIdx.z==0) ? O0off : ((blockIdx.z==1) ? O1off : O2off);
  const unsigned short* W = (const unsigned short*)(g_scratch + wOffB);
  unsigned short* out = (unsigned short*)(g_scratch + outOffB);
  // XCD swizzle: blocks with lin%8==c (same XCD by dispatch heuristic) share
  // a 16-tile y-band -> per-XCD X working set = 16*256KB = 4 MB = one L2.
  int lin = blockIdx.x + gridDim.x*blockIdx.y;
  int bx = lin >> 7;
  int by = (lin & 7)*16 + ((lin >> 3) & 15);
  int lane = threadIdx.x & 63, wave = threadIdx.x >> 6;
  int M0 = bx*128 + (wave>>1)*64;
  int T0 = by*128 + (wave&1)*64;
  gemm_body<EPI,EXB>(M0, T0, W, X, out, Xstride, Xoff, outStride, outOff,
                     sPtr, bPtr, extraIn, extraOffB, extraStride,
                     resOffB, resStride, resOff, K, Astride, lane);
}

// 2-wave 64Mx128T (emb2, qkv, wo, cls2)
template<int EPI, bool EXB>
__global__ __launch_bounds__(128) void gemm_small(
    unsigned W0off, unsigned W1off, unsigned W2off,
    unsigned O0off, unsigned O1off, unsigned O2off,
    unsigned XoffB, int Xstride, int Xoff,
    int outStride, int outOff,
    const float* sPtr, const float* bPtr,
    const float* extraIn, unsigned extraOffB, int extraStride,
    unsigned resOffB, int resStride, int resOff,
    int K, int Astride)
{
  const unsigned short* X = (const unsigned short*)(g_scratch + XoffB);
  unsigned wOffB   = (blockIdx.z==0) ? W0off : ((blockIdx.z==1) ? W1off : W2off);
  unsigned outOffB = (blockIdx.z==0) ? O0off : ((blockIdx.z==1) ? O1off : O2off);
  const unsigned short* W = (const unsigned short*)(g_scratch + wOffB);
  unsigned short* out = (unsigned short*)(g_scratch + outOffB);
  int lane = threadIdx.x & 63, wave = threadIdx.x >> 6;  // 0/1
  int M0 = blockIdx.x*64;
  int T0 = blockIdx.y*128 + wave*64;
  gemm_body<EPI,EXB>(M0, T0, W, X, out, Xstride, Xoff, outStride, outOff,
                     sPtr, bPtr, extraIn, extraOffB, extraStride,
                     resOffB, resStride, resOff, K, Astride, lane);
}

// ---------------- attention (one wave per query, 2 channels/lane) ----------------
__global__ __launch_bounds__(256) void attn_kernel(
  unsigned qOff, unsigned kOff, unsigned vOff, unsigned idxOff,
  const float* __restrict__ in, const float* __restrict__ wpos,
  unsigned aggOff)
{
  const unsigned short* Q  = (const unsigned short*)(g_scratch + qOff);
  const unsigned short* Kf = (const unsigned short*)(g_scratch + kOff);
  const unsigned short* V  = (const unsigned short*)(g_scratch + vOff);
  const int* idx           = (const int*)(g_scratch + idxOff);
  unsigned short* agg      = (unsigned short*)(g_scratch + aggOff);

  int lane = threadIdx.x & 63, wv = threadIdx.x >> 6;
  int t = blockIdx.x*4 + wv;
  int b = t >> 12, n = t & 4095;
  const float* xb = in + (size_t)b*9*NP;
  int c0 = lane*2;

  unsigned qv = *(const unsigned*)(Q + (size_t)t*128 + c0);
  float q0 = bf2f((unsigned short)(qv & 0xffff)), q1 = bf2f((unsigned short)(qv >> 16));
  float xn = xb[n], yn = xb[NP+n], zn = xb[2*NP+n];
  float wp00=wpos[c0*3+0],     wp01=wpos[c0*3+1],     wp02=wpos[c0*3+2];
  float wp10=wpos[(c0+1)*3+0], wp11=wpos[(c0+1)*3+1], wp12=wpos[(c0+1)*3+2];

  int mi[16]; float s[16];
  #pragma unroll
  for (int j=0;j<16;j++) mi[j] = idx[(size_t)t*16 + j] & 4095;  // mask: never OOB
  #pragma unroll
  for (int j=0;j<16;j++){
    unsigned kv = *(const unsigned*)(Kf + ((size_t)(b<<12) + mi[j])*128 + c0);
    float p = q0*bf2f((unsigned short)(kv & 0xffff)) + q1*bf2f((unsigned short)(kv >> 16));
    #pragma unroll
    for (int o=32;o>=1;o>>=1) p += __shfl_xor(p, o, 64);
    s[j] = p;
  }
  const float scale = 0.08838834764831845f; // 1/sqrt(128)
  float mx = s[0];
  #pragma unroll
  for (int j=1;j<16;j++) mx = fmaxf(mx, s[j]);
  float e[16], sum = 0.f;
  #pragma unroll
  for (int j=0;j<16;j++){ e[j] = __expf((s[j]-mx)*scale); sum += e[j]; }
  float inv = 1.f / sum;

  float a0=0.f, a1=0.f;
  #pragma unroll
  for (int j=0;j<16;j++){
    int m = mi[j];
    float w = e[j]*inv;
    unsigned vv = *(const unsigned*)(V + ((size_t)(b<<12) + m)*128 + c0);
    float rx = xn - xb[m];
    float ry = yn - xb[NP+m];
    float rz = zn - xb[2*NP+m];
    float p0 = wp00*rx + wp01*ry + wp02*rz;
    float p1 = wp10*rx + wp11*ry + wp12*rz;
    a0 += w*(bf2f((unsigned short)(vv & 0xffff)) + p0);
    a1 += w*(bf2f((unsigned short)(vv >> 16)) + p1);
  }
  unsigned pk = (unsigned)f2bf(a0) | ((unsigned)f2bf(a1) << 16);
  *(unsigned*)(agg + (size_t)t*128 + c0) = pk;
}

// ---------------- max/mean pool over tokens (two-stage) ----------------
__global__ __launch_bounds__(256) void pool_part(unsigned xfOff, unsigned gpOff)
{
  const unsigned short* xf = (const unsigned short*)(g_scratch + xfOff);
  float* gp = (float*)(g_scratch + gpOff);   // [b][seg][2][1024]
  int b = blockIdx.x >> 7, cblk = (blockIdx.x >> 3) & 15, seg = blockIdx.x & 7;
  int cl = threadIdx.x & 63, tg = threadIdx.x >> 6;
  int c = cblk*64 + cl;
  float mx = -3.0e38f, sm = 0.f;
  for (int n = seg*512 + tg; n < (seg+1)*512; n += 4){
    float v = bf2f(xf[((size_t)(b<<12) + n)*1024 + c]);
    mx = fmaxf(mx, v); sm += v;
  }
  __shared__ float smx[4][64], ssm[4][64];
  smx[tg][cl]=mx; ssm[tg][cl]=sm;
  __syncthreads();
  if (tg==0){
    #pragma unroll
    for (int k=1;k<4;k++){ mx = fmaxf(mx, smx[k][cl]); sm += ssm[k][cl]; }
    gp[((b*8 + seg)*2 + 0)*1024 + c] = mx;
    gp[((b*8 + seg)*2 + 1)*1024 + c] = sm;
  }
}
__global__ __launch_bounds__(256) void pool_final(unsigned gpOff, unsigned gOff)
{
  const float* gp = (const float*)(g_scratch + gpOff);
  float* g = (float*)(g_scratch + gOff);
  int b = blockIdx.x;
  for (int c = threadIdx.x; c < 1024; c += 256){
    float mx = -3.0e38f, sm = 0.f;
    #pragma unroll
    for (int seg=0; seg<8; ++seg){
      mx = fmaxf(mx, gp[((b*8 + seg)*2 + 0)*1024 + c]);
      sm += gp[((b*8 + seg)*2 + 1)*1024 + c];
    }
    g[b*2048 + c] = mx;
    g[b*2048 + 1024 + c] = sm * (1.f/4096.f);
  }
}

// gb[b][o] = cls_bias1[o] + sum_c W1[o][1024+c]*g[b][c]
__global__ __launch_bounds__(256) void gterm_kernel(const float* __restrict__ w1,
                                                    const float* __restrict__ bias1,
                                                    unsigned gOff, unsigned gbOff)
{
  const float* g = (const float*)(g_scratch + gOff);
  float* gb = (float*)(g_scratch + gbOff);
  int b = blockIdx.x >> 3, og = (blockIdx.x & 7)*64;
  int ol = threadIdx.x & 63, cq = threadIdx.x >> 6;
  int o = og + ol;
  const float* wrow = w1 + (size_t)o*3072 + 1024 + cq*512;
  const float* gp = g + b*2048 + cq*512;
  float acc = 0.f;
  for (int c=0;c<512;c+=4){
    float4 wv4 = *(const float4*)(wrow + c);
    acc += wv4.x*gp[c] + wv4.y*gp[c+1] + wv4.z*gp[c+2] + wv4.w*gp[c+3];
  }
  __shared__ float sred[4][64];
  sred[cq][ol] = acc;
  __syncthreads();
  if (cq==0){
    acc += sred[1][ol] + sred[2][ol] + sred[3][ol];
    gb[b*512 + o] = acc + bias1[o];
  }
}

// ---------------- classifier head (O=13), fp32 out ----------------
__global__ __launch_bounds__(256) void cls3_kernel(unsigned c2Off,
                                                   const float* __restrict__ w3,
                                                   const float* __restrict__ bias3,
                                                   float* __restrict__ outp)
{
  const unsigned short* c2 = (const unsigned short*)(g_scratch + c2Off);
  __shared__ float wf[13*256];
  __shared__ float bf3[13];
  for (int i=threadIdx.x;i<13*256;i+=256) wf[i]=w3[i];
  if (threadIdx.x < 13) bf3[threadIdx.x]=bias3[threadIdx.x];
  __syncthreads();
  int lane = threadIdx.x & 63, wv = threadIdx.x >> 6;
  int tl = lane >> 2, cq = lane & 3;
  int t = blockIdx.x*64 + wv*16 + tl;
  const unsigned short* xrow = c2 + (size_t)t*256 + cq*64;
  float acc[13];
  #pragma unroll
  for (int o=0;o<13;o++) acc[o]=0.f;
  for (int c=0;c<64;c+=8){
    short8 xv = *(const short8*)(xrow + c);
    float xs[8];
    #pragma unroll
    for (int u=0;u<8;u++) xs[u]=bf2f((unsigned short)xv[u]);
    #pragma unroll
    for (int o=0;o<13;o++){
      const float* wr = wf + o*256 + cq*64 + c;
      #pragma unroll
      for (int u=0;u<8;u++) acc[o] += wr[u]*xs[u];
    }
  }
  #pragma unroll
  for (int o=0;o<13;o++){
    acc[o] += __shfl_xor(acc[o], 1, 64);
    acc[o] += __shfl_xor(acc[o], 2, 64);
  }
  if (cq==0){
    int b = t >> 12, n = t & 4095;
    #pragma unroll
    for (int o=0;o<13;o++)
      outp[((size_t)b*13 + o)*NP + n] = acc[o] + bf3[o];
  }
}

// ---------------- launch ----------------
extern "C" void kernel_launch(void* const* d_in, const int* in_sizes, int n_in,
                              void* d_out, int out_size, void* d_ws, size_t ws_size,
                              hipStream_t stream) {
  (void)in_sizes; (void)n_in; (void)out_size; (void)d_ws; (void)ws_size;
  const float* in      = (const float*)d_in[0];
  const float* emb_w1  = (const float*)d_in[1];
  const float* emb_s1  = (const float*)d_in[2];
  const float* emb_b1  = (const float*)d_in[3];
  const float* emb_w2  = (const float*)d_in[4];
  const float* emb_s2  = (const float*)d_in[5];
  const float* emb_b2  = (const float*)d_in[6];
  const float* blk_wq  = (const float*)d_in[7];
  const float* blk_wk  = (const float*)d_in[8];
  const float* blk_wv  = (const float*)d_in[9];
  const float* blk_wpos= (const float*)d_in[10];
  const float* blk_wo  = (const float*)d_in[11];
  const float* blk_s   = (const float*)d_in[12];
  const float* blk_b   = (const float*)d_in[13];
  const float* fuse_w  = (const float*)d_in[14];
  const float* fuse_s  = (const float*)d_in[15];
  const float* fuse_b  = (const float*)d_in[16];
  const float* cls_w1  = (const float*)d_in[17];
  const float* cls_b1  = (const float*)d_in[18];
  const float* cls_s1  = (const float*)d_in[19];
  const float* cls_sh1 = (const float*)d_in[20];
  const float* cls_w2  = (const float*)d_in[21];
  const float* cls_b2  = (const float*)d_in[22];
  const float* cls_s2  = (const float*)d_in[23];
  const float* cls_sh2 = (const float*)d_in[24];
  const float* cls_w3  = (const float*)d_in[25];
  const float* cls_b3  = (const float*)d_in[26];

  // byte offsets into g_scratch
  const unsigned MB = 1u<<20, KB = 1024u;
  const unsigned OFF_IDX   = 0;                 // 1 MB   int idx[T][16]
  const unsigned OFF_WQ    = 1*MB;              // 96 KB  bf16 (3,128,128)
  const unsigned OFF_WK    = 1*MB + 128*KB;     // 96 KB
  const unsigned OFF_WV    = 1*MB + 256*KB;     // 96 KB
  const unsigned OFF_WO    = 1*MB + 384*KB;     // 96 KB
  const unsigned OFF_WEMB2 = 1*MB + 512*KB;     // 32 KB  bf16 (128,128)
  const unsigned OFF_WFUSE = 1*MB + 576*KB;     // 768 KB bf16 (1024,384)
  const unsigned OFF_WW1   = 3*MB;              // 1 MB   bf16 (512,1024) x-half
  const unsigned OFF_WW2   = 4*MB;              // 256 KB bf16 (256,512)
  const unsigned OFF_X1    = 5*MB;              // 4 MB   bf16 (T,128)
  const unsigned OFF_X0    = 9*MB;              // 4 MB   bf16 (T,128)
  const unsigned OFF_XCAT  = 13*MB;             // 12 MB  bf16 (T,384)
  const unsigned OFF_QB    = 25*MB;             // 4 MB
  const unsigned OFF_KB    = 29*MB;             // 4 MB
  const unsigned OFF_VB    = 33*MB;             // 4 MB
  const unsigned OFF_AGG   = 37*MB;             // 4 MB
  const unsigned OFF_XF    = 41*MB;             // 32 MB  bf16 (T,1024)
  const unsigned OFF_C1    = 73*MB;             // 16 MB  bf16 (T,512)
  const unsigned OFF_C2    = 89*MB;             // 8 MB   bf16 (T,256)
  const unsigned OFF_G     = 97*MB;             // 32 KB  f32 (B,2048)
  const unsigned OFF_GB    = 97*MB + 64*KB;     // 8 KB   f32 (B,512)
  const unsigned OFF_GP    = 97*MB + 128*KB;    // 256 KB f32 pool partials
  const unsigned OFF_THR   = 97*MB + 512*KB;    // 64 KB  f32 thr[T]
  const unsigned OFF_PD    = 98*MB;             // 16 MB  f32 knn bound vals / p2 dists
  const unsigned OFF_PI    = 114*MB;            // 16 MB  int knn idx (p2)
  float* outp = (float*)d_out;                  // (B,13,N) f32

  // 0: fused weight conversion prepass (fp32 -> bf16 into scratch)
  CvtArgs ca;
  ca.src[0]=emb_w2;  ca.dstOff[0]=OFF_WEMB2; ca.n[0]=128*128;
  ca.src[1]=blk_wq;  ca.dstOff[1]=OFF_WQ;    ca.n[1]=3*128*128;
  ca.src[2]=blk_wk;  ca.dstOff[2]=OFF_WK;    ca.n[2]=3*128*128;
  ca.src[3]=blk_wv;  ca.dstOff[3]=OFF_WV;    ca.n[3]=3*128*128;
  ca.src[4]=blk_wo;  ca.dstOff[4]=OFF_WO;    ca.n[4]=3*128*128;
  ca.src[5]=fuse_w;  ca.dstOff[5]=OFF_WFUSE; ca.n[5]=1024*384;
  ca.src[6]=cls_w2;  ca.dstOff[6]=OFF_WW2;   ca.n[6]=256*512;
  ca.src[7]=cls_w1;  ca.dstOff[7]=OFF_WW1;   ca.n[7]=512*1024;
  cvt_all<<<dim3(64,8), 256, 0, stream>>>(ca);

  // 1-4: KNN (cheap-threshold two-pass)
  knn_p1<<<dim3(16,16,4), 256, 0, stream>>>(in, OFF_PD);
  knn_thr<<<dim3(64), 256, 0, stream>>>(OFF_PD, OFF_THR);
  knn_p2<<<dim3(16,16,4), 256, 0, stream>>>(in, OFF_THR, OFF_PD, OFF_PI);
  knn_mrg<<<dim3(256), 64, 0, stream>>>(OFF_PD, OFF_PI, OFF_IDX);
  // 5-6: embedding
  emb1_kernel<<<dim3(64,4), 256, 0, stream>>>(in, emb_w1, emb_s1, emb_b1, OFF_X1);
  gemm_small<EPI_RELU_SB,false><<<dim3(2,128,1), 128, 0, stream>>>(
      OFF_WEMB2, OFF_WEMB2, OFF_WEMB2, OFF_X0, OFF_X0, OFF_X0,
      OFF_X1, 128, 0, 128, 0, emb_s2, emb_b2,
      nullptr, 0, 0, 0, 0, 0, 128, 128);
  // 7-9: transformer blocks
  for (int i=0;i<3;i++){
    unsigned wq = OFF_WQ + i*32768, wk = OFF_WK + i*32768;
    unsigned wv = OFF_WV + i*32768, wo = OFF_WO + i*32768;
    const float* wp = blk_wpos + i*128*3;
    const float* si = blk_s + i*128;
    const float* bi = blk_b + i*128;
    unsigned XiOff = (i==0) ? OFF_X0 : OFF_XCAT;
    int Xs = (i==0) ? 128 : 384;
    int Xo = (i==0) ? 0 : (i-1)*128;
    gemm_small<EPI_PLAIN,false><<<dim3(2,128,3), 128, 0, stream>>>(
        wq, wk, wv, OFF_QB, OFF_KB, OFF_VB,
        XiOff, Xs, Xo, 128, 0, nullptr, nullptr,
        nullptr, 0, 0, 0, 0, 0, 128, 128);
    attn_kernel<<<dim3(4096), 256, 0, stream>>>(OFF_QB, OFF_KB, OFF_VB, OFF_IDX, in, wp, OFF_AGG);
    gemm_small<EPI_RES,false><<<dim3(2,128,1), 128, 0, stream>>>(
        wo, wo, wo, OFF_XCAT, OFF_XCAT, OFF_XCAT,
        OFF_AGG, 128, 0, 384, i*128, si, bi,
        nullptr, 0, 0, XiOff, Xs, Xo, 128, 128);
  }
  // 10: fuse (leaky relu), XCD-swizzled
  gemm_tok<EPI_LEAKY,false><<<dim3(8,128,1), 256, 0, stream>>>(
      OFF_WFUSE, OFF_WFUSE, OFF_WFUSE, OFF_XF, OFF_XF, OFF_XF,
      OFF_XCAT, 384, 0, 1024, 0, fuse_s, fuse_b,
      nullptr, 0, 0, 0, 0, 0, 384, 384);
  // 11-13: pooling (two-stage) + broadcast-g term of cls1 (fp32)
  pool_part<<<dim3(512), 256, 0, stream>>>(OFF_XF, OFF_GP);
  pool_final<<<dim3(4), 256, 0, stream>>>(OFF_GP, OFF_G);
  gterm_kernel<<<dim3(32), 256, 0, stream>>>(cls_w1, cls_b1, OFF_G, OFF_GB);
  // 14: cls1 (K=1024 x-half of W1; gb = W1[:,1024:]@g + bias1 as extra), swizzled
  gemm_tok<EPI_CLS,false><<<dim3(4,128,1), 256, 0, stream>>>(
      OFF_WW1, OFF_WW1, OFF_WW1, OFF_C1, OFF_C1, OFF_C1,
      OFF_XF, 1024, 0, 512, 0, cls_s1, cls_sh1,
      nullptr, OFF_GB, 512, 0, 0, 0, 1024, 1024);
  // 15: cls2
  gemm_small<EPI_CLS,true><<<dim3(4,128,1), 128, 0, stream>>>(
      OFF_WW2, OFF_WW2, OFF_WW2, OFF_C2, OFF_C2, OFF_C2,
      OFF_C1, 512, 0, 256, 0, cls_s2, cls_sh2,
      cls_b2, 0, 0, 0, 0, 0, 512, 512);
  // 16: cls3 -> d_out (fp32)
  cls3_kernel<<<dim3(256), 256, 0, stream>>>(OFF_C2, cls_w3, cls_b3, outp);
}

// Round 13
// 541.426 us; speedup vs baseline: 2.1231x; 1.1113x over previous
//
#include <hip/hip_runtime.h>

// PVDST semseg, MI355X/gfx950. FP32 I/O. Round-13: LDS-staged big-K GEMMs.
//   - R12 post-mortem: swizzle halved FETCH (66->20 MB) and prefetch was
//     neutral -> cls1's 70us is NOT HBM/latency-schedule bound; it's L1/TA
//     line-throughput: strided fragment loads touch 16 lines/instr, tile
//     bytes enter the CU twice (2 waves share each slice). 245 TF observed.
//   - Fix (measured ladder m90->m93): block LDS staging. gemm_lds: 128x128
//     tile, BK=32, coalesced 16B/lane staging (4-lane clusters = 1 line),
//     ds_read_b128 fragments, 2-barrier K-loop, staging loads hoisted above
//     barrier. Used for fuse(K=384)/cls1(K=1024)/cls2(K=512); K=128 GEMMs
//     keep the LDS-free 2-wave path (barriers don't amortize over 4 steps).
// KNN cheap-threshold two-pass unchanged (absmax 2.9e-3).

#define NB 4
#define NP 4096
#define NT 16384   // NB*NP tokens

#define SCRATCH_BYTES (132u*1024u*1024u)
__device__ __align__(256) unsigned char g_scratch[SCRATCH_BYTES];

typedef __attribute__((ext_vector_type(8))) short short8;   // 8 x bf16 MFMA frag
typedef __attribute__((ext_vector_type(4))) float f32x4;    // MFMA acc
typedef __attribute__((ext_vector_type(4))) unsigned short ushort4v;

__device__ __forceinline__ float bf2f(unsigned short u){
  unsigned int v = ((unsigned int)u) << 16;
  return __builtin_bit_cast(float, v);
}
__device__ __forceinline__ unsigned short f2bf(float f){
  unsigned int x = __builtin_bit_cast(unsigned int, f);
  x += 0x7fffu + ((x >> 16) & 1u);     // RNE
  return (unsigned short)(x >> 16);
}
// numpy-matched: ((x*x)+(y*y))+(z*z), each op rounded (no fma contraction)
__device__ __forceinline__ float sq3(float x, float y, float z){
  return __fadd_rn(__fadd_rn(__fmul_rn(x,x), __fmul_rn(y,y)), __fmul_rn(z,z));
}

// sorted-4 insert: 7 native min/max, no masks
#define KINS4(a0,a1,a2,a3,dd) do{ float _d=(dd);\
  a3=fminf(fmaxf(a2,_d),a3); a2=fminf(fmaxf(a1,_d),a2);\
  a1=fminf(fmaxf(a0,_d),a1); a0=fminf(a0,_d);}while(0)

// dist-only sorted-ascending top-16 (thr kernel)
#define KDECLD float d0=3.0e38f,d1=3.0e38f,d2=3.0e38f,d3=3.0e38f,d4=3.0e38f,\
  d5=3.0e38f,d6=3.0e38f,d7=3.0e38f,d8=3.0e38f,d9=3.0e38f,d10=3.0e38f,\
  d11=3.0e38f,d12=3.0e38f,d13=3.0e38f,d14=3.0e38f,d15=3.0e38f
#define KINSD(dd) do{ float _d=(dd); \
  d15=fminf(fmaxf(d14,_d),d15); d14=fminf(fmaxf(d13,_d),d14); \
  d13=fminf(fmaxf(d12,_d),d13); d12=fminf(fmaxf(d11,_d),d12); \
  d11=fminf(fmaxf(d10,_d),d11); d10=fminf(fmaxf(d9 ,_d),d10); \
  d9 =fminf(fmaxf(d8 ,_d),d9 ); d8 =fminf(fmaxf(d7 ,_d),d8 ); \
  d7 =fminf(fmaxf(d6 ,_d),d7 ); d6 =fminf(fmaxf(d5 ,_d),d6 ); \
  d5 =fminf(fmaxf(d4 ,_d),d5 ); d4 =fminf(fmaxf(d3 ,_d),d4 ); \
  d3 =fminf(fmaxf(d2 ,_d),d3 ); d2 =fminf(fmaxf(d1 ,_d),d2 ); \
  d1 =fminf(fmaxf(d0 ,_d),d1 ); d0 =fminf(d0,_d); }while(0)

// full (dist,idx) stable insert (merge only; strict < => lower index wins)
#define KDECL KDECLD; int i0=0,i1=0,i2=0,i3=0,i4=0,i5=0,i6=0,i7=0,i8=0,\
  i9=0,i10=0,i11=0,i12=0,i13=0,i14=0,i15=0
#define KINS(dd,mm) do{ float _d=(dd); int _m=(mm); \
  bool c15 = _d < d15; \
  bool c14 = _d < d14;  i15 = c14 ? i14 : (c15 ? _m : i15);  d15 = fminf(fmaxf(d14,_d), d15); \
  bool c13 = _d < d13;  i14 = c13 ? i13 : (c14 ? _m : i14);  d14 = fminf(fmaxf(d13,_d), d14); \
  bool c12 = _d < d12;  i13 = c12 ? i12 : (c13 ? _m : i13);  d13 = fminf(fmaxf(d12,_d), d13); \
  bool c11 = _d < d11;  i12 = c11 ? i11 : (c12 ? _m : i12);  d12 = fminf(fmaxf(d11,_d), d12); \
  bool c10 = _d < d10;  i11 = c10 ? i10 : (c11 ? _m : i11);  d11 = fminf(fmaxf(d10,_d), d11); \
  bool c9  = _d < d9;   i10 = c9  ? i9  : (c10 ? _m : i10);  d10 = fminf(fmaxf(d9 ,_d), d10); \
  bool c8  = _d < d8;   i9  = c8  ? i8  : (c9  ? _m : i9 );  d9  = fminf(fmaxf(d8 ,_d), d9 ); \
  bool c7  = _d < d7;   i8  = c7  ? i7  : (c8  ? _m : i8 );  d8  = fminf(fmaxf(d7 ,_d), d8 ); \
  bool c6  = _d < d6;   i7  = c6  ? i6  : (c7  ? _m : i7 );  d7  = fminf(fmaxf(d6 ,_d), d7 ); \
  bool c5  = _d < d5;   i6  = c5  ? i5  : (c6  ? _m : i6 );  d6  = fminf(fmaxf(d5 ,_d), d6 ); \
  bool c4  = _d < d4;   i5  = c4  ? i4  : (c5  ? _m : i5 );  d5  = fminf(fmaxf(d4 ,_d), d5 ); \
  bool c3  = _d < d3;   i4  = c3  ? i3  : (c4  ? _m : i4 );  d4  = fminf(fmaxf(d3 ,_d), d4 ); \
  bool c2  = _d < d2;   i3  = c2  ? i2  : (c3  ? _m : i3 );  d3  = fminf(fmaxf(d2 ,_d), d3 ); \
  bool c1  = _d < d1;   i2  = c1  ? i1  : (c2  ? _m : i2 );  d2  = fminf(fmaxf(d1 ,_d), d2 ); \
  bool c0  = _d < d0;   i1  = c0  ? i0  : (c1  ? _m : i1 );  d1  = fminf(fmaxf(d0 ,_d), d1 ); \
  i0 = c0 ? _m : i0;  d0 = fminf(d0,_d); }while(0)

// ---------------- fused weight fp32 -> bf16 conversion prepass ----------------
struct CvtArgs {
  const float* src[8];
  unsigned dstOff[8];
  int n[8];
};
__global__ __launch_bounds__(256) void cvt_all(CvtArgs a)
{
  int y = blockIdx.y;
  const float* src = a.src[y];
  unsigned short* dst = (unsigned short*)(g_scratch + a.dstOff[y]);
  int n = a.n[y];
  if (y == 7){
    for (int i = blockIdx.x*256 + threadIdx.x; i < n; i += gridDim.x*256){
      int r = i >> 10, c = i & 1023;
      dst[i] = f2bf(src[(size_t)r*3072 + c]);
    }
  } else {
    for (int i = blockIdx.x*256 + threadIdx.x; i < n; i += gridDim.x*256)
      dst[i] = f2bf(src[i]);
  }
}

// ---------------- KNN pass1: 4x sorted-4 bound lists, fma dist ----------------
__global__ __launch_bounds__(256) void knn_p1(const float* __restrict__ in,
                                              unsigned pdOff)
{
  float* pdist = (float*)(g_scratch + pdOff);
  __shared__ float4 sp[256];
  int b = blockIdx.z, qc = blockIdx.x, cc = blockIdx.y;
  const float* xb = in + (size_t)b*9*NP;
  int base = cc*256;
  {
    int i = threadIdx.x;
    float x = xb[base+i], y = xb[NP+base+i], z = xb[2*NP+base+i];
    sp[i] = make_float4(x,y,z, x*x+y*y+z*z);
  }
  __syncthreads();
  int n = qc*256 + threadIdx.x;
  float xn=xb[n], yn=xb[NP+n], zn=xb[2*NP+n];
  float sqn = xn*xn + yn*yn + zn*zn;
  float A0=3e38f,A1=3e38f,A2=3e38f,A3=3e38f;
  float B0=3e38f,B1=3e38f,B2=3e38f,B3=3e38f;
  float C0=3e38f,C1=3e38f,C2=3e38f,C3=3e38f;
  float D0=3e38f,D1=3e38f,D2=3e38f,D3=3e38f;
  for (int mm=0; mm<256; mm+=4){
    float4 p0 = sp[mm], p1 = sp[mm+1], p2 = sp[mm+2], p3 = sp[mm+3];
    float e0 = sqn + p0.w - 2.f*(xn*p0.x + yn*p0.y + zn*p0.z);
    float e1 = sqn + p1.w - 2.f*(xn*p1.x + yn*p1.y + zn*p1.z);
    float e2 = sqn + p2.w - 2.f*(xn*p2.x + yn*p2.y + zn*p2.z);
    float e3 = sqn + p3.w - 2.f*(xn*p3.x + yn*p3.y + zn*p3.z);
    KINS4(A0,A1,A2,A3,e0);
    KINS4(B0,B1,B2,B3,e1);
    KINS4(C0,C1,C2,C3,e2);
    KINS4(D0,D1,D2,D3,e3);
  }
  size_t ob = ((size_t)(b*16+cc)*16)*NP + n;
  pdist[ob+ 0*(size_t)NP]=A0; pdist[ob+ 1*(size_t)NP]=A1; pdist[ob+ 2*(size_t)NP]=A2; pdist[ob+ 3*(size_t)NP]=A3;
  pdist[ob+ 4*(size_t)NP]=B0; pdist[ob+ 5*(size_t)NP]=B1; pdist[ob+ 6*(size_t)NP]=B2; pdist[ob+ 7*(size_t)NP]=B3;
  pdist[ob+ 8*(size_t)NP]=C0; pdist[ob+ 9*(size_t)NP]=C1; pdist[ob+10*(size_t)NP]=C2; pdist[ob+11*(size_t)NP]=C3;
  pdist[ob+12*(size_t)NP]=D0; pdist[ob+13*(size_t)NP]=D1; pdist[ob+14*(size_t)NP]=D2; pdist[ob+15*(size_t)NP]=D3;
}

// ---------------- KNN thr: 16th-smallest of the 256 bound values + margin ----
__global__ __launch_bounds__(256) void knn_thr(unsigned pdOff, unsigned thrOff)
{
  const float* pdist = (const float*)(g_scratch + pdOff);
  float* thr = (float*)(g_scratch + thrOff);
  int t = blockIdx.x*256 + threadIdx.x;
  int b = t >> 12, n = t & 4095;
  KDECLD;
  for (int cc=0; cc<16; ++cc){
    size_t ob = ((size_t)(b*16+cc)*16)*NP + n;
    #pragma unroll
    for (int j=0;j<16;j++){ KINSD(pdist[ob + (size_t)j*NP]); }
  }
  thr[t] = d15*1.000002f + 2e-4f;   // margin >> fma-vs-_rn error
}

// ---------------- KNN pass2: append qualifying (d,i), exact _rn dist --------
__global__ __launch_bounds__(256) void knn_p2(const float* __restrict__ in,
                                              unsigned thrOff, unsigned pdOff, unsigned piOff)
{
  const float* thr = (const float*)(g_scratch + thrOff);
  float* pdist = (float*)(g_scratch + pdOff);
  int*   pidx  = (int*)  (g_scratch + piOff);
  __shared__ float4 sp[256];
  int b = blockIdx.z, qc = blockIdx.x, cc = blockIdx.y;
  const float* xb = in + (size_t)b*9*NP;
  int base = cc*256;
  {
    int i = threadIdx.x;
    float x = xb[base+i], y = xb[NP+base+i], z = xb[2*NP+base+i];
    sp[i] = make_float4(x,y,z,sq3(x,y,z));
  }
  __syncthreads();
  int n = qc*256 + threadIdx.x;
  float xn=xb[n], yn=xb[NP+n], zn=xb[2*NP+n];
  float sqn = sq3(xn,yn,zn);
  float th = thr[(b<<12) + n];
  size_t o = ((size_t)((b*16 + cc)*NP + n))*16;
  int cnt = 0;
  for (int mm=0; mm<256; ++mm){
    float4 p = sp[mm];
    float dot = __fadd_rn(__fadd_rn(__fmul_rn(xn,p.x), __fmul_rn(yn,p.y)), __fmul_rn(zn,p.z));
    float d = __fsub_rn(__fadd_rn(sqn, p.w), __fmul_rn(2.0f, dot));
    if (d <= th && cnt < 16){
      pdist[o+cnt] = d;
      pidx[o+cnt] = base + mm;
      cnt++;
    }
  }
  if (cnt < 16) pdist[o+cnt] = 3.0e38f;   // sentinel terminator
}

// ---------------- KNN final merge (index-ordered sparse lists) ----------------
__global__ __launch_bounds__(64) void knn_mrg(unsigned pdOff, unsigned piOff, unsigned idxOff)
{
  const float* pdist = (const float*)(g_scratch + pdOff);
  const int*   pidx  = (const int*)  (g_scratch + piOff);
  int*         idxOut= (int*)(g_scratch + idxOff);
  int t = blockIdx.x*64 + threadIdx.x;
  int b = t >> 12, n = t & 4095;
  KDECL;
  for (int cc=0; cc<16; ++cc){
    size_t o = ((size_t)((b*16 + cc)*NP + n))*16;
    #pragma unroll 1
    for (int j=0;j<16;j++){
      float pd = pdist[o+j];
      if (pd >= 1.0e38f) break;          // sentinel
      KINS(pd, pidx[o+j]);
    }
  }
  idxOut[t*16+ 0]=i0;  idxOut[t*16+ 1]=i1;  idxOut[t*16+ 2]=i2;  idxOut[t*16+ 3]=i3;
  idxOut[t*16+ 4]=i4;  idxOut[t*16+ 5]=i5;  idxOut[t*16+ 6]=i6;  idxOut[t*16+ 7]=i7;
  idxOut[t*16+ 8]=i8;  idxOut[t*16+ 9]=i9;  idxOut[t*16+10]=i10; idxOut[t*16+11]=i11;
  idxOut[t*16+12]=i12; idxOut[t*16+13]=i13; idxOut[t*16+14]=i14; idxOut[t*16+15]=i15;
}

// ---------------- embedding conv1 (Cin=9), output-split ----------------
__global__ __launch_bounds__(256) void emb1_kernel(const float* __restrict__ in,
                                                   const float* __restrict__ w1,
                                                   const float* __restrict__ s1,
                                                   const float* __restrict__ b1,
                                                   unsigned x1Off)
{
  unsigned short* x1 = (unsigned short*)(g_scratch + x1Off);
  int og = blockIdx.y*32;
  __shared__ float wf[32*9], sf[32], bf_[32];
  for (int i = threadIdx.x; i < 32*9; i += 256) wf[i] = w1[og*9 + i];
  if (threadIdx.x < 32){ sf[threadIdx.x]=s1[og+threadIdx.x]; bf_[threadIdx.x]=b1[og+threadIdx.x]; }
  __syncthreads();
  int t = blockIdx.x*256 + threadIdx.x;
  int b = t >> 12, n = t & 4095;
  float v[9];
  #pragma unroll
  for (int c=0;c<9;c++) v[c] = in[((size_t)b*9 + c)*NP + n];
  for (int o=0;o<32;o+=2){
    float a0=0.f, a1=0.f;
    #pragma unroll
    for (int c=0;c<9;c++){ a0 += wf[o*9+c]*v[c]; a1 += wf[(o+1)*9+c]*v[c]; }
    a0 = fmaxf(sf[o]*a0 + bf_[o], 0.f);
    a1 = fmaxf(sf[o+1]*a1 + bf_[o+1], 0.f);
    unsigned pk = (unsigned)f2bf(a0) | ((unsigned)f2bf(a1) << 16);
    *(unsigned*)(x1 + (size_t)t*128 + og + o) = pk;
  }
}

// ---------------- GEMM epilogue (shared) ----------------
enum { EPI_PLAIN=0, EPI_RELU_SB=1, EPI_RES=2, EPI_LEAKY=3, EPI_CLS=4 };

template<int EPI, bool EXB>
__device__ __forceinline__ void gemm_epi(
    f32x4 (&acc)[4][4], int M0, int T0, int r, int q,
    unsigned short* out, int outStride, int outOff,
    const float* sPtr, const float* bPtr,
    const float* extraIn, unsigned extraOffB, int extraStride,
    unsigned resOffB, int resStride, int resOff)
{
  #pragma unroll
  for (int i=0;i<4;i++){
    int m = M0 + i*16 + q*4;
    float sv[4], bv[4];
    if constexpr (EPI != EPI_PLAIN){
      #pragma unroll
      for (int u=0;u<4;u++){ sv[u]=sPtr[m+u]; bv[u]=bPtr[m+u]; }
    }
    #pragma unroll
    for (int j=0;j<4;j++){
      int token = T0 + j*16 + r;
      float ex[4];
      if constexpr (EPI == EPI_CLS){
        int bb = token >> 12;
        #pragma unroll
        for (int u=0;u<4;u++)
          ex[u] = EXB ? extraIn[bb*extraStride + m + u]
                      : ((const float*)(g_scratch + extraOffB))[bb*extraStride + m + u];
      }
      float resv[4];
      if constexpr (EPI == EPI_RES){
        const unsigned short* resPtr = (const unsigned short*)(g_scratch + resOffB);
        ushort4v rv = *(const ushort4v*)(resPtr + (size_t)token*resStride + resOff + m);
        #pragma unroll
        for (int u=0;u<4;u++) resv[u]=bf2f(rv[u]);
      }
      ushort4v ov;
      #pragma unroll
      for (int u=0;u<4;u++){
        float aa = acc[i][j][u];
        float vo;
        if constexpr (EPI == EPI_PLAIN)        vo = aa;
        else if constexpr (EPI == EPI_RELU_SB) vo = fmaxf(sv[u]*aa + bv[u], 0.f);
        else if constexpr (EPI == EPI_RES)     vo = resv[u] + fmaxf(sv[u]*aa + bv[u], 0.f);
        else if constexpr (EPI == EPI_LEAKY){  float tt = sv[u]*aa + bv[u]; vo = tt>0.f ? tt : 0.2f*tt; }
        else { vo = fmaxf(sv[u]*(aa + ex[u]) + bv[u], 0.f); }
        ov[u] = f2bf(vo);
      }
      *(ushort4v*)(out + (size_t)token*outStride + outOff + m) = ov;
    }
  }
}

// ---------------- LDS-staged GEMM: 128Mx128T, BK=32 (fuse, cls1, cls2) -------
// Staging: thread t loads 16B of row (p*64 + t/4), chunk t&3 (4-lane clusters
// = one 64B line), writes short8 into As/Bs [128][32]; frags via ds_read_b128.
template<int EPI, bool EXB>
__global__ __launch_bounds__(256) void gemm_lds(
    unsigned W0off, unsigned W1off, unsigned W2off,
    unsigned O0off, unsigned O1off, unsigned O2off,
    unsigned XoffB, int Xstride, int Xoff,
    int outStride, int outOff,
    const float* sPtr, const float* bPtr,
    const float* extraIn, unsigned extraOffB, int extraStride,
    unsigned resOffB, int resStride, int resOff,
    int K, int Astride)
{
  __shared__ unsigned short As[128*32];
  __shared__ unsigned short Bs[128*32];
  const unsigned short* X = (const unsigned short*)(g_scratch + XoffB);
  unsigned wOffB   = (blockIdx.z==0) ? W0off : ((blockIdx.z==1) ? W1off : W2off);
  unsigned outOffB = (blockIdx.z==0) ? O0off : ((blockIdx.z==1) ? O1off : O2off);
  const unsigned short* W = (const unsigned short*)(g_scratch + wOffB);
  unsigned short* out = (unsigned short*)(g_scratch + outOffB);
  // XCD swizzle (gy==128): lin%8-partition shares a 16-tile y-band per XCD
  int lin = blockIdx.x + gridDim.x*blockIdx.y;
  int bx = lin >> 7;
  int by = (lin & 7)*16 + ((lin >> 3) & 15);
  int M0 = bx*128, T0 = by*128;
  int t = threadIdx.x;
  int lane = t & 63, wave = t >> 6;
  int r = lane & 15, q = lane >> 4;
  int srow = t >> 2, schunk = t & 3;

  const unsigned short* Ag0 = W + (size_t)(M0 + srow)*Astride + schunk*8;
  const unsigned short* Ag1 = W + (size_t)(M0 + 64 + srow)*Astride + schunk*8;
  const unsigned short* Bg0 = X + (size_t)(T0 + srow)*Xstride + Xoff + schunk*8;
  const unsigned short* Bg1 = X + (size_t)(T0 + 64 + srow)*Xstride + Xoff + schunk*8;
  unsigned short* Aw0 = &As[srow*32 + schunk*8];
  unsigned short* Aw1 = &As[(64 + srow)*32 + schunk*8];
  unsigned short* Bw0 = &Bs[srow*32 + schunk*8];
  unsigned short* Bw1 = &Bs[(64 + srow)*32 + schunk*8];

  int Mw = (wave>>1)*64, Tw = (wave&1)*64;
  f32x4 acc[4][4];
  #pragma unroll
  for (int i=0;i<4;i++)
    #pragma unroll
    for (int j=0;j<4;j++)
      #pragma unroll
      for (int u=0;u<4;u++) acc[i][j][u] = 0.f;

  for (int k0=0; k0<K; k0+=32){
    short8 va0 = *(const short8*)(Ag0 + k0);
    short8 va1 = *(const short8*)(Ag1 + k0);
    short8 vb0 = *(const short8*)(Bg0 + k0);
    short8 vb1 = *(const short8*)(Bg1 + k0);
    if (k0) __syncthreads();            // prev frags consumed before overwrite
    *(short8*)Aw0 = va0; *(short8*)Aw1 = va1;
    *(short8*)Bw0 = vb0; *(short8*)Bw1 = vb1;
    __syncthreads();
    short8 a[4], bfr[4];
    #pragma unroll
    for (int i=0;i<4;i++) a[i]   = *(const short8*)(&As[(Mw + i*16 + r)*32 + q*8]);
    #pragma unroll
    for (int j=0;j<4;j++) bfr[j] = *(const short8*)(&Bs[(Tw + j*16 + r)*32 + q*8]);
    #pragma unroll
    for (int i=0;i<4;i++)
      #pragma unroll
      for (int j=0;j<4;j++)
        acc[i][j] = __builtin_amdgcn_mfma_f32_16x16x32_bf16(a[i], bfr[j], acc[i][j], 0, 0, 0);
  }
  gemm_epi<EPI,EXB>(acc, M0+Mw, T0+Tw, r, q, out, outStride, outOff,
                    sPtr, bPtr, extraIn, extraOffB, extraStride,
                    resOffB, resStride, resOff);
}

// ---------------- LDS-free 2-wave 64Mx128T (K=128 sites: emb2, qkv, wo) ------
template<int EPI, bool EXB>
__global__ __launch_bounds__(128) void gemm_small(
    unsigned W0off, unsigned W1off, unsigned W2off,
    unsigned O0off, unsigned O1off, unsigned O2off,
    unsigned XoffB, int Xstride, int Xoff,
    int outStride, int outOff,
    const float* sPtr, const float* bPtr,
    const float* extraIn, unsigned extraOffB, int extraStride,
    unsigned resOffB, int resStride, int resOff,
    int K, int Astride)
{
  const unsigned short* X = (const unsigned short*)(g_scratch + XoffB);
  unsigned wOffB   = (blockIdx.z==0) ? W0off : ((blockIdx.z==1) ? W1off : W2off);
  unsigned outOffB = (blockIdx.z==0) ? O0off : ((blockIdx.z==1) ? O1off : O2off);
  const unsigned short* W = (const unsigned short*)(g_scratch + wOffB);
  unsigned short* out = (unsigned short*)(g_scratch + outOffB);
  int lane = threadIdx.x & 63, wave = threadIdx.x >> 6;  // 0/1
  int r = lane & 15, q = lane >> 4;
  int M0 = blockIdx.x*64;
  int T0 = blockIdx.y*128 + wave*64;

  f32x4 acc[4][4];
  #pragma unroll
  for (int i=0;i<4;i++)
    #pragma unroll
    for (int j=0;j<4;j++)
      #pragma unroll
      for (int u=0;u<4;u++) acc[i][j][u] = 0.f;

  const unsigned short* Arow[4]; const unsigned short* Brow[4];
  #pragma unroll
  for (int i=0;i<4;i++) Arow[i] = W + (size_t)(M0 + i*16 + r)*Astride + q*8;
  #pragma unroll
  for (int j=0;j<4;j++) Brow[j] = X + (size_t)(T0 + j*16 + r)*Xstride + Xoff + q*8;

  for (int k0=0; k0<K; k0+=32){
    short8 a[4], bfr[4];
    #pragma unroll
    for (int i=0;i<4;i++) a[i]   = *(const short8*)(Arow[i] + k0);
    #pragma unroll
    for (int j=0;j<4;j++) bfr[j] = *(const short8*)(Brow[j] + k0);
    #pragma unroll
    for (int i=0;i<4;i++)
      #pragma unroll
      for (int j=0;j<4;j++)
        acc[i][j] = __builtin_amdgcn_mfma_f32_16x16x32_bf16(a[i], bfr[j], acc[i][j], 0, 0, 0);
  }
  gemm_epi<EPI,EXB>(acc, M0, T0, r, q, out, outStride, outOff,
                    sPtr, bPtr, extraIn, extraOffB, extraStride,
                    resOffB, resStride, resOff);
}

// ---------------- attention (one wave per query, 2 channels/lane) ----------------
__global__ __launch_bounds__(256) void attn_kernel(
  unsigned qOff, unsigned kOff, unsigned vOff, unsigned idxOff,
  const float* __restrict__ in, const float* __restrict__ wpos,
  unsigned aggOff)
{
  const unsigned short* Q  = (const unsigned short*)(g_scratch + qOff);
  const unsigned short* Kf = (const unsigned short*)(g_scratch + kOff);
  const unsigned short* V  = (const unsigned short*)(g_scratch + vOff);
  const int* idx           = (const int*)(g_scratch + idxOff);
  unsigned short* agg      = (unsigned short*)(g_scratch + aggOff);

  int lane = threadIdx.x & 63, wv = threadIdx.x >> 6;
  int t = blockIdx.x*4 + wv;
  int b = t >> 12, n = t & 4095;
  const float* xb = in + (size_t)b*9*NP;
  int c0 = lane*2;

  unsigned qv = *(const unsigned*)(Q + (size_t)t*128 + c0);
  float q0 = bf2f((unsigned short)(qv & 0xffff)), q1 = bf2f((unsigned short)(qv >> 16));
  float xn = xb[n], yn = xb[NP+n], zn = xb[2*NP+n];
  float wp00=wpos[c0*3+0],     wp01=wpos[c0*3+1],     wp02=wpos[c0*3+2];
  float wp10=wpos[(c0+1)*3+0], wp11=wpos[(c0+1)*3+1], wp12=wpos[(c0+1)*3+2];

  int mi[16]; float s[16];
  #pragma unroll
  for (int j=0;j<16;j++) mi[j] = idx[(size_t)t*16 + j] & 4095;  // mask: never OOB
  #pragma unroll
  for (int j=0;j<16;j++){
    unsigned kv = *(const unsigned*)(Kf + ((size_t)(b<<12) + mi[j])*128 + c0);
    float p = q0*bf2f((unsigned short)(kv & 0xffff)) + q1*bf2f((unsigned short)(kv >> 16));
    #pragma unroll
    for (int o=32;o>=1;o>>=1) p += __shfl_xor(p, o, 64);
    s[j] = p;
  }
  const float scale = 0.08838834764831845f; // 1/sqrt(128)
  float mx = s[0];
  #pragma unroll
  for (int j=1;j<16;j++) mx = fmaxf(mx, s[j]);
  float e[16], sum = 0.f;
  #pragma unroll
  for (int j=0;j<16;j++){ e[j] = __expf((s[j]-mx)*scale); sum += e[j]; }
  float inv = 1.f / sum;

  float a0=0.f, a1=0.f;
  #pragma unroll
  for (int j=0;j<16;j++){
    int m = mi[j];
    float w = e[j]*inv;
    unsigned vv = *(const unsigned*)(V + ((size_t)(b<<12) + m)*128 + c0);
    float rx = xn - xb[m];
    float ry = yn - xb[NP+m];
    float rz = zn - xb[2*NP+m];
    float p0 = wp00*rx + wp01*ry + wp02*rz;
    float p1 = wp10*rx + wp11*ry + wp12*rz;
    a0 += w*(bf2f((unsigned short)(vv & 0xffff)) + p0);
    a1 += w*(bf2f((unsigned short)(vv >> 16)) + p1);
  }
  unsigned pk = (unsigned)f2bf(a0) | ((unsigned)f2bf(a1) << 16);
  *(unsigned*)(agg + (size_t)t*128 + c0) = pk;
}

// ---------------- max/mean pool over tokens (two-stage) ----------------
__global__ __launch_bounds__(256) void pool_part(unsigned xfOff, unsigned gpOff)
{
  const unsigned short* xf = (const unsigned short*)(g_scratch + xfOff);
  float* gp = (float*)(g_scratch + gpOff);   // [b][seg][2][1024]
  int b = blockIdx.x >> 7, cblk = (blockIdx.x >> 3) & 15, seg = blockIdx.x & 7;
  int cl = threadIdx.x & 63, tg = threadIdx.x >> 6;
  int c = cblk*64 + cl;
  float mx = -3.0e38f, sm = 0.f;
  for (int n = seg*512 + tg; n < (seg+1)*512; n += 4){
    float v = bf2f(xf[((size_t)(b<<12) + n)*1024 + c]);
    mx = fmaxf(mx, v); sm += v;
  }
  __shared__ float smx[4][64], ssm[4][64];
  smx[tg][cl]=mx; ssm[tg][cl]=sm;
  __syncthreads();
  if (tg==0){
    #pragma unroll
    for (int k=1;k<4;k++){ mx = fmaxf(mx, smx[k][cl]); sm += ssm[k][cl]; }
    gp[((b*8 + seg)*2 + 0)*1024 + c] = mx;
    gp[((b*8 + seg)*2 + 1)*1024 + c] = sm;
  }
}
__global__ __launch_bounds__(256) void pool_final(unsigned gpOff, unsigned gOff)
{
  const float* gp = (const float*)(g_scratch + gpOff);
  float* g = (float*)(g_scratch + gOff);
  int b = blockIdx.x;
  for (int c = threadIdx.x; c < 1024; c += 256){
    float mx = -3.0e38f, sm = 0.f;
    #pragma unroll
    for (int seg=0; seg<8; ++seg){
      mx = fmaxf(mx, gp[((b*8 + seg)*2 + 0)*1024 + c]);
      sm += gp[((b*8 + seg)*2 + 1)*1024 + c];
    }
    g[b*2048 + c] = mx;
    g[b*2048 + 1024 + c] = sm * (1.f/4096.f);
  }
}

// gb[b][o] = cls_bias1[o] + sum_c W1[o][1024+c]*g[b][c]
__global__ __launch_bounds__(256) void gterm_kernel(const float* __restrict__ w1,
                                                    const float* __restrict__ bias1,
                                                    unsigned gOff, unsigned gbOff)
{
  const float* g = (const float*)(g_scratch + gOff);
  float* gb = (float*)(g_scratch + gbOff);
  int b = blockIdx.x >> 3, og = (blockIdx.x & 7)*64;
  int ol = threadIdx.x & 63, cq = threadIdx.x >> 6;
  int o = og + ol;
  const float* wrow = w1 + (size_t)o*3072 + 1024 + cq*512;
  const float* gp = g + b*2048 + cq*512;
  float acc = 0.f;
  for (int c=0;c<512;c+=4){
    float4 wv4 = *(const float4*)(wrow + c);
    acc += wv4.x*gp[c] + wv4.y*gp[c+1] + wv4.z*gp[c+2] + wv4.w*gp[c+3];
  }
  __shared__ float sred[4][64];
  sred[cq][ol] = acc;
  __syncthreads();
  if (cq==0){
    acc += sred[1][ol] + sred[2][ol] + sred[3][ol];
    gb[b*512 + o] = acc + bias1[o];
  }
}

// ---------------- classifier head (O=13), fp32 out ----------------
__global__ __launch_bounds__(256) void cls3_kernel(unsigned c2Off,
                                                   const float* __restrict__ w3,
                                                   const float* __restrict__ bias3,
                                                   float* __restrict__ outp)
{
  const unsigned short* c2 = (const unsigned short*)(g_scratch + c2Off);
  __shared__ float wf[13*256];
  __shared__ float bf3[13];
  for (int i=threadIdx.x;i<13*256;i+=256) wf[i]=w3[i];
  if (threadIdx.x < 13) bf3[threadIdx.x]=bias3[threadIdx.x];
  __syncthreads();
  int lane = threadIdx.x & 63, wv = threadIdx.x >> 6;
  int tl = lane >> 2, cq = lane & 3;
  int t = blockIdx.x*64 + wv*16 + tl;
  const unsigned short* xrow = c2 + (size_t)t*256 + cq*64;
  float acc[13];
  #pragma unroll
  for (int o=0;o<13;o++) acc[o]=0.f;
  for (int c=0;c<64;c+=8){
    short8 xv = *(const short8*)(xrow + c);
    float xs[8];
    #pragma unroll
    for (int u=0;u<8;u++) xs[u]=bf2f((unsigned short)xv[u]);
    #pragma unroll
    for (int o=0;o<13;o++){
      const float* wr = wf + o*256 + cq*64 + c;
      #pragma unroll
      for (int u=0;u<8;u++) acc[o] += wr[u]*xs[u];
    }
  }
  #pragma unroll
  for (int o=0;o<13;o++){
    acc[o] += __shfl_xor(acc[o], 1, 64);
    acc[o] += __shfl_xor(acc[o], 2, 64);
  }
  if (cq==0){
    int b = t >> 12, n = t & 4095;
    #pragma unroll
    for (int o=0;o<13;o++)
      outp[((size_t)b*13 + o)*NP + n] = acc[o] + bf3[o];
  }
}

// ---------------- launch ----------------
extern "C" void kernel_launch(void* const* d_in, const int* in_sizes, int n_in,
                              void* d_out, int out_size, void* d_ws, size_t ws_size,
                              hipStream_t stream) {
  (void)in_sizes; (void)n_in; (void)out_size; (void)d_ws; (void)ws_size;
  const float* in      = (const float*)d_in[0];
  const float* emb_w1  = (const float*)d_in[1];
  const float* emb_s1  = (const float*)d_in[2];
  const float* emb_b1  = (const float*)d_in[3];
  const float* emb_w2  = (const float*)d_in[4];
  const float* emb_s2  = (const float*)d_in[5];
  const float* emb_b2  = (const float*)d_in[6];
  const float* blk_wq  = (const float*)d_in[7];
  const float* blk_wk  = (const float*)d_in[8];
  const float* blk_wv  = (const float*)d_in[9];
  const float* blk_wpos= (const float*)d_in[10];
  const float* blk_wo  = (const float*)d_in[11];
  const float* blk_s   = (const float*)d_in[12];
  const float* blk_b   = (const float*)d_in[13];
  const float* fuse_w  = (const float*)d_in[14];
  const float* fuse_s  = (const float*)d_in[15];
  const float* fuse_b  = (const float*)d_in[16];
  const float* cls_w1  = (const float*)d_in[17];
  const float* cls_b1  = (const float*)d_in[18];
  const float* cls_s1  = (const float*)d_in[19];
  const float* cls_sh1 = (const float*)d_in[20];
  const float* cls_w2  = (const float*)d_in[21];
  const float* cls_b2  = (const float*)d_in[22];
  const float* cls_s2  = (const float*)d_in[23];
  const float* cls_sh2 = (const float*)d_in[24];
  const float* cls_w3  = (const float*)d_in[25];
  const float* cls_b3  = (const float*)d_in[26];

  // byte offsets into g_scratch
  const unsigned MB = 1u<<20, KB = 1024u;
  const unsigned OFF_IDX   = 0;                 // 1 MB   int idx[T][16]
  const unsigned OFF_WQ    = 1*MB;              // 96 KB  bf16 (3,128,128)
  const unsigned OFF_WK    = 1*MB + 128*KB;     // 96 KB
  const unsigned OFF_WV    = 1*MB + 256*KB;     // 96 KB
  const unsigned OFF_WO    = 1*MB + 384*KB;     // 96 KB
  const unsigned OFF_WEMB2 = 1*MB + 512*KB;     // 32 KB  bf16 (128,128)
  const unsigned OFF_WFUSE = 1*MB + 576*KB;     // 768 KB bf16 (1024,384)
  const unsigned OFF_WW1   = 3*MB;              // 1 MB   bf16 (512,1024) x-half
  const unsigned OFF_WW2   = 4*MB;              // 256 KB bf16 (256,512)
  const unsigned OFF_X1    = 5*MB;              // 4 MB   bf16 (T,128)
  const unsigned OFF_X0    = 9*MB;              // 4 MB   bf16 (T,128)
  const unsigned OFF_XCAT  = 13*MB;             // 12 MB  bf16 (T,384)
  const unsigned OFF_QB    = 25*MB;             // 4 MB
  const unsigned OFF_KB    = 29*MB;             // 4 MB
  const unsigned OFF_VB    = 33*MB;             // 4 MB
  const unsigned OFF_AGG   = 37*MB;             // 4 MB
  const unsigned OFF_XF    = 41*MB;             // 32 MB  bf16 (T,1024)
  const unsigned OFF_C1    = 73*MB;             // 16 MB  bf16 (T,512)
  const unsigned OFF_C2    = 89*MB;             // 8 MB   bf16 (T,256)
  const unsigned OFF_G     = 97*MB;             // 32 KB  f32 (B,2048)
  const unsigned OFF_GB    = 97*MB + 64*KB;     // 8 KB   f32 (B,512)
  const unsigned OFF_GP    = 97*MB + 128*KB;    // 256 KB f32 pool partials
  const unsigned OFF_THR   = 97*MB + 512*KB;    // 64 KB  f32 thr[T]
  const unsigned OFF_PD    = 98*MB;             // 16 MB  f32 knn bound vals / p2 dists
  const unsigned OFF_PI    = 114*MB;            // 16 MB  int knn idx (p2)
  float* outp = (float*)d_out;                  // (B,13,N) f32

  // 0: fused weight conversion prepass (fp32 -> bf16 into scratch)
  CvtArgs ca;
  ca.src[0]=emb_w2;  ca.dstOff[0]=OFF_WEMB2; ca.n[0]=128*128;
  ca.src[1]=blk_wq;  ca.dstOff[1]=OFF_WQ;    ca.n[1]=3*128*128;
  ca.src[2]=blk_wk;  ca.dstOff[2]=OFF_WK;    ca.n[2]=3*128*128;
  ca.src[3]=blk_wv;  ca.dstOff[3]=OFF_WV;    ca.n[3]=3*128*128;
  ca.src[4]=blk_wo;  ca.dstOff[4]=OFF_WO;    ca.n[4]=3*128*128;
  ca.src[5]=fuse_w;  ca.dstOff[5]=OFF_WFUSE; ca.n[5]=1024*384;
  ca.src[6]=cls_w2;  ca.dstOff[6]=OFF_WW2;   ca.n[6]=256*512;
  ca.src[7]=cls_w1;  ca.dstOff[7]=OFF_WW1;   ca.n[7]=512*1024;
  cvt_all<<<dim3(64,8), 256, 0, stream>>>(ca);

  // 1-4: KNN (cheap-threshold two-pass)
  knn_p1<<<dim3(16,16,4), 256, 0, stream>>>(in, OFF_PD);
  knn_thr<<<dim3(64), 256, 0, stream>>>(OFF_PD, OFF_THR);
  knn_p2<<<dim3(16,16,4), 256, 0, stream>>>(in, OFF_THR, OFF_PD, OFF_PI);
  knn_mrg<<<dim3(256), 64, 0, stream>>>(OFF_PD, OFF_PI, OFF_IDX);
  // 5-6: embedding
  emb1_kernel<<<dim3(64,4), 256, 0, stream>>>(in, emb_w1, emb_s1, emb_b1, OFF_X1);
  gemm_small<EPI_RELU_SB,false><<<dim3(2,128,1), 128, 0, stream>>>(
      OFF_WEMB2, OFF_WEMB2, OFF_WEMB2, OFF_X0, OFF_X0, OFF_X0,
      OFF_X1, 128, 0, 128, 0, emb_s2, emb_b2,
      nullptr, 0, 0, 0, 0, 0, 128, 128);
  // 7-9: transformer blocks
  for (int i=0;i<3;i++){
    unsigned wq = OFF_WQ + i*32768, wk = OFF_WK + i*32768;
    unsigned wv = OFF_WV + i*32768, wo = OFF_WO + i*32768;
    const float* wp = blk_wpos + i*128*3;
    const float* si = blk_s + i*128;
    const float* bi = blk_b + i*128;
    unsigned XiOff = (i==0) ? OFF_X0 : OFF_XCAT;
    int Xs = (i==0) ? 128 : 384;
    int Xo = (i==0) ? 0 : (i-1)*128;
    gemm_small<EPI_PLAIN,false><<<dim3(2,128,3), 128, 0, stream>>>(
        wq, wk, wv, OFF_QB, OFF_KB, OFF_VB,
        XiOff, Xs, Xo, 128, 0, nullptr, nullptr,
        nullptr, 0, 0, 0, 0, 0, 128, 128);
    attn_kernel<<<dim3(4096), 256, 0, stream>>>(OFF_QB, OFF_KB, OFF_VB, OFF_IDX, in, wp, OFF_AGG);
    gemm_small<EPI_RES,false><<<dim3(2,128,1), 128, 0, stream>>>(
        wo, wo, wo, OFF_XCAT, OFF_XCAT, OFF_XCAT,
        OFF_AGG, 128, 0, 384, i*128, si, bi,
        nullptr, 0, 0, XiOff, Xs, Xo, 128, 128);
  }
  // 10: fuse (leaky relu), LDS-staged + swizzled
  gemm_lds<EPI_LEAKY,false><<<dim3(8,128,1), 256, 0, stream>>>(
      OFF_WFUSE, OFF_WFUSE, OFF_WFUSE, OFF_XF, OFF_XF, OFF_XF,
      OFF_XCAT, 384, 0, 1024, 0, fuse_s, fuse_b,
      nullptr, 0, 0, 0, 0, 0, 384, 384);
  // 11-13: pooling (two-stage) + broadcast-g term of cls1 (fp32)
  pool_part<<<dim3(512), 256, 0, stream>>>(OFF_XF, OFF_GP);
  pool_final<<<dim3(4), 256, 0, stream>>>(OFF_GP, OFF_G);
  gterm_kernel<<<dim3(32), 256, 0, stream>>>(cls_w1, cls_b1, OFF_G, OFF_GB);
  // 14: cls1 (K=1024 x-half of W1; gb = W1[:,1024:]@g + bias1 as extra)
  gemm_lds<EPI_CLS,false><<<dim3(4,128,1), 256, 0, stream>>>(
      OFF_WW1, OFF_WW1, OFF_WW1, OFF_C1, OFF_C1, OFF_C1,
      OFF_XF, 1024, 0, 512, 0, cls_s1, cls_sh1,
      nullptr, OFF_GB, 512, 0, 0, 0, 1024, 1024);
  // 15: cls2 (K=512), LDS-staged
  gemm_lds<EPI_CLS,true><<<dim3(2,128,1), 256, 0, stream>>>(
      OFF_WW2, OFF_WW2, OFF_WW2, OFF_C2, OFF_C2, OFF_C2,
      OFF_C1, 512, 0, 256, 0, cls_s2, cls_sh2,
      cls_b2, 0, 0, 0, 0, 0, 512, 512);
  // 16: cls3 -> d_out (fp32)
  cls3_kernel<<<dim3(256), 256, 0, stream>>>(OFF_C2, cls_w3, cls_b3, outp);
}

// Round 14
// 513.745 us; speedup vs baseline: 2.2375x; 1.0539x over previous
//
#include <hip/hip_runtime.h>

// PVDST semseg, MI355X/gfx950. FP32 I/O. Round-14.
//   - R13 post-mortem: LDS staging won (-60us, fuse/cls1/cls2). Top-5 now
//     harness d_ws re-poison memsets (256MB @82% HBM) -> all our kernels
//     <41us; steering by model this round.
//   - gemm_small_lds: LDS staging for K=128 sites (emb2/qkv/wo): 2-wave
//     64Mx128T, BK=32, 12KB LDS, ds_read_b128 frags (2-way bank alias=free).
//   - attn: 16 lanes/query (8ch/lane, 16B gathers), shuffle depth 4; halves
//     per-query instr count.
// KNN cheap-threshold two-pass + gemm_lds big-K unchanged (absmax 2.9e-3).

#define NB 4
#define NP 4096
#define NT 16384   // NB*NP tokens

#define SCRATCH_BYTES (132u*1024u*1024u)
__device__ __align__(256) unsigned char g_scratch[SCRATCH_BYTES];

typedef __attribute__((ext_vector_type(8))) short short8;   // 8 x bf16 MFMA frag
typedef __attribute__((ext_vector_type(4))) float f32x4;    // MFMA acc
typedef __attribute__((ext_vector_type(4))) unsigned short ushort4v;

__device__ __forceinline__ float bf2f(unsigned short u){
  unsigned int v = ((unsigned int)u) << 16;
  return __builtin_bit_cast(float, v);
}
__device__ __forceinline__ unsigned short f2bf(float f){
  unsigned int x = __builtin_bit_cast(unsigned int, f);
  x += 0x7fffu + ((x >> 16) & 1u);     // RNE
  return (unsigned short)(x >> 16);
}
// numpy-matched: ((x*x)+(y*y))+(z*z), each op rounded (no fma contraction)
__device__ __forceinline__ float sq3(float x, float y, float z){
  return __fadd_rn(__fadd_rn(__fmul_rn(x,x), __fmul_rn(y,y)), __fmul_rn(z,z));
}

// sorted-4 insert: 7 native min/max, no masks
#define KINS4(a0,a1,a2,a3,dd) do{ float _d=(dd);\
  a3=fminf(fmaxf(a2,_d),a3); a2=fminf(fmaxf(a1,_d),a2);\
  a1=fminf(fmaxf(a0,_d),a1); a0=fminf(a0,_d);}while(0)

// dist-only sorted-ascending top-16 (thr kernel)
#define KDECLD float d0=3.0e38f,d1=3.0e38f,d2=3.0e38f,d3=3.0e38f,d4=3.0e38f,\
  d5=3.0e38f,d6=3.0e38f,d7=3.0e38f,d8=3.0e38f,d9=3.0e38f,d10=3.0e38f,\
  d11=3.0e38f,d12=3.0e38f,d13=3.0e38f,d14=3.0e38f,d15=3.0e38f
#define KINSD(dd) do{ float _d=(dd); \
  d15=fminf(fmaxf(d14,_d),d15); d14=fminf(fmaxf(d13,_d),d14); \
  d13=fminf(fmaxf(d12,_d),d13); d12=fminf(fmaxf(d11,_d),d12); \
  d11=fminf(fmaxf(d10,_d),d11); d10=fminf(fmaxf(d9 ,_d),d10); \
  d9 =fminf(fmaxf(d8 ,_d),d9 ); d8 =fminf(fmaxf(d7 ,_d),d8 ); \
  d7 =fminf(fmaxf(d6 ,_d),d7 ); d6 =fminf(fmaxf(d5 ,_d),d6 ); \
  d5 =fminf(fmaxf(d4 ,_d),d5 ); d4 =fminf(fmaxf(d3 ,_d),d4 ); \
  d3 =fminf(fmaxf(d2 ,_d),d3 ); d2 =fminf(fmaxf(d1 ,_d),d2 ); \
  d1 =fminf(fmaxf(d0 ,_d),d1 ); d0 =fminf(d0,_d); }while(0)

// full (dist,idx) stable insert (merge only; strict < => lower index wins)
#define KDECL KDECLD; int i0=0,i1=0,i2=0,i3=0,i4=0,i5=0,i6=0,i7=0,i8=0,\
  i9=0,i10=0,i11=0,i12=0,i13=0,i14=0,i15=0
#define KINS(dd,mm) do{ float _d=(dd); int _m=(mm); \
  bool c15 = _d < d15; \
  bool c14 = _d < d14;  i15 = c14 ? i14 : (c15 ? _m : i15);  d15 = fminf(fmaxf(d14,_d), d15); \
  bool c13 = _d < d13;  i14 = c13 ? i13 : (c14 ? _m : i14);  d14 = fminf(fmaxf(d13,_d), d14); \
  bool c12 = _d < d12;  i13 = c12 ? i12 : (c13 ? _m : i13);  d13 = fminf(fmaxf(d12,_d), d13); \
  bool c11 = _d < d11;  i12 = c11 ? i11 : (c12 ? _m : i12);  d12 = fminf(fmaxf(d11,_d), d12); \
  bool c10 = _d < d10;  i11 = c10 ? i10 : (c11 ? _m : i11);  d11 = fminf(fmaxf(d10,_d), d11); \
  bool c9  = _d < d9;   i10 = c9  ? i9  : (c10 ? _m : i10);  d10 = fminf(fmaxf(d9 ,_d), d10); \
  bool c8  = _d < d8;   i9  = c8  ? i8  : (c9  ? _m : i9 );  d9  = fminf(fmaxf(d8 ,_d), d9 ); \
  bool c7  = _d < d7;   i8  = c7  ? i7  : (c8  ? _m : i8 );  d8  = fminf(fmaxf(d7 ,_d), d8 ); \
  bool c6  = _d < d6;   i7  = c6  ? i6  : (c7  ? _m : i7 );  d7  = fminf(fmaxf(d6 ,_d), d7 ); \
  bool c5  = _d < d5;   i6  = c5  ? i5  : (c6  ? _m : i6 );  d6  = fminf(fmaxf(d5 ,_d), d6 ); \
  bool c4  = _d < d4;   i5  = c4  ? i4  : (c5  ? _m : i5 );  d5  = fminf(fmaxf(d4 ,_d), d5 ); \
  bool c3  = _d < d3;   i4  = c3  ? i3  : (c4  ? _m : i4 );  d4  = fminf(fmaxf(d3 ,_d), d4 ); \
  bool c2  = _d < d2;   i3  = c2  ? i2  : (c3  ? _m : i3 );  d3  = fminf(fmaxf(d2 ,_d), d3 ); \
  bool c1  = _d < d1;   i2  = c1  ? i1  : (c2  ? _m : i2 );  d2  = fminf(fmaxf(d1 ,_d), d2 ); \
  bool c0  = _d < d0;   i1  = c0  ? i0  : (c1  ? _m : i1 );  d1  = fminf(fmaxf(d0 ,_d), d1 ); \
  i0 = c0 ? _m : i0;  d0 = fminf(d0,_d); }while(0)

// ---------------- fused weight fp32 -> bf16 conversion prepass ----------------
struct CvtArgs {
  const float* src[8];
  unsigned dstOff[8];
  int n[8];
};
__global__ __launch_bounds__(256) void cvt_all(CvtArgs a)
{
  int y = blockIdx.y;
  const float* src = a.src[y];
  unsigned short* dst = (unsigned short*)(g_scratch + a.dstOff[y]);
  int n = a.n[y];
  if (y == 7){
    for (int i = blockIdx.x*256 + threadIdx.x; i < n; i += gridDim.x*256){
      int r = i >> 10, c = i & 1023;
      dst[i] = f2bf(src[(size_t)r*3072 + c]);
    }
  } else {
    for (int i = blockIdx.x*256 + threadIdx.x; i < n; i += gridDim.x*256)
      dst[i] = f2bf(src[i]);
  }
}

// ---------------- KNN pass1: 4x sorted-4 bound lists, fma dist ----------------
__global__ __launch_bounds__(256) void knn_p1(const float* __restrict__ in,
                                              unsigned pdOff)
{
  float* pdist = (float*)(g_scratch + pdOff);
  __shared__ float4 sp[256];
  int b = blockIdx.z, qc = blockIdx.x, cc = blockIdx.y;
  const float* xb = in + (size_t)b*9*NP;
  int base = cc*256;
  {
    int i = threadIdx.x;
    float x = xb[base+i], y = xb[NP+base+i], z = xb[2*NP+base+i];
    sp[i] = make_float4(x,y,z, x*x+y*y+z*z);
  }
  __syncthreads();
  int n = qc*256 + threadIdx.x;
  float xn=xb[n], yn=xb[NP+n], zn=xb[2*NP+n];
  float sqn = xn*xn + yn*yn + zn*zn;
  float A0=3e38f,A1=3e38f,A2=3e38f,A3=3e38f;
  float B0=3e38f,B1=3e38f,B2=3e38f,B3=3e38f;
  float C0=3e38f,C1=3e38f,C2=3e38f,C3=3e38f;
  float D0=3e38f,D1=3e38f,D2=3e38f,D3=3e38f;
  for (int mm=0; mm<256; mm+=4){
    float4 p0 = sp[mm], p1 = sp[mm+1], p2 = sp[mm+2], p3 = sp[mm+3];
    float e0 = sqn + p0.w - 2.f*(xn*p0.x + yn*p0.y + zn*p0.z);
    float e1 = sqn + p1.w - 2.f*(xn*p1.x + yn*p1.y + zn*p1.z);
    float e2 = sqn + p2.w - 2.f*(xn*p2.x + yn*p2.y + zn*p2.z);
    float e3 = sqn + p3.w - 2.f*(xn*p3.x + yn*p3.y + zn*p3.z);
    KINS4(A0,A1,A2,A3,e0);
    KINS4(B0,B1,B2,B3,e1);
    KINS4(C0,C1,C2,C3,e2);
    KINS4(D0,D1,D2,D3,e3);
  }
  size_t ob = ((size_t)(b*16+cc)*16)*NP + n;
  pdist[ob+ 0*(size_t)NP]=A0; pdist[ob+ 1*(size_t)NP]=A1; pdist[ob+ 2*(size_t)NP]=A2; pdist[ob+ 3*(size_t)NP]=A3;
  pdist[ob+ 4*(size_t)NP]=B0; pdist[ob+ 5*(size_t)NP]=B1; pdist[ob+ 6*(size_t)NP]=B2; pdist[ob+ 7*(size_t)NP]=B3;
  pdist[ob+ 8*(size_t)NP]=C0; pdist[ob+ 9*(size_t)NP]=C1; pdist[ob+10*(size_t)NP]=C2; pdist[ob+11*(size_t)NP]=C3;
  pdist[ob+12*(size_t)NP]=D0; pdist[ob+13*(size_t)NP]=D1; pdist[ob+14*(size_t)NP]=D2; pdist[ob+15*(size_t)NP]=D3;
}

// ---------------- KNN thr: 16th-smallest of the 256 bound values + margin ----
__global__ __launch_bounds__(256) void knn_thr(unsigned pdOff, unsigned thrOff)
{
  const float* pdist = (const float*)(g_scratch + pdOff);
  float* thr = (float*)(g_scratch + thrOff);
  int t = blockIdx.x*256 + threadIdx.x;
  int b = t >> 12, n = t & 4095;
  KDECLD;
  for (int cc=0; cc<16; ++cc){
    size_t ob = ((size_t)(b*16+cc)*16)*NP + n;
    #pragma unroll
    for (int j=0;j<16;j++){ KINSD(pdist[ob + (size_t)j*NP]); }
  }
  thr[t] = d15*1.000002f + 2e-4f;   // margin >> fma-vs-_rn error
}

// ---------------- KNN pass2: append qualifying (d,i), exact _rn dist --------
__global__ __launch_bounds__(256) void knn_p2(const float* __restrict__ in,
                                              unsigned thrOff, unsigned pdOff, unsigned piOff)
{
  const float* thr = (const float*)(g_scratch + thrOff);
  float* pdist = (float*)(g_scratch + pdOff);
  int*   pidx  = (int*)  (g_scratch + piOff);
  __shared__ float4 sp[256];
  int b = blockIdx.z, qc = blockIdx.x, cc = blockIdx.y;
  const float* xb = in + (size_t)b*9*NP;
  int base = cc*256;
  {
    int i = threadIdx.x;
    float x = xb[base+i], y = xb[NP+base+i], z = xb[2*NP+base+i];
    sp[i] = make_float4(x,y,z,sq3(x,y,z));
  }
  __syncthreads();
  int n = qc*256 + threadIdx.x;
  float xn=xb[n], yn=xb[NP+n], zn=xb[2*NP+n];
  float sqn = sq3(xn,yn,zn);
  float th = thr[(b<<12) + n];
  size_t o = ((size_t)((b*16 + cc)*NP + n))*16;
  int cnt = 0;
  for (int mm=0; mm<256; ++mm){
    float4 p = sp[mm];
    float dot = __fadd_rn(__fadd_rn(__fmul_rn(xn,p.x), __fmul_rn(yn,p.y)), __fmul_rn(zn,p.z));
    float d = __fsub_rn(__fadd_rn(sqn, p.w), __fmul_rn(2.0f, dot));
    if (d <= th && cnt < 16){
      pdist[o+cnt] = d;
      pidx[o+cnt] = base + mm;
      cnt++;
    }
  }
  if (cnt < 16) pdist[o+cnt] = 3.0e38f;   // sentinel terminator
}

// ---------------- KNN final merge (index-ordered sparse lists) ----------------
__global__ __launch_bounds__(64) void knn_mrg(unsigned pdOff, unsigned piOff, unsigned idxOff)
{
  const float* pdist = (const float*)(g_scratch + pdOff);
  const int*   pidx  = (const int*)  (g_scratch + piOff);
  int*         idxOut= (int*)(g_scratch + idxOff);
  int t = blockIdx.x*64 + threadIdx.x;
  int b = t >> 12, n = t & 4095;
  KDECL;
  for (int cc=0; cc<16; ++cc){
    size_t o = ((size_t)((b*16 + cc)*NP + n))*16;
    #pragma unroll 1
    for (int j=0;j<16;j++){
      float pd = pdist[o+j];
      if (pd >= 1.0e38f) break;          // sentinel
      KINS(pd, pidx[o+j]);
    }
  }
  idxOut[t*16+ 0]=i0;  idxOut[t*16+ 1]=i1;  idxOut[t*16+ 2]=i2;  idxOut[t*16+ 3]=i3;
  idxOut[t*16+ 4]=i4;  idxOut[t*16+ 5]=i5;  idxOut[t*16+ 6]=i6;  idxOut[t*16+ 7]=i7;
  idxOut[t*16+ 8]=i8;  idxOut[t*16+ 9]=i9;  idxOut[t*16+10]=i10; idxOut[t*16+11]=i11;
  idxOut[t*16+12]=i12; idxOut[t*16+13]=i13; idxOut[t*16+14]=i14; idxOut[t*16+15]=i15;
}

// ---------------- embedding conv1 (Cin=9), output-split ----------------
__global__ __launch_bounds__(256) void emb1_kernel(const float* __restrict__ in,
                                                   const float* __restrict__ w1,
                                                   const float* __restrict__ s1,
                                                   const float* __restrict__ b1,
                                                   unsigned x1Off)
{
  unsigned short* x1 = (unsigned short*)(g_scratch + x1Off);
  int og = blockIdx.y*32;
  __shared__ float wf[32*9], sf[32], bf_[32];
  for (int i = threadIdx.x; i < 32*9; i += 256) wf[i] = w1[og*9 + i];
  if (threadIdx.x < 32){ sf[threadIdx.x]=s1[og+threadIdx.x]; bf_[threadIdx.x]=b1[og+threadIdx.x]; }
  __syncthreads();
  int t = blockIdx.x*256 + threadIdx.x;
  int b = t >> 12, n = t & 4095;
  float v[9];
  #pragma unroll
  for (int c=0;c<9;c++) v[c] = in[((size_t)b*9 + c)*NP + n];
  for (int o=0;o<32;o+=2){
    float a0=0.f, a1=0.f;
    #pragma unroll
    for (int c=0;c<9;c++){ a0 += wf[o*9+c]*v[c]; a1 += wf[(o+1)*9+c]*v[c]; }
    a0 = fmaxf(sf[o]*a0 + bf_[o], 0.f);
    a1 = fmaxf(sf[o+1]*a1 + bf_[o+1], 0.f);
    unsigned pk = (unsigned)f2bf(a0) | ((unsigned)f2bf(a1) << 16);
    *(unsigned*)(x1 + (size_t)t*128 + og + o) = pk;
  }
}

// ---------------- GEMM epilogue (shared) ----------------
enum { EPI_PLAIN=0, EPI_RELU_SB=1, EPI_RES=2, EPI_LEAKY=3, EPI_CLS=4 };

template<int EPI, bool EXB>
__device__ __forceinline__ void gemm_epi(
    f32x4 (&acc)[4][4], int M0, int T0, int r, int q,
    unsigned short* out, int outStride, int outOff,
    const float* sPtr, const float* bPtr,
    const float* extraIn, unsigned extraOffB, int extraStride,
    unsigned resOffB, int resStride, int resOff)
{
  #pragma unroll
  for (int i=0;i<4;i++){
    int m = M0 + i*16 + q*4;
    float sv[4], bv[4];
    if constexpr (EPI != EPI_PLAIN){
      #pragma unroll
      for (int u=0;u<4;u++){ sv[u]=sPtr[m+u]; bv[u]=bPtr[m+u]; }
    }
    #pragma unroll
    for (int j=0;j<4;j++){
      int token = T0 + j*16 + r;
      float ex[4];
      if constexpr (EPI == EPI_CLS){
        int bb = token >> 12;
        #pragma unroll
        for (int u=0;u<4;u++)
          ex[u] = EXB ? extraIn[bb*extraStride + m + u]
                      : ((const float*)(g_scratch + extraOffB))[bb*extraStride + m + u];
      }
      float resv[4];
      if constexpr (EPI == EPI_RES){
        const unsigned short* resPtr = (const unsigned short*)(g_scratch + resOffB);
        ushort4v rv = *(const ushort4v*)(resPtr + (size_t)token*resStride + resOff + m);
        #pragma unroll
        for (int u=0;u<4;u++) resv[u]=bf2f(rv[u]);
      }
      ushort4v ov;
      #pragma unroll
      for (int u=0;u<4;u++){
        float aa = acc[i][j][u];
        float vo;
        if constexpr (EPI == EPI_PLAIN)        vo = aa;
        else if constexpr (EPI == EPI_RELU_SB) vo = fmaxf(sv[u]*aa + bv[u], 0.f);
        else if constexpr (EPI == EPI_RES)     vo = resv[u] + fmaxf(sv[u]*aa + bv[u], 0.f);
        else if constexpr (EPI == EPI_LEAKY){  float tt = sv[u]*aa + bv[u]; vo = tt>0.f ? tt : 0.2f*tt; }
        else { vo = fmaxf(sv[u]*(aa + ex[u]) + bv[u], 0.f); }
        ov[u] = f2bf(vo);
      }
      *(ushort4v*)(out + (size_t)token*outStride + outOff + m) = ov;
    }
  }
}

// ---------------- LDS-staged GEMM: 128Mx128T, BK=32 (fuse, cls1, cls2) -------
template<int EPI, bool EXB>
__global__ __launch_bounds__(256) void gemm_lds(
    unsigned W0off, unsigned W1off, unsigned W2off,
    unsigned O0off, unsigned O1off, unsigned O2off,
    unsigned XoffB, int Xstride, int Xoff,
    int outStride, int outOff,
    const float* sPtr, const float* bPtr,
    const float* extraIn, unsigned extraOffB, int extraStride,
    unsigned resOffB, int resStride, int resOff,
    int K, int Astride)
{
  __shared__ unsigned short As[128*32];
  __shared__ unsigned short Bs[128*32];
  const unsigned short* X = (const unsigned short*)(g_scratch + XoffB);
  unsigned wOffB   = (blockIdx.z==0) ? W0off : ((blockIdx.z==1) ? W1off : W2off);
  unsigned outOffB = (blockIdx.z==0) ? O0off : ((blockIdx.z==1) ? O1off : O2off);
  const unsigned short* W = (const unsigned short*)(g_scratch + wOffB);
  unsigned short* out = (unsigned short*)(g_scratch + outOffB);
  int lin = blockIdx.x + gridDim.x*blockIdx.y;
  int bx = lin >> 7;
  int by = (lin & 7)*16 + ((lin >> 3) & 15);
  int M0 = bx*128, T0 = by*128;
  int t = threadIdx.x;
  int lane = t & 63, wave = t >> 6;
  int r = lane & 15, q = lane >> 4;
  int srow = t >> 2, schunk = t & 3;

  const unsigned short* Ag0 = W + (size_t)(M0 + srow)*Astride + schunk*8;
  const unsigned short* Ag1 = W + (size_t)(M0 + 64 + srow)*Astride + schunk*8;
  const unsigned short* Bg0 = X + (size_t)(T0 + srow)*Xstride + Xoff + schunk*8;
  const unsigned short* Bg1 = X + (size_t)(T0 + 64 + srow)*Xstride + Xoff + schunk*8;
  unsigned short* Aw0 = &As[srow*32 + schunk*8];
  unsigned short* Aw1 = &As[(64 + srow)*32 + schunk*8];
  unsigned short* Bw0 = &Bs[srow*32 + schunk*8];
  unsigned short* Bw1 = &Bs[(64 + srow)*32 + schunk*8];

  int Mw = (wave>>1)*64, Tw = (wave&1)*64;
  f32x4 acc[4][4];
  #pragma unroll
  for (int i=0;i<4;i++)
    #pragma unroll
    for (int j=0;j<4;j++)
      #pragma unroll
      for (int u=0;u<4;u++) acc[i][j][u] = 0.f;

  for (int k0=0; k0<K; k0+=32){
    short8 va0 = *(const short8*)(Ag0 + k0);
    short8 va1 = *(const short8*)(Ag1 + k0);
    short8 vb0 = *(const short8*)(Bg0 + k0);
    short8 vb1 = *(const short8*)(Bg1 + k0);
    if (k0) __syncthreads();
    *(short8*)Aw0 = va0; *(short8*)Aw1 = va1;
    *(short8*)Bw0 = vb0; *(short8*)Bw1 = vb1;
    __syncthreads();
    short8 a[4], bfr[4];
    #pragma unroll
    for (int i=0;i<4;i++) a[i]   = *(const short8*)(&As[(Mw + i*16 + r)*32 + q*8]);
    #pragma unroll
    for (int j=0;j<4;j++) bfr[j] = *(const short8*)(&Bs[(Tw + j*16 + r)*32 + q*8]);
    #pragma unroll
    for (int i=0;i<4;i++)
      #pragma unroll
      for (int j=0;j<4;j++)
        acc[i][j] = __builtin_amdgcn_mfma_f32_16x16x32_bf16(a[i], bfr[j], acc[i][j], 0, 0, 0);
  }
  gemm_epi<EPI,EXB>(acc, M0+Mw, T0+Tw, r, q, out, outStride, outOff,
                    sPtr, bPtr, extraIn, extraOffB, extraStride,
                    resOffB, resStride, resOff);
}

// ---------------- LDS-staged 2-wave 64Mx128T (K=128 sites: emb2, qkv, wo) ----
template<int EPI, bool EXB>
__global__ __launch_bounds__(128) void gemm_small_lds(
    unsigned W0off, unsigned W1off, unsigned W2off,
    unsigned O0off, unsigned O1off, unsigned O2off,
    unsigned XoffB, int Xstride, int Xoff,
    int outStride, int outOff,
    const float* sPtr, const float* bPtr,
    const float* extraIn, unsigned extraOffB, int extraStride,
    unsigned resOffB, int resStride, int resOff,
    int K, int Astride)
{
  __shared__ unsigned short As[64*32];    // 4 KB
  __shared__ unsigned short Bs[128*32];   // 8 KB
  const unsigned short* X = (const unsigned short*)(g_scratch + XoffB);
  unsigned wOffB   = (blockIdx.z==0) ? W0off : ((blockIdx.z==1) ? W1off : W2off);
  unsigned outOffB = (blockIdx.z==0) ? O0off : ((blockIdx.z==1) ? O1off : O2off);
  const unsigned short* W = (const unsigned short*)(g_scratch + wOffB);
  unsigned short* out = (unsigned short*)(g_scratch + outOffB);
  int M0 = blockIdx.x*64, T0 = blockIdx.y*128;
  int t = threadIdx.x;
  int lane = t & 63, wave = t >> 6;   // 0/1
  int r = lane & 15, q = lane >> 4;
  int srow = t >> 2, schunk = t & 3;  // srow 0..31

  const unsigned short* Ag0 = W + (size_t)(M0 + srow)*Astride + schunk*8;
  const unsigned short* Ag1 = W + (size_t)(M0 + 32 + srow)*Astride + schunk*8;
  const unsigned short* Bg0 = X + (size_t)(T0 + srow)*Xstride + Xoff + schunk*8;
  const unsigned short* Bg1 = X + (size_t)(T0 + 32 + srow)*Xstride + Xoff + schunk*8;
  const unsigned short* Bg2 = X + (size_t)(T0 + 64 + srow)*Xstride + Xoff + schunk*8;
  const unsigned short* Bg3 = X + (size_t)(T0 + 96 + srow)*Xstride + Xoff + schunk*8;
  unsigned short* Aw0 = &As[srow*32 + schunk*8];
  unsigned short* Aw1 = &As[(32 + srow)*32 + schunk*8];
  unsigned short* Bw0 = &Bs[srow*32 + schunk*8];
  unsigned short* Bw1 = &Bs[(32 + srow)*32 + schunk*8];
  unsigned short* Bw2 = &Bs[(64 + srow)*32 + schunk*8];
  unsigned short* Bw3 = &Bs[(96 + srow)*32 + schunk*8];

  int Tw = wave*64;
  f32x4 acc[4][4];
  #pragma unroll
  for (int i=0;i<4;i++)
    #pragma unroll
    for (int j=0;j<4;j++)
      #pragma unroll
      for (int u=0;u<4;u++) acc[i][j][u] = 0.f;

  for (int k0=0; k0<K; k0+=32){
    short8 va0 = *(const short8*)(Ag0 + k0);
    short8 va1 = *(const short8*)(Ag1 + k0);
    short8 vb0 = *(const short8*)(Bg0 + k0);
    short8 vb1 = *(const short8*)(Bg1 + k0);
    short8 vb2 = *(const short8*)(Bg2 + k0);
    short8 vb3 = *(const short8*)(Bg3 + k0);
    if (k0) __syncthreads();
    *(short8*)Aw0 = va0; *(short8*)Aw1 = va1;
    *(short8*)Bw0 = vb0; *(short8*)Bw1 = vb1;
    *(short8*)Bw2 = vb2; *(short8*)Bw3 = vb3;
    __syncthreads();
    short8 a[4], bfr[4];
    #pragma unroll
    for (int i=0;i<4;i++) a[i]   = *(const short8*)(&As[(i*16 + r)*32 + q*8]);
    #pragma unroll
    for (int j=0;j<4;j++) bfr[j] = *(const short8*)(&Bs[(Tw + j*16 + r)*32 + q*8]);
    #pragma unroll
    for (int i=0;i<4;i++)
      #pragma unroll
      for (int j=0;j<4;j++)
        acc[i][j] = __builtin_amdgcn_mfma_f32_16x16x32_bf16(a[i], bfr[j], acc[i][j], 0, 0, 0);
  }
  gemm_epi<EPI,EXB>(acc, M0, T0+Tw, r, q, out, outStride, outOff,
                    sPtr, bPtr, extraIn, extraOffB, extraStride,
                    resOffB, resStride, resOff);
}

// ---------------- attention: 16 lanes/query, 8 ch/lane ----------------
// block 256 = 4 waves x 4 queries; grid 1024.
__global__ __launch_bounds__(256) void attn_kernel(
  unsigned qOff, unsigned kOff, unsigned vOff, unsigned idxOff,
  const float* __restrict__ in, const float* __restrict__ wpos,
  unsigned aggOff)
{
  const unsigned short* Q  = (const unsigned short*)(g_scratch + qOff);
  const unsigned short* Kf = (const unsigned short*)(g_scratch + kOff);
  const unsigned short* V  = (const unsigned short*)(g_scratch + vOff);
  const int* idx           = (const int*)(g_scratch + idxOff);
  unsigned short* agg      = (unsigned short*)(g_scratch + aggOff);

  int lane = threadIdx.x & 63, wv = threadIdx.x >> 6;
  int lg = lane >> 4;            // query-in-wave 0..3
  int cl = lane & 15;            // channel lane
  int t = blockIdx.x*16 + wv*4 + lg;
  int b = t >> 12, n = t & 4095;
  const float* xb = in + (size_t)b*9*NP;
  int c0 = cl*8;

  short8 qv = *(const short8*)(Q + (size_t)t*128 + c0);
  float qf[8];
  #pragma unroll
  for (int u=0;u<8;u++) qf[u] = bf2f((unsigned short)qv[u]);
  float xn = xb[n], yn = xb[NP+n], zn = xb[2*NP+n];
  float wp[8][3];
  #pragma unroll
  for (int u=0;u<8;u++){
    wp[u][0]=wpos[(c0+u)*3+0]; wp[u][1]=wpos[(c0+u)*3+1]; wp[u][2]=wpos[(c0+u)*3+2];
  }

  int mi[16]; float s[16];
  #pragma unroll
  for (int j=0;j<16;j++) mi[j] = idx[(size_t)t*16 + j] & 4095;  // mask: never OOB
  #pragma unroll
  for (int j=0;j<16;j++){
    short8 kv = *(const short8*)(Kf + ((size_t)(b<<12) + mi[j])*128 + c0);
    float p = 0.f;
    #pragma unroll
    for (int u=0;u<8;u++) p += qf[u]*bf2f((unsigned short)kv[u]);
    #pragma unroll
    for (int o=8;o>=1;o>>=1) p += __shfl_xor(p, o, 64);   // within 16-lane group
    s[j] = p;
  }
  const float scale = 0.08838834764831845f; // 1/sqrt(128)
  float mx = s[0];
  #pragma unroll
  for (int j=1;j<16;j++) mx = fmaxf(mx, s[j]);
  float e[16], sum = 0.f;
  #pragma unroll
  for (int j=0;j<16;j++){ e[j] = __expf((s[j]-mx)*scale); sum += e[j]; }
  float inv = 1.f / sum;

  float a[8];
  #pragma unroll
  for (int u=0;u<8;u++) a[u] = 0.f;
  #pragma unroll
  for (int j=0;j<16;j++){
    int m = mi[j];
    float w = e[j]*inv;
    short8 vvv = *(const short8*)(V + ((size_t)(b<<12) + m)*128 + c0);
    float rx = xn - xb[m];
    float ry = yn - xb[NP+m];
    float rz = zn - xb[2*NP+m];
    #pragma unroll
    for (int u=0;u<8;u++){
      float pos = wp[u][0]*rx + wp[u][1]*ry + wp[u][2]*rz;
      a[u] += w*(bf2f((unsigned short)vvv[u]) + pos);
    }
  }
  short8 st;
  #pragma unroll
  for (int u=0;u<8;u++) st[u] = (short)f2bf(a[u]);
  *(short8*)(agg + (size_t)t*128 + c0) = st;
}

// ---------------- max/mean pool over tokens (two-stage) ----------------
__global__ __launch_bounds__(256) void pool_part(unsigned xfOff, unsigned gpOff)
{
  const unsigned short* xf = (const unsigned short*)(g_scratch + xfOff);
  float* gp = (float*)(g_scratch + gpOff);   // [b][seg][2][1024]
  int b = blockIdx.x >> 7, cblk = (blockIdx.x >> 3) & 15, seg = blockIdx.x & 7;
  int cl = threadIdx.x & 63, tg = threadIdx.x >> 6;
  int c = cblk*64 + cl;
  float mx = -3.0e38f, sm = 0.f;
  for (int n = seg*512 + tg; n < (seg+1)*512; n += 4){
    float v = bf2f(xf[((size_t)(b<<12) + n)*1024 + c]);
    mx = fmaxf(mx, v); sm += v;
  }
  __shared__ float smx[4][64], ssm[4][64];
  smx[tg][cl]=mx; ssm[tg][cl]=sm;
  __syncthreads();
  if (tg==0){
    #pragma unroll
    for (int k=1;k<4;k++){ mx = fmaxf(mx, smx[k][cl]); sm += ssm[k][cl]; }
    gp[((b*8 + seg)*2 + 0)*1024 + c] = mx;
    gp[((b*8 + seg)*2 + 1)*1024 + c] = sm;
  }
}
__global__ __launch_bounds__(256) void pool_final(unsigned gpOff, unsigned gOff)
{
  const float* gp = (const float*)(g_scratch + gpOff);
  float* g = (float*)(g_scratch + gOff);
  int b = blockIdx.x;
  for (int c = threadIdx.x; c < 1024; c += 256){
    float mx = -3.0e38f, sm = 0.f;
    #pragma unroll
    for (int seg=0; seg<8; ++seg){
      mx = fmaxf(mx, gp[((b*8 + seg)*2 + 0)*1024 + c]);
      sm += gp[((b*8 + seg)*2 + 1)*1024 + c];
    }
    g[b*2048 + c] = mx;
    g[b*2048 + 1024 + c] = sm * (1.f/4096.f);
  }
}

// gb[b][o] = cls_bias1[o] + sum_c W1[o][1024+c]*g[b][c]
__global__ __launch_bounds__(256) void gterm_kernel(const float* __restrict__ w1,
                                                    const float* __restrict__ bias1,
                                                    unsigned gOff, unsigned gbOff)
{
  const float* g = (const float*)(g_scratch + gOff);
  float* gb = (float*)(g_scratch + gbOff);
  int b = blockIdx.x >> 3, og = (blockIdx.x & 7)*64;
  int ol = threadIdx.x & 63, cq = threadIdx.x >> 6;
  int o = og + ol;
  const float* wrow = w1 + (size_t)o*3072 + 1024 + cq*512;
  const float* gp = g + b*2048 + cq*512;
  float acc = 0.f;
  for (int c=0;c<512;c+=4){
    float4 wv4 = *(const float4*)(wrow + c);
    acc += wv4.x*gp[c] + wv4.y*gp[c+1] + wv4.z*gp[c+2] + wv4.w*gp[c+3];
  }
  __shared__ float sred[4][64];
  sred[cq][ol] = acc;
  __syncthreads();
  if (cq==0){
    acc += sred[1][ol] + sred[2][ol] + sred[3][ol];
    gb[b*512 + o] = acc + bias1[o];
  }
}

// ---------------- classifier head (O=13), fp32 out ----------------
__global__ __launch_bounds__(256) void cls3_kernel(unsigned c2Off,
                                                   const float* __restrict__ w3,
                                                   const float* __restrict__ bias3,
                                                   float* __restrict__ outp)
{
  const unsigned short* c2 = (const unsigned short*)(g_scratch + c2Off);
  __shared__ float wf[13*256];
  __shared__ float bf3[13];
  for (int i=threadIdx.x;i<13*256;i+=256) wf[i]=w3[i];
  if (threadIdx.x < 13) bf3[threadIdx.x]=bias3[threadIdx.x];
  __syncthreads();
  int lane = threadIdx.x & 63, wv = threadIdx.x >> 6;
  int tl = lane >> 2, cq = lane & 3;
  int t = blockIdx.x*64 + wv*16 + tl;
  const unsigned short* xrow = c2 + (size_t)t*256 + cq*64;
  float acc[13];
  #pragma unroll
  for (int o=0;o<13;o++) acc[o]=0.f;
  for (int c=0;c<64;c+=8){
    short8 xv = *(const short8*)(xrow + c);
    float xs[8];
    #pragma unroll
    for (int u=0;u<8;u++) xs[u]=bf2f((unsigned short)xv[u]);
    #pragma unroll
    for (int o=0;o<13;o++){
      const float* wr = wf + o*256 + cq*64 + c;
      #pragma unroll
      for (int u=0;u<8;u++) acc[o] += wr[u]*xs[u];
    }
  }
  #pragma unroll
  for (int o=0;o<13;o++){
    acc[o] += __shfl_xor(acc[o], 1, 64);
    acc[o] += __shfl_xor(acc[o], 2, 64);
  }
  if (cq==0){
    int b = t >> 12, n = t & 4095;
    #pragma unroll
    for (int o=0;o<13;o++)
      outp[((size_t)b*13 + o)*NP + n] = acc[o] + bf3[o];
  }
}

// ---------------- launch ----------------
extern "C" void kernel_launch(void* const* d_in, const int* in_sizes, int n_in,
                              void* d_out, int out_size, void* d_ws, size_t ws_size,
                              hipStream_t stream) {
  (void)in_sizes; (void)n_in; (void)out_size; (void)d_ws; (void)ws_size;
  const float* in      = (const float*)d_in[0];
  const float* emb_w1  = (const float*)d_in[1];
  const float* emb_s1  = (const float*)d_in[2];
  const float* emb_b1  = (const float*)d_in[3];
  const float* emb_w2  = (const float*)d_in[4];
  const float* emb_s2  = (const float*)d_in[5];
  const float* emb_b2  = (const float*)d_in[6];
  const float* blk_wq  = (const float*)d_in[7];
  const float* blk_wk  = (const float*)d_in[8];
  const float* blk_wv  = (const float*)d_in[9];
  const float* blk_wpos= (const float*)d_in[10];
  const float* blk_wo  = (const float*)d_in[11];
  const float* blk_s   = (const float*)d_in[12];
  const float* blk_b   = (const float*)d_in[13];
  const float* fuse_w  = (const float*)d_in[14];
  const float* fuse_s  = (const float*)d_in[15];
  const float* fuse_b  = (const float*)d_in[16];
  const float* cls_w1  = (const float*)d_in[17];
  const float* cls_b1  = (const float*)d_in[18];
  const float* cls_s1  = (const float*)d_in[19];
  const float* cls_sh1 = (const float*)d_in[20];
  const float* cls_w2  = (const float*)d_in[21];
  const float* cls_b2  = (const float*)d_in[22];
  const float* cls_s2  = (const float*)d_in[23];
  const float* cls_sh2 = (const float*)d_in[24];
  const float* cls_w3  = (const float*)d_in[25];
  const float* cls_b3  = (const float*)d_in[26];

  // byte offsets into g_scratch
  const unsigned MB = 1u<<20, KB = 1024u;
  const unsigned OFF_IDX   = 0;                 // 1 MB   int idx[T][16]
  const unsigned OFF_WQ    = 1*MB;              // 96 KB  bf16 (3,128,128)
  const unsigned OFF_WK    = 1*MB + 128*KB;     // 96 KB
  const unsigned OFF_WV    = 1*MB + 256*KB;     // 96 KB
  const unsigned OFF_WO    = 1*MB + 384*KB;     // 96 KB
  const unsigned OFF_WEMB2 = 1*MB + 512*KB;     // 32 KB  bf16 (128,128)
  const unsigned OFF_WFUSE = 1*MB + 576*KB;     // 768 KB bf16 (1024,384)
  const unsigned OFF_WW1   = 3*MB;              // 1 MB   bf16 (512,1024) x-half
  const unsigned OFF_WW2   = 4*MB;              // 256 KB bf16 (256,512)
  const unsigned OFF_X1    = 5*MB;              // 4 MB   bf16 (T,128)
  const unsigned OFF_X0    = 9*MB;              // 4 MB   bf16 (T,128)
  const unsigned OFF_XCAT  = 13*MB;             // 12 MB  bf16 (T,384)
  const unsigned OFF_QB    = 25*MB;             // 4 MB
  const unsigned OFF_KB    = 29*MB;             // 4 MB
  const unsigned OFF_VB    = 33*MB;             // 4 MB
  const unsigned OFF_AGG   = 37*MB;             // 4 MB
  const unsigned OFF_XF    = 41*MB;             // 32 MB  bf16 (T,1024)
  const unsigned OFF_C1    = 73*MB;             // 16 MB  bf16 (T,512)
  const unsigned OFF_C2    = 89*MB;             // 8 MB   bf16 (T,256)
  const unsigned OFF_G     = 97*MB;             // 32 KB  f32 (B,2048)
  const unsigned OFF_GB    = 97*MB + 64*KB;     // 8 KB   f32 (B,512)
  const unsigned OFF_GP    = 97*MB + 128*KB;    // 256 KB f32 pool partials
  const unsigned OFF_THR   = 97*MB + 512*KB;    // 64 KB  f32 thr[T]
  const unsigned OFF_PD    = 98*MB;             // 16 MB  f32 knn bound vals / p2 dists
  const unsigned OFF_PI    = 114*MB;            // 16 MB  int knn idx (p2)
  float* outp = (float*)d_out;                  // (B,13,N) f32

  // 0: fused weight conversion prepass (fp32 -> bf16 into scratch)
  CvtArgs ca;
  ca.src[0]=emb_w2;  ca.dstOff[0]=OFF_WEMB2; ca.n[0]=128*128;
  ca.src[1]=blk_wq;  ca.dstOff[1]=OFF_WQ;    ca.n[1]=3*128*128;
  ca.src[2]=blk_wk;  ca.dstOff[2]=OFF_WK;    ca.n[2]=3*128*128;
  ca.src[3]=blk_wv;  ca.dstOff[3]=OFF_WV;    ca.n[3]=3*128*128;
  ca.src[4]=blk_wo;  ca.dstOff[4]=OFF_WO;    ca.n[4]=3*128*128;
  ca.src[5]=fuse_w;  ca.dstOff[5]=OFF_WFUSE; ca.n[5]=1024*384;
  ca.src[6]=cls_w2;  ca.dstOff[6]=OFF_WW2;   ca.n[6]=256*512;
  ca.src[7]=cls_w1;  ca.dstOff[7]=OFF_WW1;   ca.n[7]=512*1024;
  cvt_all<<<dim3(64,8), 256, 0, stream>>>(ca);

  // 1-4: KNN (cheap-threshold two-pass)
  knn_p1<<<dim3(16,16,4), 256, 0, stream>>>(in, OFF_PD);
  knn_thr<<<dim3(64), 256, 0, stream>>>(OFF_PD, OFF_THR);
  knn_p2<<<dim3(16,16,4), 256, 0, stream>>>(in, OFF_THR, OFF_PD, OFF_PI);
  knn_mrg<<<dim3(256), 64, 0, stream>>>(OFF_PD, OFF_PI, OFF_IDX);
  // 5-6: embedding
  emb1_kernel<<<dim3(64,4), 256, 0, stream>>>(in, emb_w1, emb_s1, emb_b1, OFF_X1);
  gemm_small_lds<EPI_RELU_SB,false><<<dim3(2,128,1), 128, 0, stream>>>(
      OFF_WEMB2, OFF_WEMB2, OFF_WEMB2, OFF_X0, OFF_X0, OFF_X0,
      OFF_X1, 128, 0, 128, 0, emb_s2, emb_b2,
      nullptr, 0, 0, 0, 0, 0, 128, 128);
  // 7-9: transformer blocks
  for (int i=0;i<3;i++){
    unsigned wq = OFF_WQ + i*32768, wk = OFF_WK + i*32768;
    unsigned wv = OFF_WV + i*32768, wo = OFF_WO + i*32768;
    const float* wp = blk_wpos + i*128*3;
    const float* si = blk_s + i*128;
    const float* bi = blk_b + i*128;
    unsigned XiOff = (i==0) ? OFF_X0 : OFF_XCAT;
    int Xs = (i==0) ? 128 : 384;
    int Xo = (i==0) ? 0 : (i-1)*128;
    gemm_small_lds<EPI_PLAIN,false><<<dim3(2,128,3), 128, 0, stream>>>(
        wq, wk, wv, OFF_QB, OFF_KB, OFF_VB,
        XiOff, Xs, Xo, 128, 0, nullptr, nullptr,
        nullptr, 0, 0, 0, 0, 0, 128, 128);
    attn_kernel<<<dim3(1024), 256, 0, stream>>>(OFF_QB, OFF_KB, OFF_VB, OFF_IDX, in, wp, OFF_AGG);
    gemm_small_lds<EPI_RES,false><<<dim3(2,128,1), 128, 0, stream>>>(
        wo, wo, wo, OFF_XCAT, OFF_XCAT, OFF_XCAT,
        OFF_AGG, 128, 0, 384, i*128, si, bi,
        nullptr, 0, 0, XiOff, Xs, Xo, 128, 128);
  }
  // 10: fuse (leaky relu), LDS-staged + swizzled
  gemm_lds<EPI_LEAKY,false><<<dim3(8,128,1), 256, 0, stream>>>(
      OFF_WFUSE, OFF_WFUSE, OFF_WFUSE, OFF_XF, OFF_XF, OFF_XF,
      OFF_XCAT, 384, 0, 1024, 0, fuse_s, fuse_b,
      nullptr, 0, 0, 0, 0, 0, 384, 384);
  // 11-13: pooling (two-stage) + broadcast-g term of cls1 (fp32)
  pool_part<<<dim3(512), 256, 0, stream>>>(OFF_XF, OFF_GP);
  pool_final<<<dim3(4), 256, 0, stream>>>(OFF_GP, OFF_G);
  gterm_kernel<<<dim3(32), 256, 0, stream>>>(cls_w1, cls_b1, OFF_G, OFF_GB);
  // 14: cls1 (K=1024 x-half of W1; gb = W1[:,1024:]@g + bias1 as extra)
  gemm_lds<EPI_CLS,false><<<dim3(4,128,1), 256, 0, stream>>>(
      OFF_WW1, OFF_WW1, OFF_WW1, OFF_C1, OFF_C1, OFF_C1,
      OFF_XF, 1024, 0, 512, 0, cls_s1, cls_sh1,
      nullptr, OFF_GB, 512, 0, 0, 0, 1024, 1024);
  // 15: cls2 (K=512), LDS-staged
  gemm_lds<EPI_CLS,true><<<dim3(2,128,1), 256, 0, stream>>>(
      OFF_WW2, OFF_WW2, OFF_WW2, OFF_C2, OFF_C2, OFF_C2,
      OFF_C1, 512, 0, 256, 0, cls_s2, cls_sh2,
      cls_b2, 0, 0, 0, 0, 0, 512, 512);
  // 16: cls3 -> d_out (fp32)
  cls3_kernel<<<dim3(256), 256, 0, stream>>>(OFF_C2, cls_w3, cls_b3, outp);
}